// Round 1
// baseline (653.220 us; speedup 1.0000x reference)
//
#include <hip/hip_runtime.h>
#include <hip/hip_bf16.h>

#define N_NODES 4096
#define HDIM    128
#define E1      131072
#define E2      131072
#define NMSG_B2B (2 * E1)

// ---- workspace layout (float units) ----
#define OFF_PSUM   4
#define OFF_PMAX   132
#define OFF_AGG    260
#define OFF_H      (OFF_AGG + N_NODES * HDIM)       // h f32
#define OFF_HB     (OFF_H + N_NODES * HDIM)         // h bf16 (ushort)
#define OFF_BP1    (OFF_HB + N_NODES * HDIM / 2)    // b2b W1 pack (32768 ushort)
#define OFF_BP2    (OFF_BP1 + 16384)                // b2b W2 pack (16384 ushort)
#define OFF_PP1    (OFF_BP2 + 8192)                 // p2b W1 pack (16384 ushort)
#define OFF_PP2    (OFF_PP1 + 8192)                 // p2b W2 pack (16384 ushort)
#define OFF_BLAST  (OFF_PP2 + 8192)                 // b2b W1 row 256, f32[128]
#define OFF_PEXTRA (OFF_BLAST + 128)                // p2b W1 rows 128..130, f32[384]
#define WS_FLOATS  (OFF_PEXTRA + 384)

typedef short short8 __attribute__((ext_vector_type(8)));
typedef float f32x4 __attribute__((ext_vector_type(4)));

__device__ __forceinline__ unsigned short f2bf(float f) {
  union { float f; unsigned u; } v; v.f = f;
  unsigned r = v.u + 0x7fffu + ((v.u >> 16) & 1u);   // RNE
  return (unsigned short)(r >> 16);
}

// ---------------- reductions + pmax init ----------------
__global__ __launch_bounds__(256) void reduce_kernel(const float* __restrict__ b2bw,
                                                     const float* __restrict__ p2bw,
                                                     const float* __restrict__ area,
                                                     float* __restrict__ ws) {
  __shared__ float red[256];
  int b = blockIdx.x, t = threadIdx.x;
  if (b < 32) {
    float m = 0.f;
    for (int i = b * 256 + t; i < E1; i += 32 * 256) m = fmaxf(m, fabsf(b2bw[i]));
    red[t] = m; __syncthreads();
    for (int s = 128; s > 0; s >>= 1) { if (t < s) red[t] = fmaxf(red[t], red[t + s]); __syncthreads(); }
    if (t == 0) atomicMax((unsigned*)&ws[0], __float_as_uint(red[0]));
  } else if (b < 64) {
    float m = 0.f;
    for (int i = (b - 32) * 256 + t; i < E2; i += 32 * 256) m = fmaxf(m, fabsf(p2bw[i]));
    red[t] = m; __syncthreads();
    for (int s = 128; s > 0; s >>= 1) { if (t < s) red[t] = fmaxf(red[t], red[t + s]); __syncthreads(); }
    if (t == 0) atomicMax((unsigned*)&ws[1], __float_as_uint(red[0]));
  } else if (b < 96) {
    float s0 = 0.f;
    for (int i = (b - 64) * 256 + t; i < N_NODES; i += 32 * 256) s0 += area[i];
    red[t] = s0; __syncthreads();
    for (int s = 128; s > 0; s >>= 1) { if (t < s) red[t] += red[t + s]; __syncthreads(); }
    if (t == 0) atomicAdd(&ws[2], red[0]);
  } else {
    if (t < HDIM) ((int*)ws)[OFF_PMAX + t] = 0x80000000;   // -inf encoded
  }
}

// ---------------- pack weights into MFMA B-fragment order ----------------
// B-frag (16x16x32): lane holds B[k = (lane>>4)*8 + j][n = lane&15], j=0..7, 16B contiguous.
__global__ __launch_bounds__(256) void prep_kernel(const float* __restrict__ bW1,
                                                   const float* __restrict__ bW2,
                                                   const float* __restrict__ pW1,
                                                   const float* __restrict__ pW2,
                                                   float* __restrict__ ws) {
  unsigned short* Bp1 = (unsigned short*)(ws + OFF_BP1);
  unsigned short* Bp2 = (unsigned short*)(ws + OFF_BP2);
  unsigned short* Pp1 = (unsigned short*)(ws + OFF_PP1);
  unsigned short* Pp2 = (unsigned short*)(ws + OFF_PP2);
  float* blast = ws + OFF_BLAST;
  float* pextra = ws + OFF_PEXTRA;
  const int total = 32768 + 3 * 16384 + 128 + 384;
  for (int t = blockIdx.x * 256 + threadIdx.x; t < total; t += gridDim.x * 256) {
    if (t < 32768) {                       // b2b W1: 8 ntiles x 8 ksteps
      int j = t & 7, lane = (t >> 3) & 63, ks = (t >> 9) & 7, nt = t >> 12;
      int n = nt * 16 + (lane & 15), k = ks * 32 + (lane >> 4) * 8 + j;
      Bp1[t] = f2bf(bW1[k * 128 + n]);
    } else if (t < 49152) {                // b2b W2: 8 x 4
      int u = t - 32768;
      int j = u & 7, lane = (u >> 3) & 63, ks = (u >> 9) & 3, nt = u >> 11;
      int n = nt * 16 + (lane & 15), k = ks * 32 + (lane >> 4) * 8 + j;
      Bp2[u] = f2bf(bW2[k * 128 + n]);
    } else if (t < 65536) {                // p2b W1 rows 0..127: 8 x 4
      int u = t - 49152;
      int j = u & 7, lane = (u >> 3) & 63, ks = (u >> 9) & 3, nt = u >> 11;
      int n = nt * 16 + (lane & 15), k = ks * 32 + (lane >> 4) * 8 + j;
      Pp1[u] = f2bf(pW1[k * 128 + n]);
    } else if (t < 81920) {                // p2b W2: 8 x 4
      int u = t - 65536;
      int j = u & 7, lane = (u >> 3) & 63, ks = (u >> 9) & 3, nt = u >> 11;
      int n = nt * 16 + (lane & 15), k = ks * 32 + (lane >> 4) * 8 + j;
      Pp2[u] = f2bf(pW2[k * 128 + n]);
    } else if (t < 82048) {
      int u = t - 81920;
      blast[u] = bW1[256 * 128 + u];
    } else {
      int u = t - 82048;
      int r = u >> 7, n = u & 127;
      pextra[u] = pW1[(128 + r) * 128 + n];
    }
  }
}

// ---------------- input MLP: h = relu(relu(x@W1+b1)@W2+b2), 8 nodes/block ----------------
__global__ __launch_bounds__(128) void input_mlp_kernel(const float* __restrict__ bfeat,
                                                        const int* __restrict__ rid,
                                                        const float* __restrict__ remb,
                                                        const float* __restrict__ iemb,
                                                        const float* __restrict__ W1,
                                                        const float* __restrict__ b1,
                                                        const float* __restrict__ W2,
                                                        const float* __restrict__ b2,
                                                        float* __restrict__ hf,
                                                        unsigned short* __restrict__ hb) {
  __shared__ __attribute__((aligned(16))) float x[8][40];
  __shared__ __attribute__((aligned(16))) float h1[8][128];
  int t = threadIdx.x;
  int n0 = blockIdx.x * 8;
  for (int idx = t; idx < 8 * 40; idx += 128) {
    int nb = idx / 40, f = idx - nb * 40;
    int n = n0 + nb;
    float v;
    if (f < 16)      v = bfeat[n * 16 + f];
    else if (f < 32) v = remb[rid[n] * 16 + (f - 16)];
    else             v = iemb[(n & 1023) * 8 + (f - 32)];
    x[nb][f] = v;
  }
  __syncthreads();
  float acc[8];
  float bb = b1[t];
#pragma unroll
  for (int nb = 0; nb < 8; nb++) acc[nb] = bb;
  for (int k = 0; k < 40; k++) {
    float wv = W1[k * 128 + t];
#pragma unroll
    for (int nb = 0; nb < 8; nb++) acc[nb] += x[nb][k] * wv;
  }
#pragma unroll
  for (int nb = 0; nb < 8; nb++) h1[nb][t] = fmaxf(acc[nb], 0.f);
  __syncthreads();
  float bb2 = b2[t];
#pragma unroll
  for (int nb = 0; nb < 8; nb++) acc[nb] = bb2;
  for (int k = 0; k < 128; k++) {
    float wv = W2[k * 128 + t];
#pragma unroll
    for (int nb = 0; nb < 8; nb++) acc[nb] += h1[nb][k] * wv;
  }
#pragma unroll
  for (int nb = 0; nb < 8; nb++) {
    float v = fmaxf(acc[nb], 0.f);
    int n = n0 + nb;
    hf[n * 128 + t] = v;
    hb[n * 128 + t] = f2bf(v);
  }
}

// ---------------- b2b edge kernel: 64 messages/block, MFMA ----------------
__global__ __launch_bounds__(256) void b2b_kernel(const unsigned short* __restrict__ hb,
                                                  const int* __restrict__ src,
                                                  const int* __restrict__ dst,
                                                  const float* __restrict__ w,
                                                  const float* __restrict__ wsf,
                                                  const unsigned short* __restrict__ Bp1,
                                                  const unsigned short* __restrict__ Bp2,
                                                  const float* __restrict__ b1,
                                                  const float* __restrict__ b2,
                                                  const float* __restrict__ w1last,
                                                  float* __restrict__ agg) {
  __shared__ __attribute__((aligned(16))) unsigned short A[64 * 264];    // [m][256] + pad8
  __shared__ __attribute__((aligned(16))) unsigned short H1s[64 * 136];  // [m][128] + pad8
  __shared__ float wsc[64];
  __shared__ int tgt[64];
  int tid = threadIdx.x;
  int base = blockIdx.x * 64;
  float invb = 1.f / fmaxf(__uint_as_float(((const unsigned*)wsf)[0]), 1.f);
  if (tid < 64) {
    int g = base + tid, e = g >> 1, d = g & 1;
    int s = src[e], dd = dst[e];
    tgt[tid] = d ? dd : s;
    wsc[tid] = w[e] * invb;
  }
  // gather A: msg m = [h[i] | h[j]], i = target node, j = other node
  for (int c = tid; c < 2048; c += 256) {
    int m = c >> 5, cc = c & 31;
    int half = cc >> 4, o = (cc & 15) * 8;
    int g = base + m, e = g >> 1, d = g & 1;
    int s = src[e], dd = dst[e];
    int node = ((d ^ half) & 1) ? dd : s;
    uint4 v = *(const uint4*)(hb + node * 128 + o);
    *(uint4*)(&A[m * 264 + half * 128 + o]) = v;
  }
  __syncthreads();
  int lane = tid & 63, wv = tid >> 6;
  int l15 = lane & 15, q = lane >> 4;
  int m0 = wv * 16;
  f32x4 zero = {0.f, 0.f, 0.f, 0.f};
  f32x4 acc[8];
#pragma unroll
  for (int i = 0; i < 8; i++) acc[i] = zero;
  const unsigned short* Arow = &A[(m0 + l15) * 264 + q * 8];
#pragma unroll
  for (int ks = 0; ks < 8; ks++) {
    short8 af = *(const short8*)(Arow + ks * 32);
#pragma unroll
    for (int nt = 0; nt < 8; nt++) {
      short8 bfr = *(const short8*)(Bp1 + ((nt * 8 + ks) * 64 + lane) * 8);
      acc[nt] = __builtin_amdgcn_mfma_f32_16x16x32_bf16(af, bfr, acc[nt], 0, 0, 0);
    }
  }
  float wr[4];
#pragma unroll
  for (int r = 0; r < 4; r++) wr[r] = wsc[m0 + q * 4 + r];
#pragma unroll
  for (int nt = 0; nt < 8; nt++) {
    int n = nt * 16 + l15;
    float b1v = b1[n], wlv = w1last[n];
#pragma unroll
    for (int r = 0; r < 4; r++) {
      float v = acc[nt][r] + b1v + wr[r] * wlv;
      H1s[(m0 + q * 4 + r) * 136 + n] = f2bf(fmaxf(v, 0.f));
    }
  }
  __syncthreads();
  f32x4 acc2[8];
#pragma unroll
  for (int i = 0; i < 8; i++) acc2[i] = zero;
  const unsigned short* Hrow = &H1s[(m0 + l15) * 136 + q * 8];
#pragma unroll
  for (int ks = 0; ks < 4; ks++) {
    short8 af = *(const short8*)(Hrow + ks * 32);
#pragma unroll
    for (int nt = 0; nt < 8; nt++) {
      short8 bfr = *(const short8*)(Bp2 + ((nt * 4 + ks) * 64 + lane) * 8);
      acc2[nt] = __builtin_amdgcn_mfma_f32_16x16x32_bf16(af, bfr, acc2[nt], 0, 0, 0);
    }
  }
  int tg[4];
#pragma unroll
  for (int r = 0; r < 4; r++) tg[r] = tgt[m0 + q * 4 + r];
#pragma unroll
  for (int nt = 0; nt < 8; nt++) {
    int n = nt * 16 + l15;
    float b2v = b2[n];
#pragma unroll
    for (int r = 0; r < 4; r++) {
      atomicAdd(&agg[tg[r] * 128 + n], acc2[nt][r] + b2v);
    }
  }
}

// ---------------- p2b edge kernel ----------------
__global__ __launch_bounds__(256) void p2b_kernel(const unsigned short* __restrict__ hb,
                                                  const int* __restrict__ pblk,
                                                  const int* __restrict__ ppin,
                                                  const float* __restrict__ pw,
                                                  const float* __restrict__ pins,
                                                  const float* __restrict__ wsf,
                                                  const unsigned short* __restrict__ Pp1,
                                                  const unsigned short* __restrict__ Pp2,
                                                  const float* __restrict__ b1,
                                                  const float* __restrict__ b2,
                                                  const float* __restrict__ wextra,
                                                  float* __restrict__ agg) {
  __shared__ __attribute__((aligned(16))) unsigned short A[64 * 136];
  __shared__ __attribute__((aligned(16))) unsigned short H1s[64 * 136];
  __shared__ float pf0[64], pf1[64], pf2[64];
  __shared__ int tgt[64];
  int tid = threadIdx.x;
  int base = blockIdx.x * 64;
  float invp = 1.f / fmaxf(__uint_as_float(((const unsigned*)wsf)[1]), 1.f);
  float as = wsf[2];
  float cs = fmaxf(sqrtf(fmaxf(as, 1e-6f)), 1e-6f);
  float invc = 1.f / cs;
  if (tid < 64) {
    int e = base + tid;
    int pin = ppin[e];
    pf0[tid] = pins[pin * 2] * invc;
    pf1[tid] = pins[pin * 2 + 1] * invc;
    pf2[tid] = pw[e] * invp;
    tgt[tid] = pblk[e];
  }
  for (int c = tid; c < 1024; c += 256) {
    int m = c >> 4, o = (c & 15) * 8;
    int e = base + m;
    int node = pblk[e];
    *(uint4*)(&A[m * 136 + o]) = *(const uint4*)(hb + node * 128 + o);
  }
  __syncthreads();
  int lane = tid & 63, wvi = tid >> 6;
  int l15 = lane & 15, q = lane >> 4;
  int m0 = wvi * 16;
  f32x4 zero = {0.f, 0.f, 0.f, 0.f};
  f32x4 acc[8];
#pragma unroll
  for (int i = 0; i < 8; i++) acc[i] = zero;
  const unsigned short* Arow = &A[(m0 + l15) * 136 + q * 8];
#pragma unroll
  for (int ks = 0; ks < 4; ks++) {
    short8 af = *(const short8*)(Arow + ks * 32);
#pragma unroll
    for (int nt = 0; nt < 8; nt++) {
      short8 bfr = *(const short8*)(Pp1 + ((nt * 4 + ks) * 64 + lane) * 8);
      acc[nt] = __builtin_amdgcn_mfma_f32_16x16x32_bf16(af, bfr, acc[nt], 0, 0, 0);
    }
  }
  float x0[4], x1[4], x2[4];
#pragma unroll
  for (int r = 0; r < 4; r++) {
    int m = m0 + q * 4 + r;
    x0[r] = pf0[m]; x1[r] = pf1[m]; x2[r] = pf2[m];
  }
#pragma unroll
  for (int nt = 0; nt < 8; nt++) {
    int n = nt * 16 + l15;
    float b1v = b1[n];
    float e0 = wextra[n], e1 = wextra[128 + n], e2 = wextra[256 + n];
#pragma unroll
    for (int r = 0; r < 4; r++) {
      float v = acc[nt][r] + b1v + x0[r] * e0 + x1[r] * e1 + x2[r] * e2;
      H1s[(m0 + q * 4 + r) * 136 + n] = f2bf(fmaxf(v, 0.f));
    }
  }
  __syncthreads();
  f32x4 acc2[8];
#pragma unroll
  for (int i = 0; i < 8; i++) acc2[i] = zero;
  const unsigned short* Hrow = &H1s[(m0 + l15) * 136 + q * 8];
#pragma unroll
  for (int ks = 0; ks < 4; ks++) {
    short8 af = *(const short8*)(Hrow + ks * 32);
#pragma unroll
    for (int nt = 0; nt < 8; nt++) {
      short8 bfr = *(const short8*)(Pp2 + ((nt * 4 + ks) * 64 + lane) * 8);
      acc2[nt] = __builtin_amdgcn_mfma_f32_16x16x32_bf16(af, bfr, acc2[nt], 0, 0, 0);
    }
  }
  int tg[4];
#pragma unroll
  for (int r = 0; r < 4; r++) tg[r] = tgt[m0 + q * 4 + r];
#pragma unroll
  for (int nt = 0; nt < 8; nt++) {
    int n = nt * 16 + l15;
    float b2v = b2[n];
#pragma unroll
    for (int r = 0; r < 4; r++) {
      atomicAdd(&agg[tg[r] * 128 + n], acc2[nt][r] + b2v);
    }
  }
}

// ---------------- z = h@selfW + selfb + agg, LayerNorm, pooling contribs ----------------
__global__ __launch_bounds__(128) void selfln_kernel(const float* __restrict__ hf,
                                                     const float* __restrict__ agg,
                                                     const float* __restrict__ sW,
                                                     const float* __restrict__ sb,
                                                     const float* __restrict__ lng,
                                                     const float* __restrict__ lnb,
                                                     float* __restrict__ ws,
                                                     float* __restrict__ out) {
  __shared__ float hrow[128];
  __shared__ float red[128];
  int n = blockIdx.x, t = threadIdx.x;
  hrow[t] = hf[n * 128 + t];
  __syncthreads();
  float acc = sb[t] + agg[n * 128 + t];
  for (int k = 0; k < 128; k++) acc += hrow[k] * sW[k * 128 + t];
  red[t] = acc; __syncthreads();
  for (int s = 64; s > 0; s >>= 1) { if (t < s) red[t] += red[t + s]; __syncthreads(); }
  float mu = red[0] * (1.f / 128.f);
  __syncthreads();
  float dv = acc - mu;
  red[t] = dv * dv; __syncthreads();
  for (int s = 64; s > 0; s >>= 1) { if (t < s) red[t] += red[t + s]; __syncthreads(); }
  float var = red[0] * (1.f / 128.f);
  float o = dv * rsqrtf(var + 1e-5f) * lng[t] + lnb[t];
  out[n * 128 + t] = o;
  atomicAdd(&ws[OFF_PSUM + t], o);
  int enc = __float_as_int(o);
  enc = enc >= 0 ? enc : (enc ^ 0x7fffffff);
  atomicMax(&((int*)ws)[OFF_PMAX + t], enc);
  if (t == 0) out[N_NODES * HDIM + HDIM + n] = 1.0f;   // block_mask = True
}

// ---------------- graph embedding ----------------
__global__ __launch_bounds__(128) void graph_kernel(const float* __restrict__ ws,
                                                    const float* __restrict__ W1,
                                                    const float* __restrict__ b1,
                                                    const float* __restrict__ W2,
                                                    const float* __restrict__ b2,
                                                    float* __restrict__ out) {
  __shared__ float pooled[256];
  __shared__ float g1[128];
  int t = threadIdx.x;
  pooled[t] = ws[OFF_PSUM + t] * (1.f / (float)N_NODES);
  int e = ((const int*)ws)[OFF_PMAX + t];
  int bits = e >= 0 ? e : (e ^ 0x7fffffff);
  pooled[128 + t] = __int_as_float(bits);
  __syncthreads();
  float acc = b1[t];
  for (int k = 0; k < 256; k++) acc += pooled[k] * W1[k * 128 + t];
  g1[t] = fmaxf(acc, 0.f);
  __syncthreads();
  float a2 = b2[t];
  for (int k = 0; k < 128; k++) a2 += g1[k] * W2[k * 128 + t];
  out[N_NODES * HDIM + t] = a2;
}

extern "C" void kernel_launch(void* const* d_in, const int* in_sizes, int n_in,
                              void* d_out, int out_size, void* d_ws, size_t ws_size,
                              hipStream_t stream) {
  const float* bfeat = (const float*)d_in[0];
  const int*   rid   = (const int*)d_in[1];
  const int*   bsrc  = (const int*)d_in[2];
  const int*   bdst  = (const int*)d_in[3];
  const float* bw    = (const float*)d_in[4];
  const int*   ppin  = (const int*)d_in[5];
  const int*   pblk  = (const int*)d_in[6];
  const float* pw    = (const float*)d_in[7];
  const float* pins  = (const float*)d_in[8];
  const float* area  = (const float*)d_in[9];
  const float* remb  = (const float*)d_in[10];
  const float* iemb  = (const float*)d_in[11];
  const float* inW1  = (const float*)d_in[12];
  const float* inb1  = (const float*)d_in[13];
  const float* inW2  = (const float*)d_in[14];
  const float* inb2  = (const float*)d_in[15];
  const float* bW1   = (const float*)d_in[16];
  const float* bb1   = (const float*)d_in[17];
  const float* bW2   = (const float*)d_in[18];
  const float* bb2   = (const float*)d_in[19];
  const float* pW1   = (const float*)d_in[20];
  const float* pb1   = (const float*)d_in[21];
  const float* pW2   = (const float*)d_in[22];
  const float* pb2   = (const float*)d_in[23];
  const float* sW    = (const float*)d_in[24];
  const float* sb    = (const float*)d_in[25];
  const float* lng   = (const float*)d_in[26];
  const float* lnb   = (const float*)d_in[27];
  const float* gW1   = (const float*)d_in[28];
  const float* gb1   = (const float*)d_in[29];
  const float* gW2   = (const float*)d_in[30];
  const float* gb2   = (const float*)d_in[31];

  float* ws  = (float*)d_ws;
  float* out = (float*)d_out;
  float* agg = ws + OFF_AGG;
  float* hf  = ws + OFF_H;
  unsigned short* hb  = (unsigned short*)(ws + OFF_HB);
  unsigned short* Bp1 = (unsigned short*)(ws + OFF_BP1);
  unsigned short* Bp2 = (unsigned short*)(ws + OFF_BP2);
  unsigned short* Pp1 = (unsigned short*)(ws + OFF_PP1);
  unsigned short* Pp2 = (unsigned short*)(ws + OFF_PP2);
  const float* blast  = ws + OFF_BLAST;
  const float* pextra = ws + OFF_PEXTRA;

  // zero scalars + psum + pmax + agg
  hipMemsetAsync(d_ws, 0, (size_t)OFF_H * sizeof(float), stream);
  reduce_kernel<<<97, 256, 0, stream>>>(bw, pw, area, ws);
  prep_kernel<<<128, 256, 0, stream>>>(bW1, bW2, pW1, pW2, ws);
  input_mlp_kernel<<<N_NODES / 8, 128, 0, stream>>>(bfeat, rid, remb, iemb,
                                                    inW1, inb1, inW2, inb2, hf, hb);
  b2b_kernel<<<NMSG_B2B / 64, 256, 0, stream>>>(hb, bsrc, bdst, bw, ws, Bp1, Bp2,
                                                bb1, bb2, blast, agg);
  p2b_kernel<<<E2 / 64, 256, 0, stream>>>(hb, pblk, ppin, pw, pins, ws, Pp1, Pp2,
                                          pb1, pb2, pextra, agg);
  selfln_kernel<<<N_NODES, 128, 0, stream>>>(hf, agg, sW, sb, lng, lnb, ws, out);
  graph_kernel<<<1, 128, 0, stream>>>(ws, gW1, gb1, gW2, gb2, out);
}

// Round 2
// 452.488 us; speedup vs baseline: 1.4436x; 1.4436x over previous
//
#include <hip/hip_runtime.h>
#include <hip/hip_bf16.h>

#define N_NODES 4096
#define HDIM    128
#define E1      131072
#define E2      131072
#define NMSG_B2B (2 * E1)

// ---- workspace layout (float units) ----
#define OFF_PSUM   4
#define OFF_PMAX   132
#define OFF_AGG    260
#define OFF_H      (OFF_AGG + N_NODES * HDIM)       // h f32
#define OFF_HB     (OFF_H + N_NODES * HDIM)         // h bf16 (ushort)
#define OFF_BP1    (OFF_HB + N_NODES * HDIM / 2)    // b2b W1 pack (32768 ushort)
#define OFF_BP2    (OFF_BP1 + 16384)                // b2b W2 pack (16384 ushort)
#define OFF_PP1    (OFF_BP2 + 8192)                 // p2b W1 pack (16384 ushort)
#define OFF_PP2    (OFF_PP1 + 8192)                 // p2b W2 pack (16384 ushort)
#define OFF_BLAST  (OFF_PP2 + 8192)                 // b2b W1 row 256, f32[128]
#define OFF_PEXTRA (OFF_BLAST + 128)                // p2b W1 rows 128..130, f32[384]
#define OFF_CNTB   (OFF_PEXTRA + 384)               // int[4096]
#define OFF_STARTB (OFF_CNTB + 4096)                // int[4096]
#define OFF_CNTP   (OFF_STARTB + 4096)              // int[4096]
#define OFF_STARTP (OFF_CNTP + 4096)                // int[4096]
#define OFF_SRTB   (OFF_STARTP + 4096)              // int[262144] sorted b2b msg ids
#define OFF_SRTP   (OFF_SRTB + NMSG_B2B)            // int[131072] sorted p2b edge ids
#define WS_FLOATS  (OFF_SRTP + E2)

typedef short short8 __attribute__((ext_vector_type(8)));
typedef float f32x4 __attribute__((ext_vector_type(4)));

__device__ __forceinline__ unsigned short f2bf(float f) {
  union { float f; unsigned u; } v; v.f = f;
  unsigned r = v.u + 0x7fffu + ((v.u >> 16) & 1u);   // RNE
  return (unsigned short)(r >> 16);
}

// ---------------- reductions + pmax init ----------------
__global__ __launch_bounds__(256) void reduce_kernel(const float* __restrict__ b2bw,
                                                     const float* __restrict__ p2bw,
                                                     const float* __restrict__ area,
                                                     float* __restrict__ ws) {
  __shared__ float red[256];
  int b = blockIdx.x, t = threadIdx.x;
  if (b < 32) {
    float m = 0.f;
    for (int i = b * 256 + t; i < E1; i += 32 * 256) m = fmaxf(m, fabsf(b2bw[i]));
    red[t] = m; __syncthreads();
    for (int s = 128; s > 0; s >>= 1) { if (t < s) red[t] = fmaxf(red[t], red[t + s]); __syncthreads(); }
    if (t == 0) atomicMax((unsigned*)&ws[0], __float_as_uint(red[0]));
  } else if (b < 64) {
    float m = 0.f;
    for (int i = (b - 32) * 256 + t; i < E2; i += 32 * 256) m = fmaxf(m, fabsf(p2bw[i]));
    red[t] = m; __syncthreads();
    for (int s = 128; s > 0; s >>= 1) { if (t < s) red[t] = fmaxf(red[t], red[t + s]); __syncthreads(); }
    if (t == 0) atomicMax((unsigned*)&ws[1], __float_as_uint(red[0]));
  } else if (b < 96) {
    float s0 = 0.f;
    for (int i = (b - 64) * 256 + t; i < N_NODES; i += 32 * 256) s0 += area[i];
    red[t] = s0; __syncthreads();
    for (int s = 128; s > 0; s >>= 1) { if (t < s) red[t] += red[t + s]; __syncthreads(); }
    if (t == 0) atomicAdd(&ws[2], red[0]);
  } else {
    if (t < HDIM) ((int*)ws)[OFF_PMAX + t] = 0x80000000;   // -inf encoded
  }
}

// ---------------- counting sort: histogram / scan / scatter ----------------
__global__ __launch_bounds__(256) void hist_kernel(const int* __restrict__ src,
                                                   const int* __restrict__ dst,
                                                   const int* __restrict__ pblk,
                                                   int* __restrict__ cntB,
                                                   int* __restrict__ cntP) {
  int i = blockIdx.x * 256 + threadIdx.x;
  if (i < NMSG_B2B) {
    int e = i >> 1;
    int t = (i & 1) ? dst[e] : src[e];
    atomicAdd(&cntB[t], 1);
  } else if (i < NMSG_B2B + E2) {
    atomicAdd(&cntP[pblk[i - NMSG_B2B]], 1);
  }
}

__global__ __launch_bounds__(1024) void scan_kernel(float* __restrict__ ws) {
  const int* cnt = (const int*)ws + (blockIdx.x == 0 ? OFF_CNTB : OFF_CNTP);
  int* start     = (int*)ws + (blockIdx.x == 0 ? OFF_STARTB : OFF_STARTP);
  __shared__ int s[1024];
  int t = threadIdx.x;
  int base = t * 4;
  int a0 = cnt[base], a1 = cnt[base + 1], a2 = cnt[base + 2], a3 = cnt[base + 3];
  int sum = a0 + a1 + a2 + a3;
  s[t] = sum; __syncthreads();
  for (int off = 1; off < 1024; off <<= 1) {
    int v = (t >= off) ? s[t - off] : 0;
    __syncthreads();
    s[t] += v;
    __syncthreads();
  }
  int excl = s[t] - sum;
  start[base]     = excl;
  start[base + 1] = excl + a0;
  start[base + 2] = excl + a0 + a1;
  start[base + 3] = excl + a0 + a1 + a2;
}

__global__ __launch_bounds__(256) void scatter_kernel(const int* __restrict__ src,
                                                      const int* __restrict__ dst,
                                                      const int* __restrict__ pblk,
                                                      int* __restrict__ startB,
                                                      int* __restrict__ startP,
                                                      int* __restrict__ sortedB,
                                                      int* __restrict__ sortedP) {
  int i = blockIdx.x * 256 + threadIdx.x;
  if (i < NMSG_B2B) {
    int e = i >> 1;
    int t = (i & 1) ? dst[e] : src[e];
    int pos = atomicAdd(&startB[t], 1);
    sortedB[pos] = i;
  } else if (i < NMSG_B2B + E2) {
    int e = i - NMSG_B2B;
    int t = pblk[e];
    int pos = atomicAdd(&startP[t], 1);
    sortedP[pos] = e;
  }
}

// ---------------- pack weights into MFMA B-fragment order ----------------
__global__ __launch_bounds__(256) void prep_kernel(const float* __restrict__ bW1,
                                                   const float* __restrict__ bW2,
                                                   const float* __restrict__ pW1,
                                                   const float* __restrict__ pW2,
                                                   float* __restrict__ ws) {
  unsigned short* Bp1 = (unsigned short*)(ws + OFF_BP1);
  unsigned short* Bp2 = (unsigned short*)(ws + OFF_BP2);
  unsigned short* Pp1 = (unsigned short*)(ws + OFF_PP1);
  unsigned short* Pp2 = (unsigned short*)(ws + OFF_PP2);
  float* blast = ws + OFF_BLAST;
  float* pextra = ws + OFF_PEXTRA;
  const int total = 32768 + 3 * 16384 + 128 + 384;
  for (int t = blockIdx.x * 256 + threadIdx.x; t < total; t += gridDim.x * 256) {
    if (t < 32768) {                       // b2b W1: 8 ntiles x 8 ksteps
      int j = t & 7, lane = (t >> 3) & 63, ks = (t >> 9) & 7, nt = t >> 12;
      int n = nt * 16 + (lane & 15), k = ks * 32 + (lane >> 4) * 8 + j;
      Bp1[t] = f2bf(bW1[k * 128 + n]);
    } else if (t < 49152) {                // b2b W2: 8 x 4
      int u = t - 32768;
      int j = u & 7, lane = (u >> 3) & 63, ks = (u >> 9) & 3, nt = u >> 11;
      int n = nt * 16 + (lane & 15), k = ks * 32 + (lane >> 4) * 8 + j;
      Bp2[u] = f2bf(bW2[k * 128 + n]);
    } else if (t < 65536) {                // p2b W1 rows 0..127
      int u = t - 49152;
      int j = u & 7, lane = (u >> 3) & 63, ks = (u >> 9) & 3, nt = u >> 11;
      int n = nt * 16 + (lane & 15), k = ks * 32 + (lane >> 4) * 8 + j;
      Pp1[u] = f2bf(pW1[k * 128 + n]);
    } else if (t < 81920) {                // p2b W2
      int u = t - 65536;
      int j = u & 7, lane = (u >> 3) & 63, ks = (u >> 9) & 3, nt = u >> 11;
      int n = nt * 16 + (lane & 15), k = ks * 32 + (lane >> 4) * 8 + j;
      Pp2[u] = f2bf(pW2[k * 128 + n]);
    } else if (t < 82048) {
      int u = t - 81920;
      blast[u] = bW1[256 * 128 + u];
    } else {
      int u = t - 82048;
      int r = u >> 7, n = u & 127;
      pextra[u] = pW1[(128 + r) * 128 + n];
    }
  }
}

// ---------------- input MLP ----------------
__global__ __launch_bounds__(128) void input_mlp_kernel(const float* __restrict__ bfeat,
                                                        const int* __restrict__ rid,
                                                        const float* __restrict__ remb,
                                                        const float* __restrict__ iemb,
                                                        const float* __restrict__ W1,
                                                        const float* __restrict__ b1,
                                                        const float* __restrict__ W2,
                                                        const float* __restrict__ b2,
                                                        float* __restrict__ hf,
                                                        unsigned short* __restrict__ hb) {
  __shared__ __attribute__((aligned(16))) float x[8][40];
  __shared__ __attribute__((aligned(16))) float h1[8][128];
  int t = threadIdx.x;
  int n0 = blockIdx.x * 8;
  for (int idx = t; idx < 8 * 40; idx += 128) {
    int nb = idx / 40, f = idx - nb * 40;
    int n = n0 + nb;
    float v;
    if (f < 16)      v = bfeat[n * 16 + f];
    else if (f < 32) v = remb[rid[n] * 16 + (f - 16)];
    else             v = iemb[(n & 1023) * 8 + (f - 32)];
    x[nb][f] = v;
  }
  __syncthreads();
  float acc[8];
  float bb = b1[t];
#pragma unroll
  for (int nb = 0; nb < 8; nb++) acc[nb] = bb;
  for (int k = 0; k < 40; k++) {
    float wv = W1[k * 128 + t];
#pragma unroll
    for (int nb = 0; nb < 8; nb++) acc[nb] += x[nb][k] * wv;
  }
#pragma unroll
  for (int nb = 0; nb < 8; nb++) h1[nb][t] = fmaxf(acc[nb], 0.f);
  __syncthreads();
  float bb2 = b2[t];
#pragma unroll
  for (int nb = 0; nb < 8; nb++) acc[nb] = bb2;
  for (int k = 0; k < 128; k++) {
    float wv = W2[k * 128 + t];
#pragma unroll
    for (int nb = 0; nb < 8; nb++) acc[nb] += h1[nb][k] * wv;
  }
#pragma unroll
  for (int nb = 0; nb < 8; nb++) {
    float v = fmaxf(acc[nb], 0.f);
    int n = n0 + nb;
    hf[n * 128 + t] = v;
    hb[n * 128 + t] = f2bf(v);
  }
}

// ---------------- b2b edge kernel: 64 sorted messages/block, MFMA + segmented reduce ----------------
__global__ __launch_bounds__(256) void b2b_kernel(const unsigned short* __restrict__ hb,
                                                  const int* __restrict__ src,
                                                  const int* __restrict__ dst,
                                                  const float* __restrict__ w,
                                                  const float* __restrict__ wsf,
                                                  const int* __restrict__ sortedB,
                                                  const unsigned short* __restrict__ Bp1,
                                                  const unsigned short* __restrict__ Bp2,
                                                  const float* __restrict__ b1,
                                                  const float* __restrict__ b2,
                                                  const float* __restrict__ w1last,
                                                  float* __restrict__ agg) {
  __shared__ __attribute__((aligned(16))) unsigned short A[64 * 264];    // reused as float M[64*132]
  __shared__ __attribute__((aligned(16))) unsigned short H1s[64 * 136];
  __shared__ float wsc[64];
  __shared__ int tgt[64];
  __shared__ int oth[64];
  float* Mf = (float*)A;
  int tid = threadIdx.x;
  int base = blockIdx.x * 64;
  float invb = 1.f / fmaxf(__uint_as_float(((const unsigned*)wsf)[0]), 1.f);
  if (tid < 64) {
    int g = sortedB[base + tid];
    int e = g >> 1, d = g & 1;
    int s = src[e], dd = dst[e];
    tgt[tid] = d ? dd : s;      // message target (i)
    oth[tid] = d ? s : dd;      // other endpoint (j)
    wsc[tid] = w[e] * invb;
  }
  __syncthreads();
  // gather A: msg m = [h[i] | h[j]]
  for (int c = tid; c < 2048; c += 256) {
    int m = c >> 5, cc = c & 31;
    int half = cc >> 4, o = (cc & 15) * 8;
    int node = half ? oth[m] : tgt[m];
    uint4 v = *(const uint4*)(hb + node * 128 + o);
    *(uint4*)(&A[m * 264 + half * 128 + o]) = v;
  }
  __syncthreads();
  int lane = tid & 63, wv = tid >> 6;
  int l15 = lane & 15, q = lane >> 4;
  int m0 = wv * 16;
  f32x4 zero = {0.f, 0.f, 0.f, 0.f};
  f32x4 acc[8];
#pragma unroll
  for (int i = 0; i < 8; i++) acc[i] = zero;
  const unsigned short* Arow = &A[(m0 + l15) * 264 + q * 8];
#pragma unroll
  for (int ks = 0; ks < 8; ks++) {
    short8 af = *(const short8*)(Arow + ks * 32);
#pragma unroll
    for (int nt = 0; nt < 8; nt++) {
      short8 bfr = *(const short8*)(Bp1 + ((nt * 8 + ks) * 64 + lane) * 8);
      acc[nt] = __builtin_amdgcn_mfma_f32_16x16x32_bf16(af, bfr, acc[nt], 0, 0, 0);
    }
  }
  float wr[4];
#pragma unroll
  for (int r = 0; r < 4; r++) wr[r] = wsc[m0 + q * 4 + r];
#pragma unroll
  for (int nt = 0; nt < 8; nt++) {
    int n = nt * 16 + l15;
    float b1v = b1[n], wlv = w1last[n];
#pragma unroll
    for (int r = 0; r < 4; r++) {
      float v = acc[nt][r] + b1v + wr[r] * wlv;
      H1s[(m0 + q * 4 + r) * 136 + n] = f2bf(fmaxf(v, 0.f));
    }
  }
  __syncthreads();   // all waves done with A + H1s ready
  f32x4 acc2[8];
#pragma unroll
  for (int i = 0; i < 8; i++) acc2[i] = zero;
  const unsigned short* Hrow = &H1s[(m0 + l15) * 136 + q * 8];
#pragma unroll
  for (int ks = 0; ks < 4; ks++) {
    short8 af = *(const short8*)(Hrow + ks * 32);
#pragma unroll
    for (int nt = 0; nt < 8; nt++) {
      short8 bfr = *(const short8*)(Bp2 + ((nt * 4 + ks) * 64 + lane) * 8);
      acc2[nt] = __builtin_amdgcn_mfma_f32_16x16x32_bf16(af, bfr, acc2[nt], 0, 0, 0);
    }
  }
  // write full messages (incl. bias) to LDS (A's storage, now free)
#pragma unroll
  for (int nt = 0; nt < 8; nt++) {
    int n = nt * 16 + l15;
    float b2v = b2[n];
#pragma unroll
    for (int r = 0; r < 4; r++) {
      Mf[(m0 + q * 4 + r) * 132 + n] = acc2[nt][r] + b2v;
    }
  }
  __syncthreads();
  // segmented reduce over the 64 sorted messages; one atomic row per segment
  int c = tid & 127, half = tid >> 7;
  int r0 = half * 32;
  float accv = 0.f;
  int cur = tgt[r0];
  for (int r = r0; r < r0 + 32; r++) {
    int tg = tgt[r];
    if (tg != cur) { atomicAdd(&agg[cur * 128 + c], accv); accv = 0.f; cur = tg; }
    accv += Mf[r * 132 + c];
  }
  atomicAdd(&agg[cur * 128 + c], accv);
}

// ---------------- p2b edge kernel ----------------
__global__ __launch_bounds__(256) void p2b_kernel(const unsigned short* __restrict__ hb,
                                                  const int* __restrict__ pblk,
                                                  const int* __restrict__ ppin,
                                                  const float* __restrict__ pw,
                                                  const float* __restrict__ pins,
                                                  const float* __restrict__ wsf,
                                                  const int* __restrict__ sortedP,
                                                  const unsigned short* __restrict__ Pp1,
                                                  const unsigned short* __restrict__ Pp2,
                                                  const float* __restrict__ b1,
                                                  const float* __restrict__ b2,
                                                  const float* __restrict__ wextra,
                                                  float* __restrict__ agg) {
  __shared__ __attribute__((aligned(16))) float Mf[64 * 132];            // also holds A (bf16)
  __shared__ __attribute__((aligned(16))) unsigned short H1s[64 * 136];
  __shared__ float pf0[64], pf1[64], pf2[64];
  __shared__ int tgt[64];
  unsigned short* A = (unsigned short*)Mf;   // 64*136 ushort fits in 64*132 float
  int tid = threadIdx.x;
  int base = blockIdx.x * 64;
  float invp = 1.f / fmaxf(__uint_as_float(((const unsigned*)wsf)[1]), 1.f);
  float as = wsf[2];
  float cs = fmaxf(sqrtf(fmaxf(as, 1e-6f)), 1e-6f);
  float invc = 1.f / cs;
  if (tid < 64) {
    int e = sortedP[base + tid];
    int pin = ppin[e];
    pf0[tid] = pins[pin * 2] * invc;
    pf1[tid] = pins[pin * 2 + 1] * invc;
    pf2[tid] = pw[e] * invp;
    tgt[tid] = pblk[e];
  }
  __syncthreads();
  for (int c = tid; c < 1024; c += 256) {
    int m = c >> 4, o = (c & 15) * 8;
    int node = tgt[m];
    *(uint4*)(&A[m * 136 + o]) = *(const uint4*)(hb + node * 128 + o);
  }
  __syncthreads();
  int lane = tid & 63, wvi = tid >> 6;
  int l15 = lane & 15, q = lane >> 4;
  int m0 = wvi * 16;
  f32x4 zero = {0.f, 0.f, 0.f, 0.f};
  f32x4 acc[8];
#pragma unroll
  for (int i = 0; i < 8; i++) acc[i] = zero;
  const unsigned short* Arow = &A[(m0 + l15) * 136 + q * 8];
#pragma unroll
  for (int ks = 0; ks < 4; ks++) {
    short8 af = *(const short8*)(Arow + ks * 32);
#pragma unroll
    for (int nt = 0; nt < 8; nt++) {
      short8 bfr = *(const short8*)(Pp1 + ((nt * 4 + ks) * 64 + lane) * 8);
      acc[nt] = __builtin_amdgcn_mfma_f32_16x16x32_bf16(af, bfr, acc[nt], 0, 0, 0);
    }
  }
  float x0[4], x1[4], x2[4];
#pragma unroll
  for (int r = 0; r < 4; r++) {
    int m = m0 + q * 4 + r;
    x0[r] = pf0[m]; x1[r] = pf1[m]; x2[r] = pf2[m];
  }
#pragma unroll
  for (int nt = 0; nt < 8; nt++) {
    int n = nt * 16 + l15;
    float b1v = b1[n];
    float e0 = wextra[n], e1 = wextra[128 + n], e2 = wextra[256 + n];
#pragma unroll
    for (int r = 0; r < 4; r++) {
      float v = acc[nt][r] + b1v + x0[r] * e0 + x1[r] * e1 + x2[r] * e2;
      H1s[(m0 + q * 4 + r) * 136 + n] = f2bf(fmaxf(v, 0.f));
    }
  }
  __syncthreads();   // all waves done with A + H1s ready
  f32x4 acc2[8];
#pragma unroll
  for (int i = 0; i < 8; i++) acc2[i] = zero;
  const unsigned short* Hrow = &H1s[(m0 + l15) * 136 + q * 8];
#pragma unroll
  for (int ks = 0; ks < 4; ks++) {
    short8 af = *(const short8*)(Hrow + ks * 32);
#pragma unroll
    for (int nt = 0; nt < 8; nt++) {
      short8 bfr = *(const short8*)(Pp2 + ((nt * 4 + ks) * 64 + lane) * 8);
      acc2[nt] = __builtin_amdgcn_mfma_f32_16x16x32_bf16(af, bfr, acc2[nt], 0, 0, 0);
    }
  }
#pragma unroll
  for (int nt = 0; nt < 8; nt++) {
    int n = nt * 16 + l15;
    float b2v = b2[n];
#pragma unroll
    for (int r = 0; r < 4; r++) {
      Mf[(m0 + q * 4 + r) * 132 + n] = acc2[nt][r] + b2v;
    }
  }
  __syncthreads();
  int c = tid & 127, half = tid >> 7;
  int r0 = half * 32;
  float accv = 0.f;
  int cur = tgt[r0];
  for (int r = r0; r < r0 + 32; r++) {
    int tg = tgt[r];
    if (tg != cur) { atomicAdd(&agg[cur * 128 + c], accv); accv = 0.f; cur = tg; }
    accv += Mf[r * 132 + c];
  }
  atomicAdd(&agg[cur * 128 + c], accv);
}

// ---------------- z = h@selfW + selfb + agg, LayerNorm, pooling contribs ----------------
__global__ __launch_bounds__(128) void selfln_kernel(const float* __restrict__ hf,
                                                     const float* __restrict__ agg,
                                                     const float* __restrict__ sW,
                                                     const float* __restrict__ sb,
                                                     const float* __restrict__ lng,
                                                     const float* __restrict__ lnb,
                                                     float* __restrict__ ws,
                                                     float* __restrict__ out) {
  __shared__ float hrow[128];
  __shared__ float red[128];
  int n = blockIdx.x, t = threadIdx.x;
  hrow[t] = hf[n * 128 + t];
  __syncthreads();
  float acc = sb[t] + agg[n * 128 + t];
  for (int k = 0; k < 128; k++) acc += hrow[k] * sW[k * 128 + t];
  red[t] = acc; __syncthreads();
  for (int s = 64; s > 0; s >>= 1) { if (t < s) red[t] += red[t + s]; __syncthreads(); }
  float mu = red[0] * (1.f / 128.f);
  __syncthreads();
  float dv = acc - mu;
  red[t] = dv * dv; __syncthreads();
  for (int s = 64; s > 0; s >>= 1) { if (t < s) red[t] += red[t + s]; __syncthreads(); }
  float var = red[0] * (1.f / 128.f);
  float o = dv * rsqrtf(var + 1e-5f) * lng[t] + lnb[t];
  out[n * 128 + t] = o;
  atomicAdd(&ws[OFF_PSUM + t], o);
  int enc = __float_as_int(o);
  enc = enc >= 0 ? enc : (enc ^ 0x7fffffff);
  atomicMax(&((int*)ws)[OFF_PMAX + t], enc);
  if (t == 0) out[N_NODES * HDIM + HDIM + n] = 1.0f;   // block_mask = True
}

// ---------------- graph embedding ----------------
__global__ __launch_bounds__(128) void graph_kernel(const float* __restrict__ ws,
                                                    const float* __restrict__ W1,
                                                    const float* __restrict__ b1,
                                                    const float* __restrict__ W2,
                                                    const float* __restrict__ b2,
                                                    float* __restrict__ out) {
  __shared__ float pooled[256];
  __shared__ float g1[128];
  int t = threadIdx.x;
  pooled[t] = ws[OFF_PSUM + t] * (1.f / (float)N_NODES);
  int e = ((const int*)ws)[OFF_PMAX + t];
  int bits = e >= 0 ? e : (e ^ 0x7fffffff);
  pooled[128 + t] = __int_as_float(bits);
  __syncthreads();
  float acc = b1[t];
  for (int k = 0; k < 256; k++) acc += pooled[k] * W1[k * 128 + t];
  g1[t] = fmaxf(acc, 0.f);
  __syncthreads();
  float a2 = b2[t];
  for (int k = 0; k < 128; k++) a2 += g1[k] * W2[k * 128 + t];
  out[N_NODES * HDIM + t] = a2;
}

extern "C" void kernel_launch(void* const* d_in, const int* in_sizes, int n_in,
                              void* d_out, int out_size, void* d_ws, size_t ws_size,
                              hipStream_t stream) {
  const float* bfeat = (const float*)d_in[0];
  const int*   rid   = (const int*)d_in[1];
  const int*   bsrc  = (const int*)d_in[2];
  const int*   bdst  = (const int*)d_in[3];
  const float* bw    = (const float*)d_in[4];
  const int*   ppin  = (const int*)d_in[5];
  const int*   pblk  = (const int*)d_in[6];
  const float* pw    = (const float*)d_in[7];
  const float* pins  = (const float*)d_in[8];
  const float* area  = (const float*)d_in[9];
  const float* remb  = (const float*)d_in[10];
  const float* iemb  = (const float*)d_in[11];
  const float* inW1  = (const float*)d_in[12];
  const float* inb1  = (const float*)d_in[13];
  const float* inW2  = (const float*)d_in[14];
  const float* inb2  = (const float*)d_in[15];
  const float* bW1   = (const float*)d_in[16];
  const float* bb1   = (const float*)d_in[17];
  const float* bW2   = (const float*)d_in[18];
  const float* bb2   = (const float*)d_in[19];
  const float* pW1   = (const float*)d_in[20];
  const float* pb1   = (const float*)d_in[21];
  const float* pW2   = (const float*)d_in[22];
  const float* pb2   = (const float*)d_in[23];
  const float* sW    = (const float*)d_in[24];
  const float* sb    = (const float*)d_in[25];
  const float* lng   = (const float*)d_in[26];
  const float* lnb   = (const float*)d_in[27];
  const float* gW1   = (const float*)d_in[28];
  const float* gb1   = (const float*)d_in[29];
  const float* gW2   = (const float*)d_in[30];
  const float* gb2   = (const float*)d_in[31];

  float* ws  = (float*)d_ws;
  float* out = (float*)d_out;
  float* agg = ws + OFF_AGG;
  float* hf  = ws + OFF_H;
  unsigned short* hb  = (unsigned short*)(ws + OFF_HB);
  unsigned short* Bp1 = (unsigned short*)(ws + OFF_BP1);
  unsigned short* Bp2 = (unsigned short*)(ws + OFF_BP2);
  unsigned short* Pp1 = (unsigned short*)(ws + OFF_PP1);
  unsigned short* Pp2 = (unsigned short*)(ws + OFF_PP2);
  const float* blast  = ws + OFF_BLAST;
  const float* pextra = ws + OFF_PEXTRA;
  int* cntB   = (int*)ws + OFF_CNTB;
  int* startB = (int*)ws + OFF_STARTB;
  int* cntP   = (int*)ws + OFF_CNTP;
  int* startP = (int*)ws + OFF_STARTP;
  int* sortedB = (int*)ws + OFF_SRTB;
  int* sortedP = (int*)ws + OFF_SRTP;

  // zero scalars + psum + pmax + agg, and sort counters
  hipMemsetAsync(d_ws, 0, (size_t)OFF_H * sizeof(float), stream);
  hipMemsetAsync((void*)cntB, 0, 4 * 4096 * sizeof(int), stream);
  reduce_kernel<<<97, 256, 0, stream>>>(bw, pw, area, ws);
  hist_kernel<<<(NMSG_B2B + E2 + 255) / 256, 256, 0, stream>>>(bsrc, bdst, pblk, cntB, cntP);
  scan_kernel<<<2, 1024, 0, stream>>>(ws);
  scatter_kernel<<<(NMSG_B2B + E2 + 255) / 256, 256, 0, stream>>>(bsrc, bdst, pblk,
                                                                  startB, startP, sortedB, sortedP);
  prep_kernel<<<128, 256, 0, stream>>>(bW1, bW2, pW1, pW2, ws);
  input_mlp_kernel<<<N_NODES / 8, 128, 0, stream>>>(bfeat, rid, remb, iemb,
                                                    inW1, inb1, inW2, inb2, hf, hb);
  b2b_kernel<<<NMSG_B2B / 64, 256, 0, stream>>>(hb, bsrc, bdst, bw, ws, sortedB, Bp1, Bp2,
                                                bb1, bb2, blast, agg);
  p2b_kernel<<<E2 / 64, 256, 0, stream>>>(hb, pblk, ppin, pw, pins, ws, sortedP, Pp1, Pp2,
                                          pb1, pb2, pextra, agg);
  selfln_kernel<<<N_NODES, 128, 0, stream>>>(hf, agg, sW, sb, lng, lnb, ws, out);
  graph_kernel<<<1, 128, 0, stream>>>(ws, gW1, gb1, gW2, gb2, out);
}

// Round 3
// 322.832 us; speedup vs baseline: 2.0234x; 1.4016x over previous
//
#include <hip/hip_runtime.h>
#include <hip/hip_bf16.h>

#define N_NODES 4096
#define HDIM    128
#define E1      131072
#define E2      131072
#define NMSG_B2B (2 * E1)

// ---- workspace layout (float units) ----
#define OFF_PSUM   4
#define OFF_PMAX   132
#define OFF_AGG    260
#define OFF_H      (OFF_AGG + N_NODES * HDIM)       // (unused f32 h slot, keeps layout)
#define OFF_HB     (OFF_H + N_NODES * HDIM)         // h bf16 (ushort)
#define OFF_BP1    (OFF_HB + N_NODES * HDIM / 2)    // b2b W1 pack (32768 ushort)
#define OFF_BP2    (OFF_BP1 + 16384)                // b2b W2 pack (16384 ushort)
#define OFF_PP1    (OFF_BP2 + 8192)                 // p2b W1 pack (16384 ushort)
#define OFF_PP2    (OFF_PP1 + 8192)                 // p2b W2 pack (16384 ushort)
#define OFF_SP     (OFF_PP2 + 8192)                 // self_W pack (16384 ushort)
#define OFF_BLAST  (OFF_SP + 8192)                  // b2b W1 row 256, f32[128]
#define OFF_PEXTRA (OFF_BLAST + 128)                // p2b W1 rows 128..130, f32[384]
#define OFF_CNTB   (OFF_PEXTRA + 384)               // int[4096]
#define OFF_STARTB (OFF_CNTB + 4096)                // int[4096]
#define OFF_CNTP   (OFF_STARTB + 4096)              // int[4096]
#define OFF_STARTP (OFF_CNTP + 4096)                // int[4096]
#define OFF_SRTB   (OFF_STARTP + 4096)              // int[262144] sorted b2b msg ids
#define OFF_SRTP   (OFF_SRTB + NMSG_B2B)            // int[131072] sorted p2b edge ids
#define WS_FLOATS  (OFF_SRTP + E2)

typedef short short8 __attribute__((ext_vector_type(8)));
typedef float f32x4 __attribute__((ext_vector_type(4)));

__device__ __forceinline__ unsigned short f2bf(float f) {
  union { float f; unsigned u; } v; v.f = f;
  unsigned r = v.u + 0x7fffu + ((v.u >> 16) & 1u);   // RNE
  return (unsigned short)(r >> 16);
}

// ---------------- reductions + pmax init ----------------
__global__ __launch_bounds__(256) void reduce_kernel(const float* __restrict__ b2bw,
                                                     const float* __restrict__ p2bw,
                                                     const float* __restrict__ area,
                                                     float* __restrict__ ws) {
  __shared__ float red[256];
  int b = blockIdx.x, t = threadIdx.x;
  if (b < 32) {
    float m = 0.f;
    for (int i = b * 256 + t; i < E1; i += 32 * 256) m = fmaxf(m, fabsf(b2bw[i]));
    red[t] = m; __syncthreads();
    for (int s = 128; s > 0; s >>= 1) { if (t < s) red[t] = fmaxf(red[t], red[t + s]); __syncthreads(); }
    if (t == 0) atomicMax((unsigned*)&ws[0], __float_as_uint(red[0]));
  } else if (b < 64) {
    float m = 0.f;
    for (int i = (b - 32) * 256 + t; i < E2; i += 32 * 256) m = fmaxf(m, fabsf(p2bw[i]));
    red[t] = m; __syncthreads();
    for (int s = 128; s > 0; s >>= 1) { if (t < s) red[t] = fmaxf(red[t], red[t + s]); __syncthreads(); }
    if (t == 0) atomicMax((unsigned*)&ws[1], __float_as_uint(red[0]));
  } else if (b < 96) {
    float s0 = 0.f;
    for (int i = (b - 64) * 256 + t; i < N_NODES; i += 32 * 256) s0 += area[i];
    red[t] = s0; __syncthreads();
    for (int s = 128; s > 0; s >>= 1) { if (t < s) red[t] += red[t + s]; __syncthreads(); }
    if (t == 0) atomicAdd(&ws[2], red[0]);
  } else {
    if (t < HDIM) ((int*)ws)[OFF_PMAX + t] = 0x80000000;   // -inf encoded
  }
}

// ---------------- counting sort: histogram / scan / scatter ----------------
__global__ __launch_bounds__(256) void hist_kernel(const int* __restrict__ src,
                                                   const int* __restrict__ dst,
                                                   const int* __restrict__ pblk,
                                                   int* __restrict__ cntB,
                                                   int* __restrict__ cntP) {
  int i = blockIdx.x * 256 + threadIdx.x;
  if (i < NMSG_B2B) {
    int e = i >> 1;
    int t = (i & 1) ? dst[e] : src[e];
    atomicAdd(&cntB[t], 1);
  } else if (i < NMSG_B2B + E2) {
    atomicAdd(&cntP[pblk[i - NMSG_B2B]], 1);
  }
}

__global__ __launch_bounds__(1024) void scan_kernel(float* __restrict__ ws) {
  const int* cnt = (const int*)ws + (blockIdx.x == 0 ? OFF_CNTB : OFF_CNTP);
  int* start     = (int*)ws + (blockIdx.x == 0 ? OFF_STARTB : OFF_STARTP);
  __shared__ int s[1024];
  int t = threadIdx.x;
  int base = t * 4;
  int a0 = cnt[base], a1 = cnt[base + 1], a2 = cnt[base + 2], a3 = cnt[base + 3];
  int sum = a0 + a1 + a2 + a3;
  s[t] = sum; __syncthreads();
  for (int off = 1; off < 1024; off <<= 1) {
    int v = (t >= off) ? s[t - off] : 0;
    __syncthreads();
    s[t] += v;
    __syncthreads();
  }
  int excl = s[t] - sum;
  start[base]     = excl;
  start[base + 1] = excl + a0;
  start[base + 2] = excl + a0 + a1;
  start[base + 3] = excl + a0 + a1 + a2;
}

__global__ __launch_bounds__(256) void scatter_kernel(const int* __restrict__ src,
                                                      const int* __restrict__ dst,
                                                      const int* __restrict__ pblk,
                                                      int* __restrict__ startB,
                                                      int* __restrict__ startP,
                                                      int* __restrict__ sortedB,
                                                      int* __restrict__ sortedP) {
  int i = blockIdx.x * 256 + threadIdx.x;
  if (i < NMSG_B2B) {
    int e = i >> 1;
    int t = (i & 1) ? dst[e] : src[e];
    int pos = atomicAdd(&startB[t], 1);
    sortedB[pos] = i;
  } else if (i < NMSG_B2B + E2) {
    int e = i - NMSG_B2B;
    int t = pblk[e];
    int pos = atomicAdd(&startP[t], 1);
    sortedP[pos] = e;
  }
}

// ---------------- pack weights into MFMA B-fragment order ----------------
// B-frag (16x16x32): lane holds B[k = (lane>>4)*8 + j][n = lane&15], j=0..7, 16B contiguous.
__global__ __launch_bounds__(256) void prep_kernel(const float* __restrict__ bW1,
                                                   const float* __restrict__ bW2,
                                                   const float* __restrict__ pW1,
                                                   const float* __restrict__ pW2,
                                                   const float* __restrict__ sWm,
                                                   float* __restrict__ ws) {
  unsigned short* Bp1 = (unsigned short*)(ws + OFF_BP1);
  unsigned short* Bp2 = (unsigned short*)(ws + OFF_BP2);
  unsigned short* Pp1 = (unsigned short*)(ws + OFF_PP1);
  unsigned short* Pp2 = (unsigned short*)(ws + OFF_PP2);
  unsigned short* Sp  = (unsigned short*)(ws + OFF_SP);
  float* blast = ws + OFF_BLAST;
  float* pextra = ws + OFF_PEXTRA;
  const int total = 32768 + 4 * 16384 + 128 + 384;
  for (int t = blockIdx.x * 256 + threadIdx.x; t < total; t += gridDim.x * 256) {
    if (t < 32768) {                       // b2b W1: 8 ntiles x 8 ksteps
      int j = t & 7, lane = (t >> 3) & 63, ks = (t >> 9) & 7, nt = t >> 12;
      int n = nt * 16 + (lane & 15), k = ks * 32 + (lane >> 4) * 8 + j;
      Bp1[t] = f2bf(bW1[k * 128 + n]);
    } else if (t < 49152) {                // b2b W2: 8 x 4
      int u = t - 32768;
      int j = u & 7, lane = (u >> 3) & 63, ks = (u >> 9) & 3, nt = u >> 11;
      int n = nt * 16 + (lane & 15), k = ks * 32 + (lane >> 4) * 8 + j;
      Bp2[u] = f2bf(bW2[k * 128 + n]);
    } else if (t < 65536) {                // p2b W1 rows 0..127
      int u = t - 49152;
      int j = u & 7, lane = (u >> 3) & 63, ks = (u >> 9) & 3, nt = u >> 11;
      int n = nt * 16 + (lane & 15), k = ks * 32 + (lane >> 4) * 8 + j;
      Pp1[u] = f2bf(pW1[k * 128 + n]);
    } else if (t < 81920) {                // p2b W2
      int u = t - 65536;
      int j = u & 7, lane = (u >> 3) & 63, ks = (u >> 9) & 3, nt = u >> 11;
      int n = nt * 16 + (lane & 15), k = ks * 32 + (lane >> 4) * 8 + j;
      Pp2[u] = f2bf(pW2[k * 128 + n]);
    } else if (t < 98304) {                // self_W
      int u = t - 81920;
      int j = u & 7, lane = (u >> 3) & 63, ks = (u >> 9) & 3, nt = u >> 11;
      int n = nt * 16 + (lane & 15), k = ks * 32 + (lane >> 4) * 8 + j;
      Sp[u] = f2bf(sWm[k * 128 + n]);
    } else if (t < 98432) {
      int u = t - 98304;
      blast[u] = bW1[256 * 128 + u];
    } else {
      int u = t - 98432;
      int r = u >> 7, n = u & 127;
      pextra[u] = pW1[(128 + r) * 128 + n];
    }
  }
}

// ---------------- input MLP ----------------
__global__ __launch_bounds__(128) void input_mlp_kernel(const float* __restrict__ bfeat,
                                                        const int* __restrict__ rid,
                                                        const float* __restrict__ remb,
                                                        const float* __restrict__ iemb,
                                                        const float* __restrict__ W1,
                                                        const float* __restrict__ b1,
                                                        const float* __restrict__ W2,
                                                        const float* __restrict__ b2,
                                                        unsigned short* __restrict__ hb) {
  __shared__ __attribute__((aligned(16))) float x[8][40];
  __shared__ __attribute__((aligned(16))) float h1[8][128];
  int t = threadIdx.x;
  int n0 = blockIdx.x * 8;
  for (int idx = t; idx < 8 * 40; idx += 128) {
    int nb = idx / 40, f = idx - nb * 40;
    int n = n0 + nb;
    float v;
    if (f < 16)      v = bfeat[n * 16 + f];
    else if (f < 32) v = remb[rid[n] * 16 + (f - 16)];
    else             v = iemb[(n & 1023) * 8 + (f - 32)];
    x[nb][f] = v;
  }
  __syncthreads();
  float acc[8];
  float bb = b1[t];
#pragma unroll
  for (int nb = 0; nb < 8; nb++) acc[nb] = bb;
  for (int k = 0; k < 40; k++) {
    float wv = W1[k * 128 + t];
#pragma unroll
    for (int nb = 0; nb < 8; nb++) acc[nb] += x[nb][k] * wv;
  }
#pragma unroll
  for (int nb = 0; nb < 8; nb++) h1[nb][t] = fmaxf(acc[nb], 0.f);
  __syncthreads();
  float bb2 = b2[t];
#pragma unroll
  for (int nb = 0; nb < 8; nb++) acc[nb] = bb2;
  for (int k = 0; k < 128; k++) {
    float wv = W2[k * 128 + t];
#pragma unroll
    for (int nb = 0; nb < 8; nb++) acc[nb] += h1[nb][k] * wv;
  }
#pragma unroll
  for (int nb = 0; nb < 8; nb++) {
    float v = fmaxf(acc[nb], 0.f);
    int n = n0 + nb;
    hb[n * 128 + t] = f2bf(v);
  }
}

// ---------------- b2b edge kernel: 64 sorted messages/block, MFMA + segmented reduce ----------------
__global__ __launch_bounds__(256) void b2b_kernel(const unsigned short* __restrict__ hb,
                                                  const int* __restrict__ src,
                                                  const int* __restrict__ dst,
                                                  const float* __restrict__ w,
                                                  const float* __restrict__ wsf,
                                                  const int* __restrict__ sortedB,
                                                  const unsigned short* __restrict__ Bp1,
                                                  const unsigned short* __restrict__ Bp2,
                                                  const float* __restrict__ b1,
                                                  const float* __restrict__ b2,
                                                  const float* __restrict__ w1last,
                                                  float* __restrict__ agg) {
  __shared__ __attribute__((aligned(16))) unsigned short A[64 * 264];    // reused as float M[64*132]
  __shared__ __attribute__((aligned(16))) unsigned short H1s[64 * 136];
  __shared__ float wsc[64];
  __shared__ int tgt[64];
  __shared__ int oth[64];
  float* Mf = (float*)A;
  int tid = threadIdx.x;
  int base = blockIdx.x * 64;
  float invb = 1.f / fmaxf(__uint_as_float(((const unsigned*)wsf)[0]), 1.f);
  if (tid < 64) {
    int g = sortedB[base + tid];
    int e = g >> 1, d = g & 1;
    int s = src[e], dd = dst[e];
    tgt[tid] = d ? dd : s;      // message target (i)
    oth[tid] = d ? s : dd;      // other endpoint (j)
    wsc[tid] = w[e] * invb;
  }
  __syncthreads();
  // gather A: msg m = [h[i] | h[j]]
  for (int c = tid; c < 2048; c += 256) {
    int m = c >> 5, cc = c & 31;
    int half = cc >> 4, o = (cc & 15) * 8;
    int node = half ? oth[m] : tgt[m];
    uint4 v = *(const uint4*)(hb + node * 128 + o);
    *(uint4*)(&A[m * 264 + half * 128 + o]) = v;
  }
  __syncthreads();
  int lane = tid & 63, wv = tid >> 6;
  int l15 = lane & 15, q = lane >> 4;
  int m0 = wv * 16;
  f32x4 zero = {0.f, 0.f, 0.f, 0.f};
  f32x4 acc[8];
#pragma unroll
  for (int i = 0; i < 8; i++) acc[i] = zero;
  const unsigned short* Arow = &A[(m0 + l15) * 264 + q * 8];
#pragma unroll
  for (int ks = 0; ks < 8; ks++) {
    short8 af = *(const short8*)(Arow + ks * 32);
#pragma unroll
    for (int nt = 0; nt < 8; nt++) {
      short8 bfr = *(const short8*)(Bp1 + ((nt * 8 + ks) * 64 + lane) * 8);
      acc[nt] = __builtin_amdgcn_mfma_f32_16x16x32_bf16(af, bfr, acc[nt], 0, 0, 0);
    }
  }
  float wr[4];
#pragma unroll
  for (int r = 0; r < 4; r++) wr[r] = wsc[m0 + q * 4 + r];
#pragma unroll
  for (int nt = 0; nt < 8; nt++) {
    int n = nt * 16 + l15;
    float b1v = b1[n], wlv = w1last[n];
#pragma unroll
    for (int r = 0; r < 4; r++) {
      float v = acc[nt][r] + b1v + wr[r] * wlv;
      H1s[(m0 + q * 4 + r) * 136 + n] = f2bf(fmaxf(v, 0.f));
    }
  }
  __syncthreads();   // all waves done with A + H1s ready
  f32x4 acc2[8];
#pragma unroll
  for (int i = 0; i < 8; i++) acc2[i] = zero;
  const unsigned short* Hrow = &H1s[(m0 + l15) * 136 + q * 8];
#pragma unroll
  for (int ks = 0; ks < 4; ks++) {
    short8 af = *(const short8*)(Hrow + ks * 32);
#pragma unroll
    for (int nt = 0; nt < 8; nt++) {
      short8 bfr = *(const short8*)(Bp2 + ((nt * 4 + ks) * 64 + lane) * 8);
      acc2[nt] = __builtin_amdgcn_mfma_f32_16x16x32_bf16(af, bfr, acc2[nt], 0, 0, 0);
    }
  }
  // write full messages (incl. bias) to LDS (A's storage, now free)
#pragma unroll
  for (int nt = 0; nt < 8; nt++) {
    int n = nt * 16 + l15;
    float b2v = b2[n];
#pragma unroll
    for (int r = 0; r < 4; r++) {
      Mf[(m0 + q * 4 + r) * 132 + n] = acc2[nt][r] + b2v;
    }
  }
  __syncthreads();
  // segmented reduce over the 64 sorted messages; one atomic row per segment
  int c = tid & 127, half = tid >> 7;
  int r0 = half * 32;
  float accv = 0.f;
  int cur = tgt[r0];
  for (int r = r0; r < r0 + 32; r++) {
    int tg = tgt[r];
    if (tg != cur) { atomicAdd(&agg[cur * 128 + c], accv); accv = 0.f; cur = tg; }
    accv += Mf[r * 132 + c];
  }
  atomicAdd(&agg[cur * 128 + c], accv);
}

// ---------------- p2b edge kernel ----------------
__global__ __launch_bounds__(256) void p2b_kernel(const unsigned short* __restrict__ hb,
                                                  const int* __restrict__ pblk,
                                                  const int* __restrict__ ppin,
                                                  const float* __restrict__ pw,
                                                  const float* __restrict__ pins,
                                                  const float* __restrict__ wsf,
                                                  const int* __restrict__ sortedP,
                                                  const unsigned short* __restrict__ Pp1,
                                                  const unsigned short* __restrict__ Pp2,
                                                  const float* __restrict__ b1,
                                                  const float* __restrict__ b2,
                                                  const float* __restrict__ wextra,
                                                  float* __restrict__ agg) {
  __shared__ __attribute__((aligned(16))) float Mf[64 * 132];            // also holds A (bf16)
  __shared__ __attribute__((aligned(16))) unsigned short H1s[64 * 136];
  __shared__ float pf0[64], pf1[64], pf2[64];
  __shared__ int tgt[64];
  unsigned short* A = (unsigned short*)Mf;   // 64*136 ushort fits in 64*132 float
  int tid = threadIdx.x;
  int base = blockIdx.x * 64;
  float invp = 1.f / fmaxf(__uint_as_float(((const unsigned*)wsf)[1]), 1.f);
  float as = wsf[2];
  float cs = fmaxf(sqrtf(fmaxf(as, 1e-6f)), 1e-6f);
  float invc = 1.f / cs;
  if (tid < 64) {
    int e = sortedP[base + tid];
    int pin = ppin[e];
    pf0[tid] = pins[pin * 2] * invc;
    pf1[tid] = pins[pin * 2 + 1] * invc;
    pf2[tid] = pw[e] * invp;
    tgt[tid] = pblk[e];
  }
  __syncthreads();
  for (int c = tid; c < 1024; c += 256) {
    int m = c >> 4, o = (c & 15) * 8;
    int node = tgt[m];
    *(uint4*)(&A[m * 136 + o]) = *(const uint4*)(hb + node * 128 + o);
  }
  __syncthreads();
  int lane = tid & 63, wvi = tid >> 6;
  int l15 = lane & 15, q = lane >> 4;
  int m0 = wvi * 16;
  f32x4 zero = {0.f, 0.f, 0.f, 0.f};
  f32x4 acc[8];
#pragma unroll
  for (int i = 0; i < 8; i++) acc[i] = zero;
  const unsigned short* Arow = &A[(m0 + l15) * 136 + q * 8];
#pragma unroll
  for (int ks = 0; ks < 4; ks++) {
    short8 af = *(const short8*)(Arow + ks * 32);
#pragma unroll
    for (int nt = 0; nt < 8; nt++) {
      short8 bfr = *(const short8*)(Pp1 + ((nt * 4 + ks) * 64 + lane) * 8);
      acc[nt] = __builtin_amdgcn_mfma_f32_16x16x32_bf16(af, bfr, acc[nt], 0, 0, 0);
    }
  }
  float x0[4], x1[4], x2[4];
#pragma unroll
  for (int r = 0; r < 4; r++) {
    int m = m0 + q * 4 + r;
    x0[r] = pf0[m]; x1[r] = pf1[m]; x2[r] = pf2[m];
  }
#pragma unroll
  for (int nt = 0; nt < 8; nt++) {
    int n = nt * 16 + l15;
    float b1v = b1[n];
    float e0 = wextra[n], e1 = wextra[128 + n], e2 = wextra[256 + n];
#pragma unroll
    for (int r = 0; r < 4; r++) {
      float v = acc[nt][r] + b1v + x0[r] * e0 + x1[r] * e1 + x2[r] * e2;
      H1s[(m0 + q * 4 + r) * 136 + n] = f2bf(fmaxf(v, 0.f));
    }
  }
  __syncthreads();   // all waves done with A + H1s ready
  f32x4 acc2[8];
#pragma unroll
  for (int i = 0; i < 8; i++) acc2[i] = zero;
  const unsigned short* Hrow = &H1s[(m0 + l15) * 136 + q * 8];
#pragma unroll
  for (int ks = 0; ks < 4; ks++) {
    short8 af = *(const short8*)(Hrow + ks * 32);
#pragma unroll
    for (int nt = 0; nt < 8; nt++) {
      short8 bfr = *(const short8*)(Pp2 + ((nt * 4 + ks) * 64 + lane) * 8);
      acc2[nt] = __builtin_amdgcn_mfma_f32_16x16x32_bf16(af, bfr, acc2[nt], 0, 0, 0);
    }
  }
#pragma unroll
  for (int nt = 0; nt < 8; nt++) {
    int n = nt * 16 + l15;
    float b2v = b2[n];
#pragma unroll
    for (int r = 0; r < 4; r++) {
      Mf[(m0 + q * 4 + r) * 132 + n] = acc2[nt][r] + b2v;
    }
  }
  __syncthreads();
  int c = tid & 127, half = tid >> 7;
  int r0 = half * 32;
  float accv = 0.f;
  int cur = tgt[r0];
  for (int r = r0; r < r0 + 32; r++) {
    int tg = tgt[r];
    if (tg != cur) { atomicAdd(&agg[cur * 128 + c], accv); accv = 0.f; cur = tg; }
    accv += Mf[r * 132 + c];
  }
  atomicAdd(&agg[cur * 128 + c], accv);
}

// ---------------- selfln v2: 64 nodes/block, MFMA z=h@selfW, fused LN + pooling ----------------
__global__ __launch_bounds__(256) void selfln_kernel(const unsigned short* __restrict__ hb,
                                                     const float* __restrict__ agg,
                                                     const unsigned short* __restrict__ Sp,
                                                     const float* __restrict__ sb,
                                                     const float* __restrict__ lng,
                                                     const float* __restrict__ lnb,
                                                     float* __restrict__ ws,
                                                     float* __restrict__ out) {
  __shared__ __attribute__((aligned(16))) float zs[64 * 133];   // also A overlay (bf16, stride 136)
  __shared__ float muS[64], rsg[64];
  __shared__ float partS[64][4], partQ[64][4];
  __shared__ float psumL[2][128];
  __shared__ int   pmaxL[2][128];
  unsigned short* A = (unsigned short*)zs;   // 64*136 ushort = 4352 floats < 64*133
  int tid = threadIdx.x;
  int n0 = blockIdx.x * 64;
  for (int c = tid; c < 1024; c += 256) {
    int m = c >> 4, o = (c & 15) * 8;
    *(uint4*)(&A[m * 136 + o]) = *(const uint4*)(hb + (n0 + m) * 128 + o);
  }
  __syncthreads();
  int lane = tid & 63, wv = tid >> 6;
  int l15 = lane & 15, q = lane >> 4;
  int m0 = wv * 16;
  f32x4 zero = {0.f, 0.f, 0.f, 0.f};
  f32x4 acc[8];
#pragma unroll
  for (int i = 0; i < 8; i++) acc[i] = zero;
  const unsigned short* Arow = &A[(m0 + l15) * 136 + q * 8];
#pragma unroll
  for (int ks = 0; ks < 4; ks++) {
    short8 af = *(const short8*)(Arow + ks * 32);
#pragma unroll
    for (int nt = 0; nt < 8; nt++) {
      short8 bfr = *(const short8*)(Sp + ((nt * 4 + ks) * 64 + lane) * 8);
      acc[nt] = __builtin_amdgcn_mfma_f32_16x16x32_bf16(af, bfr, acc[nt], 0, 0, 0);
    }
  }
  __syncthreads();   // all waves finished reading A; zs can be overwritten
#pragma unroll
  for (int nt = 0; nt < 8; nt++) {
    int n = nt * 16 + l15;
    float sbv = sb[n];
#pragma unroll
    for (int r = 0; r < 4; r++) {
      int row = m0 + q * 4 + r;
      zs[row * 133 + n] = acc[nt][r] + sbv + agg[(n0 + row) * 128 + n];
    }
  }
  __syncthreads();
  {
    int r = tid & 63, g = tid >> 6;
    const float* zr = &zs[r * 133 + g * 32];
    float s = 0.f, s2 = 0.f;
#pragma unroll
    for (int i = 0; i < 32; i++) { float v = zr[i]; s += v; s2 += v * v; }
    partS[r][g] = s; partQ[r][g] = s2;
  }
  __syncthreads();
  if (tid < 64) {
    int r = tid;
    float s  = partS[r][0] + partS[r][1] + partS[r][2] + partS[r][3];
    float s2 = partQ[r][0] + partQ[r][1] + partQ[r][2] + partQ[r][3];
    float m = s * (1.f / 128.f);
    float var = s2 * (1.f / 128.f) - m * m;
    muS[r] = m;
    rsg[r] = rsqrtf(fmaxf(var, 0.f) + 1e-5f);
  }
  __syncthreads();
  {
    int c = tid & 127, half = tid >> 7;
    float g = lng[c], b = lnb[c];
    float ls = 0.f; int lm = 0x80000000;
    for (int r = half * 32; r < half * 32 + 32; r++) {
      float v = (zs[r * 133 + c] - muS[r]) * rsg[r] * g + b;
      out[(n0 + r) * 128 + c] = v;
      ls += v;
      int e = __float_as_int(v);
      e = e >= 0 ? e : (e ^ 0x7fffffff);
      lm = max(lm, e);
    }
    psumL[half][c] = ls; pmaxL[half][c] = lm;
  }
  __syncthreads();
  if (tid < 128) {
    atomicAdd(&ws[OFF_PSUM + tid], psumL[0][tid] + psumL[1][tid]);
    atomicMax(&((int*)ws)[OFF_PMAX + tid], max(pmaxL[0][tid], pmaxL[1][tid]));
  }
  if (tid < 64) out[N_NODES * HDIM + HDIM + n0 + tid] = 1.0f;   // block_mask
}

// ---------------- graph embedding ----------------
__global__ __launch_bounds__(128) void graph_kernel(const float* __restrict__ ws,
                                                    const float* __restrict__ W1,
                                                    const float* __restrict__ b1,
                                                    const float* __restrict__ W2,
                                                    const float* __restrict__ b2,
                                                    float* __restrict__ out) {
  __shared__ float pooled[256];
  __shared__ float g1[128];
  int t = threadIdx.x;
  pooled[t] = ws[OFF_PSUM + t] * (1.f / (float)N_NODES);
  int e = ((const int*)ws)[OFF_PMAX + t];
  int bits = e >= 0 ? e : (e ^ 0x7fffffff);
  pooled[128 + t] = __int_as_float(bits);
  __syncthreads();
  float acc = b1[t];
  for (int k = 0; k < 256; k++) acc += pooled[k] * W1[k * 128 + t];
  g1[t] = fmaxf(acc, 0.f);
  __syncthreads();
  float a2 = b2[t];
  for (int k = 0; k < 128; k++) a2 += g1[k] * W2[k * 128 + t];
  out[N_NODES * HDIM + t] = a2;
}

extern "C" void kernel_launch(void* const* d_in, const int* in_sizes, int n_in,
                              void* d_out, int out_size, void* d_ws, size_t ws_size,
                              hipStream_t stream) {
  const float* bfeat = (const float*)d_in[0];
  const int*   rid   = (const int*)d_in[1];
  const int*   bsrc  = (const int*)d_in[2];
  const int*   bdst  = (const int*)d_in[3];
  const float* bw    = (const float*)d_in[4];
  const int*   ppin  = (const int*)d_in[5];
  const int*   pblk  = (const int*)d_in[6];
  const float* pw    = (const float*)d_in[7];
  const float* pins  = (const float*)d_in[8];
  const float* area  = (const float*)d_in[9];
  const float* remb  = (const float*)d_in[10];
  const float* iemb  = (const float*)d_in[11];
  const float* inW1  = (const float*)d_in[12];
  const float* inb1  = (const float*)d_in[13];
  const float* inW2  = (const float*)d_in[14];
  const float* inb2  = (const float*)d_in[15];
  const float* bW1   = (const float*)d_in[16];
  const float* bb1   = (const float*)d_in[17];
  const float* bW2   = (const float*)d_in[18];
  const float* bb2   = (const float*)d_in[19];
  const float* pW1   = (const float*)d_in[20];
  const float* pb1   = (const float*)d_in[21];
  const float* pW2   = (const float*)d_in[22];
  const float* pb2   = (const float*)d_in[23];
  const float* sW    = (const float*)d_in[24];
  const float* sb    = (const float*)d_in[25];
  const float* lng   = (const float*)d_in[26];
  const float* lnb   = (const float*)d_in[27];
  const float* gW1   = (const float*)d_in[28];
  const float* gb1   = (const float*)d_in[29];
  const float* gW2   = (const float*)d_in[30];
  const float* gb2   = (const float*)d_in[31];

  float* ws  = (float*)d_ws;
  float* out = (float*)d_out;
  float* agg = ws + OFF_AGG;
  unsigned short* hb  = (unsigned short*)(ws + OFF_HB);
  unsigned short* Bp1 = (unsigned short*)(ws + OFF_BP1);
  unsigned short* Bp2 = (unsigned short*)(ws + OFF_BP2);
  unsigned short* Pp1 = (unsigned short*)(ws + OFF_PP1);
  unsigned short* Pp2 = (unsigned short*)(ws + OFF_PP2);
  unsigned short* Sp  = (unsigned short*)(ws + OFF_SP);
  const float* blast  = ws + OFF_BLAST;
  const float* pextra = ws + OFF_PEXTRA;
  int* cntB   = (int*)ws + OFF_CNTB;
  int* startB = (int*)ws + OFF_STARTB;
  int* cntP   = (int*)ws + OFF_CNTP;
  int* startP = (int*)ws + OFF_STARTP;
  int* sortedB = (int*)ws + OFF_SRTB;
  int* sortedP = (int*)ws + OFF_SRTP;

  // zero scalars + psum + pmax + agg, and sort counters
  hipMemsetAsync(d_ws, 0, (size_t)OFF_H * sizeof(float), stream);
  hipMemsetAsync((void*)cntB, 0, 4 * 4096 * sizeof(int), stream);
  reduce_kernel<<<97, 256, 0, stream>>>(bw, pw, area, ws);
  hist_kernel<<<(NMSG_B2B + E2 + 255) / 256, 256, 0, stream>>>(bsrc, bdst, pblk, cntB, cntP);
  scan_kernel<<<2, 1024, 0, stream>>>(ws);
  scatter_kernel<<<(NMSG_B2B + E2 + 255) / 256, 256, 0, stream>>>(bsrc, bdst, pblk,
                                                                  startB, startP, sortedB, sortedP);
  prep_kernel<<<128, 256, 0, stream>>>(bW1, bW2, pW1, pW2, sW, ws);
  input_mlp_kernel<<<N_NODES / 8, 128, 0, stream>>>(bfeat, rid, remb, iemb,
                                                    inW1, inb1, inW2, inb2, hb);
  b2b_kernel<<<NMSG_B2B / 64, 256, 0, stream>>>(hb, bsrc, bdst, bw, ws, sortedB, Bp1, Bp2,
                                                bb1, bb2, blast, agg);
  p2b_kernel<<<E2 / 64, 256, 0, stream>>>(hb, pblk, ppin, pw, pins, ws, sortedP, Pp1, Pp2,
                                          pb1, pb2, pextra, agg);
  selfln_kernel<<<N_NODES / 64, 256, 0, stream>>>(hb, agg, Sp, sb, lng, lnb, ws, out);
  graph_kernel<<<1, 128, 0, stream>>>(ws, gW1, gb1, gW2, gb2, out);
}

// Round 4
// 288.496 us; speedup vs baseline: 2.2642x; 1.1190x over previous
//
#include <hip/hip_runtime.h>
#include <hip/hip_bf16.h>

#define N_NODES 4096
#define HDIM    128
#define E1      131072
#define E2      131072
#define NMSG_B2B (2 * E1)

// ---- workspace layout (float units) ----
#define OFF_PSUM   4
#define OFF_PMAX   132
#define OFF_AGG    260
#define OFF_HB     (OFF_AGG + N_NODES * HDIM)         // h bf16 (ushort), 262144 fl
#define OFF_P      (OFF_HB + N_NODES * HDIM / 2)      // P f32 [4096][128] (+b2b_b1)
#define OFF_Q      (OFF_P + N_NODES * HDIM)           // Q f32
#define OFF_R      (OFF_Q + N_NODES * HDIM)           // R f32 (+p2b_b1)
#define OFF_CP     (OFF_R + N_NODES * HDIM)           // W1cat pack, 49152 ushort = 24576 fl
#define OFF_BP2    (OFF_CP + 24576)                   // b2b W2 pack (16384 ushort)
#define OFF_PP2    (OFF_BP2 + 8192)                   // p2b W2 pack
#define OFF_SP     (OFF_PP2 + 8192)                   // self_W pack
#define OFF_WLAST  (OFF_SP + 8192)                    // b2b W1 row 256, f32[128]
#define OFF_PEXTRA (OFF_WLAST + 128)                  // p2b W1 rows 128..130, f32[384]
#define OFF_CNTB   (OFF_PEXTRA + 384)                 // int[4096]
#define OFF_STARTB (OFF_CNTB + 4096)
#define OFF_CNTP   (OFF_STARTB + 4096)
#define OFF_STARTP (OFF_CNTP + 4096)
#define OFF_SRTB   (OFF_STARTP + 4096)                // int[262144]
#define OFF_SRTP   (OFF_SRTB + NMSG_B2B)              // int[131072]
#define WS_FLOATS  (OFF_SRTP + E2)

typedef short short8 __attribute__((ext_vector_type(8)));
typedef float f32x4 __attribute__((ext_vector_type(4)));

__device__ __forceinline__ unsigned short f2bf(float f) {
  union { float f; unsigned u; } v; v.f = f;
  unsigned r = v.u + 0x7fffu + ((v.u >> 16) & 1u);   // RNE
  return (unsigned short)(r >> 16);
}

// ---------------- reductions + pmax init ----------------
__global__ __launch_bounds__(256) void reduce_kernel(const float* __restrict__ b2bw,
                                                     const float* __restrict__ p2bw,
                                                     const float* __restrict__ area,
                                                     float* __restrict__ ws) {
  __shared__ float red[256];
  int b = blockIdx.x, t = threadIdx.x;
  if (b < 32) {
    float m = 0.f;
    for (int i = b * 256 + t; i < E1; i += 32 * 256) m = fmaxf(m, fabsf(b2bw[i]));
    red[t] = m; __syncthreads();
    for (int s = 128; s > 0; s >>= 1) { if (t < s) red[t] = fmaxf(red[t], red[t + s]); __syncthreads(); }
    if (t == 0) atomicMax((unsigned*)&ws[0], __float_as_uint(red[0]));
  } else if (b < 64) {
    float m = 0.f;
    for (int i = (b - 32) * 256 + t; i < E2; i += 32 * 256) m = fmaxf(m, fabsf(p2bw[i]));
    red[t] = m; __syncthreads();
    for (int s = 128; s > 0; s >>= 1) { if (t < s) red[t] = fmaxf(red[t], red[t + s]); __syncthreads(); }
    if (t == 0) atomicMax((unsigned*)&ws[1], __float_as_uint(red[0]));
  } else if (b < 96) {
    float s0 = 0.f;
    for (int i = (b - 64) * 256 + t; i < N_NODES; i += 32 * 256) s0 += area[i];
    red[t] = s0; __syncthreads();
    for (int s = 128; s > 0; s >>= 1) { if (t < s) red[t] += red[t + s]; __syncthreads(); }
    if (t == 0) atomicAdd(&ws[2], red[0]);
  } else {
    if (t < HDIM) ((int*)ws)[OFF_PMAX + t] = 0x80000000;
  }
}

// ---------------- counting sort: histogram / scan / scatter ----------------
__global__ __launch_bounds__(256) void hist_kernel(const int* __restrict__ src,
                                                   const int* __restrict__ dst,
                                                   const int* __restrict__ pblk,
                                                   int* __restrict__ cntB,
                                                   int* __restrict__ cntP) {
  int i = blockIdx.x * 256 + threadIdx.x;
  if (i < NMSG_B2B) {
    int e = i >> 1;
    int t = (i & 1) ? dst[e] : src[e];
    atomicAdd(&cntB[t], 1);
  } else if (i < NMSG_B2B + E2) {
    atomicAdd(&cntP[pblk[i - NMSG_B2B]], 1);
  }
}

__global__ __launch_bounds__(1024) void scan_kernel(float* __restrict__ ws) {
  const int* cnt = (const int*)ws + (blockIdx.x == 0 ? OFF_CNTB : OFF_CNTP);
  int* start     = (int*)ws + (blockIdx.x == 0 ? OFF_STARTB : OFF_STARTP);
  __shared__ int s[1024];
  int t = threadIdx.x;
  int base = t * 4;
  int a0 = cnt[base], a1 = cnt[base + 1], a2 = cnt[base + 2], a3 = cnt[base + 3];
  int sum = a0 + a1 + a2 + a3;
  s[t] = sum; __syncthreads();
  for (int off = 1; off < 1024; off <<= 1) {
    int v = (t >= off) ? s[t - off] : 0;
    __syncthreads();
    s[t] += v;
    __syncthreads();
  }
  int excl = s[t] - sum;
  start[base]     = excl;
  start[base + 1] = excl + a0;
  start[base + 2] = excl + a0 + a1;
  start[base + 3] = excl + a0 + a1 + a2;
}

__global__ __launch_bounds__(256) void scatter_kernel(const int* __restrict__ src,
                                                      const int* __restrict__ dst,
                                                      const int* __restrict__ pblk,
                                                      int* __restrict__ startB,
                                                      int* __restrict__ startP,
                                                      int* __restrict__ sortedB,
                                                      int* __restrict__ sortedP) {
  int i = blockIdx.x * 256 + threadIdx.x;
  if (i < NMSG_B2B) {
    int e = i >> 1;
    int t = (i & 1) ? dst[e] : src[e];
    int pos = atomicAdd(&startB[t], 1);
    sortedB[pos] = i;
  } else if (i < NMSG_B2B + E2) {
    int e = i - NMSG_B2B;
    int t = pblk[e];
    int pos = atomicAdd(&startP[t], 1);
    sortedP[pos] = e;
  }
}

// ---------------- pack weights into MFMA B-fragment order ----------------
// B-frag (16x16x32): lane holds B[k=(lane>>4)*8+j][n=lane&15], j=0..7.
__global__ __launch_bounds__(256) void prep_kernel(const float* __restrict__ bW1,
                                                   const float* __restrict__ bW2,
                                                   const float* __restrict__ pW1,
                                                   const float* __restrict__ pW2,
                                                   const float* __restrict__ sWm,
                                                   float* __restrict__ ws) {
  unsigned short* Cp  = (unsigned short*)(ws + OFF_CP);
  unsigned short* Bp2 = (unsigned short*)(ws + OFF_BP2);
  unsigned short* Pp2 = (unsigned short*)(ws + OFF_PP2);
  unsigned short* Sp  = (unsigned short*)(ws + OFF_SP);
  float* wlast = ws + OFF_WLAST;
  float* pextra = ws + OFF_PEXTRA;
  const int total = 49152 + 3 * 16384 + 128 + 384;
  for (int t = blockIdx.x * 256 + threadIdx.x; t < total; t += gridDim.x * 256) {
    if (t < 49152) {                       // W1cat: 24 ntiles x 4 ksteps (P|Q|R columns)
      int j = t & 7, lane = (t >> 3) & 63, ks = (t >> 9) & 3, ncat = t >> 11;
      int col = ncat * 16 + (lane & 15), k = ks * 32 + (lane >> 4) * 8 + j;
      float v;
      if (col < 128)      v = bW1[k * 128 + col];                 // W1a (h_i)
      else if (col < 256) v = bW1[(128 + k) * 128 + (col - 128)]; // W1b (h_j)
      else                v = pW1[k * 128 + (col - 256)];         // p2b W1a
      Cp[t] = f2bf(v);
    } else if (t < 65536) {                // b2b W2: 8nt x 4ks
      int u = t - 49152;
      int j = u & 7, lane = (u >> 3) & 63, ks = (u >> 9) & 3, nt = u >> 11;
      int n = nt * 16 + (lane & 15), k = ks * 32 + (lane >> 4) * 8 + j;
      Bp2[u] = f2bf(bW2[k * 128 + n]);
    } else if (t < 81920) {                // p2b W2
      int u = t - 65536;
      int j = u & 7, lane = (u >> 3) & 63, ks = (u >> 9) & 3, nt = u >> 11;
      int n = nt * 16 + (lane & 15), k = ks * 32 + (lane >> 4) * 8 + j;
      Pp2[u] = f2bf(pW2[k * 128 + n]);
    } else if (t < 98304) {                // self_W
      int u = t - 81920;
      int j = u & 7, lane = (u >> 3) & 63, ks = (u >> 9) & 3, nt = u >> 11;
      int n = nt * 16 + (lane & 15), k = ks * 32 + (lane >> 4) * 8 + j;
      Sp[u] = f2bf(sWm[k * 128 + n]);
    } else if (t < 98432) {
      int u = t - 98304;
      wlast[u] = bW1[256 * 128 + u];
    } else {
      int u = t - 98432;
      int r = u >> 7, n = u & 127;
      pextra[u] = pW1[(128 + r) * 128 + n];
    }
  }
}

// ---------------- input MLP ----------------
__global__ __launch_bounds__(128) void input_mlp_kernel(const float* __restrict__ bfeat,
                                                        const int* __restrict__ rid,
                                                        const float* __restrict__ remb,
                                                        const float* __restrict__ iemb,
                                                        const float* __restrict__ W1,
                                                        const float* __restrict__ b1,
                                                        const float* __restrict__ W2,
                                                        const float* __restrict__ b2,
                                                        unsigned short* __restrict__ hb) {
  __shared__ __attribute__((aligned(16))) float x[8][40];
  __shared__ __attribute__((aligned(16))) float h1[8][128];
  int t = threadIdx.x;
  int n0 = blockIdx.x * 8;
  for (int idx = t; idx < 8 * 40; idx += 128) {
    int nb = idx / 40, f = idx - nb * 40;
    int n = n0 + nb;
    float v;
    if (f < 16)      v = bfeat[n * 16 + f];
    else if (f < 32) v = remb[rid[n] * 16 + (f - 16)];
    else             v = iemb[(n & 1023) * 8 + (f - 32)];
    x[nb][f] = v;
  }
  __syncthreads();
  float acc[8];
  float bb = b1[t];
#pragma unroll
  for (int nb = 0; nb < 8; nb++) acc[nb] = bb;
  for (int k = 0; k < 40; k++) {
    float wv = W1[k * 128 + t];
#pragma unroll
    for (int nb = 0; nb < 8; nb++) acc[nb] += x[nb][k] * wv;
  }
#pragma unroll
  for (int nb = 0; nb < 8; nb++) h1[nb][t] = fmaxf(acc[nb], 0.f);
  __syncthreads();
  float bb2 = b2[t];
#pragma unroll
  for (int nb = 0; nb < 8; nb++) acc[nb] = bb2;
  for (int k = 0; k < 128; k++) {
    float wv = W2[k * 128 + t];
#pragma unroll
    for (int nb = 0; nb < 8; nb++) acc[nb] += h1[nb][k] * wv;
  }
#pragma unroll
  for (int nb = 0; nb < 8; nb++) {
    hb[(n0 + nb) * 128 + t] = f2bf(fmaxf(acc[nb], 0.f));
  }
}

// ---------------- PQR precompute: [P|Q|R] = H @ W1cat (+biases), 16 nodes/block ----------------
__global__ __launch_bounds__(256) void pqr_kernel(const unsigned short* __restrict__ hb,
                                                  const unsigned short* __restrict__ Cp,
                                                  const float* __restrict__ bb1,
                                                  const float* __restrict__ pb1,
                                                  float* __restrict__ P,
                                                  float* __restrict__ Q,
                                                  float* __restrict__ R) {
  __shared__ __attribute__((aligned(16))) unsigned short A[16 * 136];
  int tid = threadIdx.x;
  int n0 = blockIdx.x * 16;
  if (tid < 256) {
    int m = tid >> 4, o = (tid & 15) * 8;
    *(uint4*)(&A[m * 136 + o]) = *(const uint4*)(hb + (n0 + m) * 128 + o);
  }
  __syncthreads();
  int lane = tid & 63, wv = tid >> 6;
  int l15 = lane & 15, q = lane >> 4;
  f32x4 zero = {0.f, 0.f, 0.f, 0.f};
  f32x4 acc[6];
#pragma unroll
  for (int i = 0; i < 6; i++) acc[i] = zero;
#pragma unroll
  for (int ks = 0; ks < 4; ks++) {
    short8 af = *(const short8*)(&A[l15 * 136 + ks * 32 + q * 8]);
#pragma unroll
    for (int nt = 0; nt < 6; nt++) {
      short8 bfr = *(const short8*)(Cp + (((wv * 6 + nt) * 4 + ks) * 64 + lane) * 8);
      acc[nt] = __builtin_amdgcn_mfma_f32_16x16x32_bf16(af, bfr, acc[nt], 0, 0, 0);
    }
  }
#pragma unroll
  for (int nt = 0; nt < 6; nt++) {
    int col = (wv * 6 + nt) * 16 + l15;
    int arr = col >> 7, cc = col & 127;
    float bias = (arr == 0) ? bb1[cc] : ((arr == 2) ? pb1[cc] : 0.f);
    float* dstp = (arr == 0) ? P : ((arr == 1) ? Q : R);
#pragma unroll
    for (int r = 0; r < 4; r++) {
      dstp[(n0 + q * 4 + r) * 128 + cc] = acc[nt][r] + bias;
    }
  }
}

// ---------------- unified edge kernel: gather P/Q/R + relu -> GEMM2 -> segmented reduce ----------------
__global__ __launch_bounds__(256, 4) void edge_kernel(const int* __restrict__ src,
                                                      const int* __restrict__ dst,
                                                      const float* __restrict__ w,
                                                      const int* __restrict__ pblk,
                                                      const int* __restrict__ ppin,
                                                      const float* __restrict__ pw,
                                                      const float* __restrict__ pins,
                                                      const float* __restrict__ wsf,
                                                      float* __restrict__ ws,
                                                      float* __restrict__ agg) {
  // union buffer: H1s (64x136 ushort = 17408 B) then Mf (64x132 f32 = 33792 B)
  __shared__ __attribute__((aligned(16))) float BufU[64 * 132];
  __shared__ float wsc[64], pf0[64], pf1[64], pf2[64];
  __shared__ int tgt[64], oth[64];
  unsigned short* H1s = (unsigned short*)BufU;
  float* Mf = BufU;
  int tid = threadIdx.x;
  bool isB = blockIdx.x < (NMSG_B2B / 64);
  int base = isB ? blockIdx.x * 64 : (blockIdx.x - NMSG_B2B / 64) * 64;
  const float* Pm = ws + OFF_P;
  const float* Qm = ws + OFF_Q;
  const float* Rm = ws + OFF_R;
  const float* wlast = ws + OFF_WLAST;
  const float* pextra = ws + OFF_PEXTRA;
  const int* sortedB = (const int*)ws + OFF_SRTB;
  const int* sortedP = (const int*)ws + OFF_SRTP;
  if (tid < 64) {
    if (isB) {
      float invb = 1.f / fmaxf(__uint_as_float(((const unsigned*)wsf)[0]), 1.f);
      int g = sortedB[base + tid];
      int e = g >> 1, d = g & 1;
      int s = src[e], dd = dst[e];
      tgt[tid] = d ? dd : s;
      oth[tid] = d ? s : dd;
      wsc[tid] = w[e] * invb;
    } else {
      float invp = 1.f / fmaxf(__uint_as_float(((const unsigned*)wsf)[1]), 1.f);
      float cs = fmaxf(sqrtf(fmaxf(wsf[2], 1e-6f)), 1e-6f);
      float invc = 1.f / cs;
      int e = sortedP[base + tid];
      int pin = ppin[e];
      tgt[tid] = pblk[e];
      pf0[tid] = pins[pin * 2] * invc;
      pf1[tid] = pins[pin * 2 + 1] * invc;
      pf2[tid] = pw[e] * invp;
    }
  }
  __syncthreads();
  // stage 2: H1 = relu(P[i]+Q[j]+w*wlast) or relu(R[b]+x0*e0+x1*e1+x2*e2), bf16 into LDS
  if (isB) {
    for (int c = tid; c < 2048; c += 256) {
      int m = c >> 5, ch = c & 31;
      f32x4 p = *(const f32x4*)(Pm + (size_t)tgt[m] * 128 + ch * 4);
      f32x4 qv = *(const f32x4*)(Qm + (size_t)oth[m] * 128 + ch * 4);
      f32x4 wl = *(const f32x4*)(wlast + ch * 4);
      f32x4 v = p + qv + wsc[m] * wl;
      ushort4 hv;
      hv.x = f2bf(fmaxf(v.x, 0.f)); hv.y = f2bf(fmaxf(v.y, 0.f));
      hv.z = f2bf(fmaxf(v.z, 0.f)); hv.w = f2bf(fmaxf(v.w, 0.f));
      *(ushort4*)(&H1s[m * 136 + ch * 4]) = hv;
    }
  } else {
    for (int c = tid; c < 2048; c += 256) {
      int m = c >> 5, ch = c & 31;
      f32x4 rv = *(const f32x4*)(Rm + (size_t)tgt[m] * 128 + ch * 4);
      f32x4 e0 = *(const f32x4*)(pextra + ch * 4);
      f32x4 e1 = *(const f32x4*)(pextra + 128 + ch * 4);
      f32x4 e2 = *(const f32x4*)(pextra + 256 + ch * 4);
      f32x4 v = rv + pf0[m] * e0 + pf1[m] * e1 + pf2[m] * e2;
      ushort4 hv;
      hv.x = f2bf(fmaxf(v.x, 0.f)); hv.y = f2bf(fmaxf(v.y, 0.f));
      hv.z = f2bf(fmaxf(v.z, 0.f)); hv.w = f2bf(fmaxf(v.w, 0.f));
      *(ushort4*)(&H1s[m * 136 + ch * 4]) = hv;
    }
  }
  __syncthreads();
  // stage 3: GEMM2, 2x2 wave split: rows 32 x cols 64 per wave
  const unsigned short* B2p = (const unsigned short*)(ws + (isB ? OFF_BP2 : OFF_PP2));
  int lane = tid & 63, wv = tid >> 6;
  int l15 = lane & 15, q = lane >> 4;
  int rowbase = (wv >> 1) * 32;
  int nt0 = (wv & 1) * 4;
  f32x4 zero = {0.f, 0.f, 0.f, 0.f};
  f32x4 acc2[2][4];
#pragma unroll
  for (int a = 0; a < 2; a++)
#pragma unroll
    for (int b = 0; b < 4; b++) acc2[a][b] = zero;
#pragma unroll
  for (int ks = 0; ks < 4; ks++) {
    short8 bf[4];
#pragma unroll
    for (int ntl = 0; ntl < 4; ntl++)
      bf[ntl] = *(const short8*)(B2p + (((nt0 + ntl) * 4 + ks) * 64 + lane) * 8);
#pragma unroll
    for (int mt = 0; mt < 2; mt++) {
      short8 af = *(const short8*)(&H1s[(rowbase + mt * 16 + l15) * 136 + ks * 32 + q * 8]);
#pragma unroll
      for (int ntl = 0; ntl < 4; ntl++)
        acc2[mt][ntl] = __builtin_amdgcn_mfma_f32_16x16x32_bf16(af, bf[ntl], acc2[mt][ntl], 0, 0, 0);
    }
  }
  __syncthreads();   // all waves done reading H1s; Mf overlays it
  const float* bias2 = isB ? (ws + OFF_BP2 - 0) : nullptr;  // (unused; biases passed below)
  (void)bias2;
  // stage 4: messages (+b2) into Mf
  {
    const float* b2v_ptr = isB ? (const float*)nullptr : (const float*)nullptr;
    (void)b2v_ptr;
  }
#pragma unroll
  for (int mt = 0; mt < 2; mt++) {
#pragma unroll
    for (int ntl = 0; ntl < 4; ntl++) {
      int n = (nt0 + ntl) * 16 + l15;
#pragma unroll
      for (int r = 0; r < 4; r++) {
        int row = rowbase + mt * 16 + q * 4 + r;
        Mf[row * 132 + n] = acc2[mt][ntl][r];
      }
    }
  }
  __syncthreads();
  // stage 5: segmented reduce; bias b2 added once per emitted segment-row
  extern __global__ void edge_kernel_dummy();  // (no-op decl)
  {
    const float* bb = isB ? nullptr : nullptr;
    (void)bb;
  }
  int c = tid & 127, half = tid >> 7;
  int r0 = half * 32;
  float accv = 0.f;
  int cnt = 0;
  int cur = tgt[r0];
  // b2 bias per message: each message adds bias once -> add bias*count at segment flush
  const float* biasArr = isB ? (ws + OFF_WLAST - 128) : (ws + OFF_WLAST - 128); // placeholder, real bias below
  (void)biasArr;
  float b2c = isB ? ws[OFF_CNTB - 1] : 0.f;  // placeholder (not used)
  (void)b2c;
  // NOTE: bias handled via global arrays passed through ws? -> use direct pointers:
  // We stored b2 biases nowhere in ws; add them here from constant args is not possible.
  // Instead bias was NOT added in stage 4; add bias*count at flush using bias loaded from
  // the appropriate global bias array via the wsf-adjacent pointers passed as kernel args.
  for (int r = r0; r < r0 + 32; r++) {
    int tg = tgt[r];
    if (tg != cur) {
      atomicAdd(&agg[cur * 128 + c], accv + ws[(isB ? OFF_CNTB : OFF_CNTB)] * 0.f + (float)cnt * 0.f);
      accv = 0.f; cnt = 0; cur = tg;
    }
    accv += Mf[r * 132 + c];
    cnt++;
  }
  atomicAdd(&agg[cur * 128 + c], accv);
}

// ---------------- selfln: 16 nodes/block, MFMA + fused LN + pooling ----------------
__global__ __launch_bounds__(256) void selfln_kernel(const unsigned short* __restrict__ hb,
                                                     const float* __restrict__ agg,
                                                     const unsigned short* __restrict__ Sp,
                                                     const float* __restrict__ sb,
                                                     const float* __restrict__ lng,
                                                     const float* __restrict__ lnb,
                                                     float* __restrict__ ws,
                                                     float* __restrict__ out) {
  __shared__ __attribute__((aligned(16))) float zs[16 * 133];   // A overlays front
  __shared__ float muS[16], rsg[16];
  __shared__ float partS[16][16], partQ[16][16];
  __shared__ float psumL[2][128];
  __shared__ int   pmaxL[2][128];
  unsigned short* A = (unsigned short*)zs;
  int tid = threadIdx.x;
  int n0 = blockIdx.x * 16;
  {
    int m = tid >> 4, o = (tid & 15) * 8;
    *(uint4*)(&A[m * 136 + o]) = *(const uint4*)(hb + (n0 + m) * 128 + o);
  }
  __syncthreads();
  int lane = tid & 63, wv = tid >> 6;
  int l15 = lane & 15, q = lane >> 4;
  f32x4 zero = {0.f, 0.f, 0.f, 0.f};
  f32x4 acc[2];
  acc[0] = zero; acc[1] = zero;
#pragma unroll
  for (int ks = 0; ks < 4; ks++) {
    short8 af = *(const short8*)(&A[l15 * 136 + ks * 32 + q * 8]);
#pragma unroll
    for (int j = 0; j < 2; j++) {
      short8 bfr = *(const short8*)(Sp + (((2 * wv + j) * 4 + ks) * 64 + lane) * 8);
      acc[j] = __builtin_amdgcn_mfma_f32_16x16x32_bf16(af, bfr, acc[j], 0, 0, 0);
    }
  }
  __syncthreads();   // A dead
#pragma unroll
  for (int j = 0; j < 2; j++) {
    int n = (2 * wv + j) * 16 + l15;
    float sbv = sb[n];
#pragma unroll
    for (int r = 0; r < 4; r++) {
      int row = q * 4 + r;
      zs[row * 133 + n] = acc[j][r] + sbv + agg[(n0 + row) * 128 + n];
    }
  }
  __syncthreads();
  {
    int r = tid >> 4, g = tid & 15;
    const float* zr = &zs[r * 133 + g * 8];
    float s = 0.f, s2 = 0.f;
#pragma unroll
    for (int i = 0; i < 8; i++) { float v = zr[i]; s += v; s2 += v * v; }
    partS[r][g] = s; partQ[r][g] = s2;
  }
  __syncthreads();
  if (tid < 16) {
    float s = 0.f, s2 = 0.f;
#pragma unroll
    for (int g = 0; g < 16; g++) { s += partS[tid][g]; s2 += partQ[tid][g]; }
    float m = s * (1.f / 128.f);
    float var = s2 * (1.f / 128.f) - m * m;
    muS[tid] = m;
    rsg[tid] = rsqrtf(fmaxf(var, 0.f) + 1e-5f);
  }
  __syncthreads();
  {
    int c = tid & 127, half = tid >> 7;
    float g = lng[c], b = lnb[c];
    float ls = 0.f; int lm = 0x80000000;
    for (int r = half * 8; r < half * 8 + 8; r++) {
      float v = (zs[r * 133 + c] - muS[r]) * rsg[r] * g + b;
      out[(n0 + r) * 128 + c] = v;
      ls += v;
      int e = __float_as_int(v);
      e = e >= 0 ? e : (e ^ 0x7fffffff);
      lm = max(lm, e);
    }
    psumL[half][c] = ls; pmaxL[half][c] = lm;
  }
  __syncthreads();
  if (tid < 128) {
    atomicAdd(&ws[OFF_PSUM + tid], psumL[0][tid] + psumL[1][tid]);
    atomicMax(&((int*)ws)[OFF_PMAX + tid], max(pmaxL[0][tid], pmaxL[1][tid]));
  }
  if (tid < 16) out[N_NODES * HDIM + HDIM + n0 + tid] = 1.0f;
}

// ---------------- graph embedding (512 threads) ----------------
__global__ __launch_bounds__(512) void graph_kernel(const float* __restrict__ ws,
                                                    const float* __restrict__ W1,
                                                    const float* __restrict__ b1,
                                                    const float* __restrict__ W2,
                                                    const float* __restrict__ b2,
                                                    float* __restrict__ out) {
  __shared__ float pooled[256];
  __shared__ float part[4][128];
  __shared__ float g1[128];
  int t = threadIdx.x;
  if (t < 128) {
    pooled[t] = ws[OFF_PSUM + t] * (1.f / (float)N_NODES);
  } else if (t < 256) {
    int e = ((const int*)ws)[OFF_PMAX + (t - 128)];
    int bits = e >= 0 ? e : (e ^ 0x7fffffff);
    pooled[t] = __int_as_float(bits);
  }
  __syncthreads();
  {
    int c = t & 127, g = t >> 7;
    float acc = 0.f;
#pragma unroll 8
    for (int k = g * 64; k < g * 64 + 64; k++) acc += pooled[k] * W1[k * 128 + c];
    part[g][c] = acc;
  }
  __syncthreads();
  if (t < 128) {
    g1[t] = fmaxf(part[0][t] + part[1][t] + part[2][t] + part[3][t] + b1[t], 0.f);
  }
  __syncthreads();
  {
    int c = t & 127, g = t >> 7;
    float acc = 0.f;
#pragma unroll 8
    for (int k = g * 32; k < g * 32 + 32; k++) acc += g1[k] * W2[k * 128 + c];
    part[g][c] = acc;
  }
  __syncthreads();
  if (t < 128) {
    out[N_NODES * HDIM + t] = part[0][t] + part[1][t] + part[2][t] + part[3][t] + b2[t];
  }
}

// bias-add kernel for agg: agg[n][c] += cnt_b2b[n]*b2[c] + cnt_p2b[n]*pb2[c]
// (edge_kernel omits the per-message +b2; each message contributes exactly one b2,
//  so agg needs +count*bias per node. counts are in CNTB/CNTP from the histogram.)
__global__ __launch_bounds__(256) void aggbias_kernel(const float* __restrict__ bb2,
                                                      const float* __restrict__ pb2,
                                                      float* __restrict__ ws) {
  __shared__ float b2s[128], p2s[128];
  int t = threadIdx.x;
  if (t < 128) { b2s[t] = bb2[t]; p2s[t] = pb2[t]; }
  __syncthreads();
  int n0 = blockIdx.x * 16;
  const int* cntB = (const int*)ws + OFF_CNTB;
  const int* cntP = (const int*)ws + OFF_CNTP;
  float* agg = ws + OFF_AGG;
  for (int idx = t; idx < 16 * 128; idx += 256) {
    int m = idx >> 7, c = idx & 127;
    int n = n0 + m;
    agg[n * 128 + c] += (float)cntB[n] * b2s[c] + (float)cntP[n] * p2s[c];
  }
}

extern "C" void kernel_launch(void* const* d_in, const int* in_sizes, int n_in,
                              void* d_out, int out_size, void* d_ws, size_t ws_size,
                              hipStream_t stream) {
  const float* bfeat = (const float*)d_in[0];
  const int*   rid   = (const int*)d_in[1];
  const int*   bsrc  = (const int*)d_in[2];
  const int*   bdst  = (const int*)d_in[3];
  const float* bw    = (const float*)d_in[4];
  const int*   ppin  = (const int*)d_in[5];
  const int*   pblk  = (const int*)d_in[6];
  const float* pw    = (const float*)d_in[7];
  const float* pins  = (const float*)d_in[8];
  const float* area  = (const float*)d_in[9];
  const float* remb  = (const float*)d_in[10];
  const float* iemb  = (const float*)d_in[11];
  const float* inW1  = (const float*)d_in[12];
  const float* inb1  = (const float*)d_in[13];
  const float* inW2  = (const float*)d_in[14];
  const float* inb2  = (const float*)d_in[15];
  const float* bW1   = (const float*)d_in[16];
  const float* bb1   = (const float*)d_in[17];
  const float* bW2   = (const float*)d_in[18];
  const float* bb2   = (const float*)d_in[19];
  const float* pW1   = (const float*)d_in[20];
  const float* pb1   = (const float*)d_in[21];
  const float* pW2   = (const float*)d_in[22];
  const float* pb2   = (const float*)d_in[23];
  const float* sW    = (const float*)d_in[24];
  const float* sb    = (const float*)d_in[25];
  const float* lng   = (const float*)d_in[26];
  const float* lnb   = (const float*)d_in[27];
  const float* gW1   = (const float*)d_in[28];
  const float* gb1   = (const float*)d_in[29];
  const float* gW2   = (const float*)d_in[30];
  const float* gb2   = (const float*)d_in[31];

  float* ws  = (float*)d_ws;
  float* out = (float*)d_out;
  float* agg = ws + OFF_AGG;
  unsigned short* hb  = (unsigned short*)(ws + OFF_HB);
  unsigned short* Cp  = (unsigned short*)(ws + OFF_CP);
  unsigned short* Sp  = (unsigned short*)(ws + OFF_SP);
  int* cntB   = (int*)ws + OFF_CNTB;
  int* startB = (int*)ws + OFF_STARTB;
  int* cntP   = (int*)ws + OFF_CNTP;
  int* startP = (int*)ws + OFF_STARTP;
  int* sortedB = (int*)ws + OFF_SRTB;
  int* sortedP = (int*)ws + OFF_SRTP;

  hipMemsetAsync(d_ws, 0, (size_t)OFF_HB * sizeof(float), stream);
  hipMemsetAsync((void*)cntB, 0, 4 * 4096 * sizeof(int), stream);
  reduce_kernel<<<97, 256, 0, stream>>>(bw, pw, area, ws);
  hist_kernel<<<(NMSG_B2B + E2 + 255) / 256, 256, 0, stream>>>(bsrc, bdst, pblk, cntB, cntP);
  scan_kernel<<<2, 1024, 0, stream>>>(ws);
  scatter_kernel<<<(NMSG_B2B + E2 + 255) / 256, 256, 0, stream>>>(bsrc, bdst, pblk,
                                                                  startB, startP, sortedB, sortedP);
  prep_kernel<<<128, 256, 0, stream>>>(bW1, bW2, pW1, pW2, sW, ws);
  input_mlp_kernel<<<N_NODES / 8, 128, 0, stream>>>(bfeat, rid, remb, iemb,
                                                    inW1, inb1, inW2, inb2, hb);
  pqr_kernel<<<N_NODES / 16, 256, 0, stream>>>(hb, Cp, bb1, pb1,
                                               ws + OFF_P, ws + OFF_Q, ws + OFF_R);
  edge_kernel<<<(NMSG_B2B + E2) / 64, 256, 0, stream>>>(bsrc, bdst, bw, pblk, ppin, pw,
                                                        pins, ws, ws, agg);
  aggbias_kernel<<<N_NODES / 16, 256, 0, stream>>>(bb2, pb2, ws);
  selfln_kernel<<<N_NODES / 16, 256, 0, stream>>>(hb, agg, Sp, sb, lng, lnb, ws, out);
  graph_kernel<<<1, 512, 0, stream>>>(ws, gW1, gb1, gW2, gb2, out);
}

// Round 5
// 265.019 us; speedup vs baseline: 2.4648x; 1.0886x over previous
//
#include <hip/hip_runtime.h>
#include <hip/hip_bf16.h>

#define N_NODES 4096
#define HDIM    128
#define E1      131072
#define E2      131072
#define NMSG_B2B (2 * E1)

// ---- workspace layout (float units) ----
#define OFF_PSUM   4
#define OFF_PMAX   132
#define OFF_HB     260                               // h bf16: 524288 u16 = 262144 fl
#define OFF_P      (OFF_HB + 262144)                 // P = H@bW1a + bb1, f32 [4096][128]
#define OFF_Q      (OFF_P + 524288)                  // Q = H@bW1b
#define OFF_R      (OFF_Q + 524288)                  // R = H@pW1a + pb1
#define OFF_SB     (OFF_R + 524288)                  // Sb[n] = sum relu(H1) b2b, f32
#define OFF_SPA    (OFF_SB + 524288)                 // Sp[n] p2b
#define OFF_CP     (OFF_SPA + 524288)                // W1cat pack 49152 u16 = 24576 fl
#define OFF_B2H    (OFF_CP + 24576)                  // bW2 hi pack 16384 u16 = 8192 fl
#define OFF_B2L    (OFF_B2H + 8192)
#define OFF_P2H    (OFF_B2L + 8192)
#define OFF_P2L    (OFF_P2H + 8192)
#define OFF_SWP    (OFF_P2L + 8192)                  // self_W pack
#define OFF_IW1    (OFF_SWP + 8192)                  // in_W1 pack (K=64 pad) 8192 u16
#define OFF_IW2    (OFF_IW1 + 4096)                  // in_W2 pack 16384 u16
#define OFF_WLAST  (OFF_IW2 + 8192)                  // bW1 row 256, f32[128]
#define OFF_PEXTRA (OFF_WLAST + 128)                 // pW1 rows 128..130, f32[384]
#define OFF_CNTB   (OFF_PEXTRA + 384)
#define OFF_STARTB (OFF_CNTB + 4096)
#define OFF_CNTP   (OFF_STARTB + 4096)
#define OFF_STARTP (OFF_CNTP + 4096)
#define OFF_SRTB   (OFF_STARTP + 4096)               // packed (oth<<17)|eid, 262144
#define OFF_SRTP   (OFF_SRTB + NMSG_B2B)             // eid, 131072
#define WS_FLOATS  (OFF_SRTP + E2)

typedef short short8 __attribute__((ext_vector_type(8)));
typedef float f32x4 __attribute__((ext_vector_type(4)));

__device__ __forceinline__ unsigned short f2bf(float f) {
  union { float f; unsigned u; } v; v.f = f;
  unsigned r = v.u + 0x7fffu + ((v.u >> 16) & 1u);   // RNE
  return (unsigned short)(r >> 16);
}
__device__ __forceinline__ float bf2f(unsigned short h) {
  return __uint_as_float((unsigned)h << 16);
}

// ---------------- reductions + pmax init ----------------
__global__ __launch_bounds__(256) void reduce_kernel(const float* __restrict__ b2bw,
                                                     const float* __restrict__ p2bw,
                                                     const float* __restrict__ area,
                                                     float* __restrict__ ws) {
  __shared__ float red[256];
  int b = blockIdx.x, t = threadIdx.x;
  if (b < 32) {
    float m = 0.f;
    for (int i = b * 256 + t; i < E1; i += 32 * 256) m = fmaxf(m, fabsf(b2bw[i]));
    red[t] = m; __syncthreads();
    for (int s = 128; s > 0; s >>= 1) { if (t < s) red[t] = fmaxf(red[t], red[t + s]); __syncthreads(); }
    if (t == 0) atomicMax((unsigned*)&ws[0], __float_as_uint(red[0]));
  } else if (b < 64) {
    float m = 0.f;
    for (int i = (b - 32) * 256 + t; i < E2; i += 32 * 256) m = fmaxf(m, fabsf(p2bw[i]));
    red[t] = m; __syncthreads();
    for (int s = 128; s > 0; s >>= 1) { if (t < s) red[t] = fmaxf(red[t], red[t + s]); __syncthreads(); }
    if (t == 0) atomicMax((unsigned*)&ws[1], __float_as_uint(red[0]));
  } else if (b < 96) {
    float s0 = 0.f;
    for (int i = (b - 64) * 256 + t; i < N_NODES; i += 32 * 256) s0 += area[i];
    red[t] = s0; __syncthreads();
    for (int s = 128; s > 0; s >>= 1) { if (t < s) red[t] += red[t + s]; __syncthreads(); }
    if (t == 0) atomicAdd(&ws[2], red[0]);
  } else {
    if (t < HDIM) ((int*)ws)[OFF_PMAX + t] = 0x80000000;
  }
}

// ---------------- counting sort: histogram / scan / scatter ----------------
__global__ __launch_bounds__(256) void hist_kernel(const int* __restrict__ src,
                                                   const int* __restrict__ dst,
                                                   const int* __restrict__ pblk,
                                                   int* __restrict__ cntB,
                                                   int* __restrict__ cntP) {
  int i = blockIdx.x * 256 + threadIdx.x;
  if (i < NMSG_B2B) {
    int e = i >> 1;
    int t = (i & 1) ? dst[e] : src[e];
    atomicAdd(&cntB[t], 1);
  } else if (i < NMSG_B2B + E2) {
    atomicAdd(&cntP[pblk[i - NMSG_B2B]], 1);
  }
}

__global__ __launch_bounds__(1024) void scan_kernel(float* __restrict__ ws) {
  const int* cnt = (const int*)ws + (blockIdx.x == 0 ? OFF_CNTB : OFF_CNTP);
  int* start     = (int*)ws + (blockIdx.x == 0 ? OFF_STARTB : OFF_STARTP);
  __shared__ int s[1024];
  int t = threadIdx.x;
  int base = t * 4;
  int a0 = cnt[base], a1 = cnt[base + 1], a2 = cnt[base + 2], a3 = cnt[base + 3];
  int sum = a0 + a1 + a2 + a3;
  s[t] = sum; __syncthreads();
  for (int off = 1; off < 1024; off <<= 1) {
    int v = (t >= off) ? s[t - off] : 0;
    __syncthreads();
    s[t] += v;
    __syncthreads();
  }
  int excl = s[t] - sum;
  start[base]     = excl;
  start[base + 1] = excl + a0;
  start[base + 2] = excl + a0 + a1;
  start[base + 3] = excl + a0 + a1 + a2;
}

__global__ __launch_bounds__(256) void scatter_kernel(const int* __restrict__ src,
                                                      const int* __restrict__ dst,
                                                      const int* __restrict__ pblk,
                                                      int* __restrict__ startB,
                                                      int* __restrict__ startP,
                                                      unsigned* __restrict__ sortedB,
                                                      int* __restrict__ sortedP) {
  int i = blockIdx.x * 256 + threadIdx.x;
  if (i < NMSG_B2B) {
    int e = i >> 1, d = i & 1;
    int t = d ? dst[e] : src[e];
    int o = d ? src[e] : dst[e];
    int pos = atomicAdd(&startB[t], 1);
    sortedB[pos] = ((unsigned)o << 17) | (unsigned)e;
  } else if (i < NMSG_B2B + E2) {
    int e = i - NMSG_B2B;
    int t = pblk[e];
    int pos = atomicAdd(&startP[t], 1);
    sortedP[pos] = e;
  }
}

// ---------------- pack weights: MFMA B-fragment order (+ hi/lo splits for W2s) --------
// B-frag (16x16x32): lane holds B[k=(lane>>4)*8+j][n=lane&15], j=0..7.
__global__ __launch_bounds__(256) void prep_kernel(const float* __restrict__ bW1,
                                                   const float* __restrict__ bW2,
                                                   const float* __restrict__ pW1,
                                                   const float* __restrict__ pW2,
                                                   const float* __restrict__ sWm,
                                                   const float* __restrict__ iW1,
                                                   const float* __restrict__ iW2,
                                                   float* __restrict__ ws) {
  unsigned short* Cp  = (unsigned short*)(ws + OFF_CP);
  unsigned short* B2h = (unsigned short*)(ws + OFF_B2H);
  unsigned short* B2l = (unsigned short*)(ws + OFF_B2L);
  unsigned short* P2h = (unsigned short*)(ws + OFF_P2H);
  unsigned short* P2l = (unsigned short*)(ws + OFF_P2L);
  unsigned short* Swp = (unsigned short*)(ws + OFF_SWP);
  unsigned short* I1p = (unsigned short*)(ws + OFF_IW1);
  unsigned short* I2p = (unsigned short*)(ws + OFF_IW2);
  float* wlast = ws + OFF_WLAST;
  float* pextra = ws + OFF_PEXTRA;
  const int total = 156160;
  for (int t = blockIdx.x * 256 + threadIdx.x; t < total; t += gridDim.x * 256) {
    if (t < 49152) {                       // W1cat: 24 nt x 4 ks -> [P|Q|R] cols
      int j = t & 7, lane = (t >> 3) & 63, ks = (t >> 9) & 3, nc = t >> 11;
      int col = nc * 16 + (lane & 15), k = ks * 32 + (lane >> 4) * 8 + j;
      float v;
      if (col < 128)      v = bW1[k * 128 + col];
      else if (col < 256) v = bW1[(128 + k) * 128 + (col - 128)];
      else                v = pW1[k * 128 + (col - 256)];
      Cp[t] = f2bf(v);
    } else if (t < 114688) {               // b2h/b2l/p2h/p2l: 8nt x 4ks each
      int u = (t - 49152) & 16383, which = (t - 49152) >> 14;
      int j = u & 7, lane = (u >> 3) & 63, ks = (u >> 9) & 3, nt = u >> 11;
      int n = nt * 16 + (lane & 15), k = ks * 32 + (lane >> 4) * 8 + j;
      float v = (which < 2) ? bW2[k * 128 + n] : pW2[k * 128 + n];
      unsigned short hi = f2bf(v);
      unsigned short out = (which & 1) ? f2bf(v - bf2f(hi)) : hi;
      ((which < 2) ? ((which & 1) ? B2l : B2h) : ((which & 1) ? P2l : P2h))[u] = out;
    } else if (t < 131072) {               // self_W
      int u = t - 114688;
      int j = u & 7, lane = (u >> 3) & 63, ks = (u >> 9) & 3, nt = u >> 11;
      int n = nt * 16 + (lane & 15), k = ks * 32 + (lane >> 4) * 8 + j;
      Swp[u] = f2bf(sWm[k * 128 + n]);
    } else if (t < 139264) {               // in_W1: 8nt x 2ks, K padded 40->64
      int u = t - 131072;
      int j = u & 7, lane = (u >> 3) & 63, ks = (u >> 9) & 1, nt = u >> 10;
      int n = nt * 16 + (lane & 15), k = ks * 32 + (lane >> 4) * 8 + j;
      I1p[u] = (k < 40) ? f2bf(iW1[k * 128 + n]) : 0;
    } else if (t < 155648) {               // in_W2: 8nt x 4ks
      int u = t - 139264;
      int j = u & 7, lane = (u >> 3) & 63, ks = (u >> 9) & 3, nt = u >> 11;
      int n = nt * 16 + (lane & 15), k = ks * 32 + (lane >> 4) * 8 + j;
      I2p[u] = f2bf(iW2[k * 128 + n]);
    } else if (t < 155776) {
      wlast[t - 155648] = bW1[256 * 128 + (t - 155648)];
    } else {
      int u = t - 155776;
      int r = u >> 7, n = u & 127;
      pextra[u] = pW1[(128 + r) * 128 + n];
    }
  }
}

// ---------------- node kernel: input MLP + PQR, 16 nodes/block, all-MFMA ----------------
__global__ __launch_bounds__(256) void node_kernel(const float* __restrict__ bfeat,
                                                   const int* __restrict__ rid,
                                                   const float* __restrict__ remb,
                                                   const float* __restrict__ iemb,
                                                   const float* __restrict__ ib1,
                                                   const float* __restrict__ ib2,
                                                   const float* __restrict__ bb1,
                                                   const float* __restrict__ pb1,
                                                   float* __restrict__ ws,
                                                   unsigned short* __restrict__ hb) {
  __shared__ __attribute__((aligned(16))) unsigned short xs[16 * 72];
  __shared__ __attribute__((aligned(16))) unsigned short h1s[16 * 136];
  __shared__ __attribute__((aligned(16))) unsigned short hs[16 * 136];
  const unsigned short* I1p = (const unsigned short*)(ws + OFF_IW1);
  const unsigned short* I2p = (const unsigned short*)(ws + OFF_IW2);
  const unsigned short* Cp  = (const unsigned short*)(ws + OFF_CP);
  float* P = ws + OFF_P;
  float* Q = ws + OFF_Q;
  float* R = ws + OFF_R;
  int tid = threadIdx.x;
  int n0 = blockIdx.x * 16;
  for (int idx = tid; idx < 1024; idx += 256) {
    int m = idx >> 6, c = idx & 63;
    int n = n0 + m;
    float v = 0.f;
    if (c < 16)      v = bfeat[n * 16 + c];
    else if (c < 32) v = remb[rid[n] * 16 + (c - 16)];
    else if (c < 40) v = iemb[(n & 1023) * 8 + (c - 32)];
    xs[m * 72 + c] = f2bf(v);
  }
  __syncthreads();
  int lane = tid & 63, wv = tid >> 6;
  int l15 = lane & 15, q = lane >> 4;
  f32x4 zero = {0.f, 0.f, 0.f, 0.f};
  // GEMM1: K=64
  f32x4 a1[2]; a1[0] = zero; a1[1] = zero;
#pragma unroll
  for (int ks = 0; ks < 2; ks++) {
    short8 af = *(const short8*)(&xs[l15 * 72 + ks * 32 + q * 8]);
#pragma unroll
    for (int j = 0; j < 2; j++) {
      short8 bfr = *(const short8*)(I1p + (((2 * wv + j) * 2 + ks) * 64 + lane) * 8);
      a1[j] = __builtin_amdgcn_mfma_f32_16x16x32_bf16(af, bfr, a1[j], 0, 0, 0);
    }
  }
#pragma unroll
  for (int j = 0; j < 2; j++) {
    int n = (2 * wv + j) * 16 + l15;
    float b = ib1[n];
#pragma unroll
    for (int r = 0; r < 4; r++)
      h1s[(q * 4 + r) * 136 + n] = f2bf(fmaxf(a1[j][r] + b, 0.f));
  }
  __syncthreads();
  // GEMM2: K=128
  f32x4 a2[2]; a2[0] = zero; a2[1] = zero;
#pragma unroll
  for (int ks = 0; ks < 4; ks++) {
    short8 af = *(const short8*)(&h1s[l15 * 136 + ks * 32 + q * 8]);
#pragma unroll
    for (int j = 0; j < 2; j++) {
      short8 bfr = *(const short8*)(I2p + (((2 * wv + j) * 4 + ks) * 64 + lane) * 8);
      a2[j] = __builtin_amdgcn_mfma_f32_16x16x32_bf16(af, bfr, a2[j], 0, 0, 0);
    }
  }
#pragma unroll
  for (int j = 0; j < 2; j++) {
    int n = (2 * wv + j) * 16 + l15;
    float b = ib2[n];
#pragma unroll
    for (int r = 0; r < 4; r++) {
      unsigned short hv = f2bf(fmaxf(a2[j][r] + b, 0.f));
      hs[(q * 4 + r) * 136 + n] = hv;
      hb[(n0 + q * 4 + r) * 128 + n] = hv;
    }
  }
  __syncthreads();
  // GEMM3: [P|Q|R] = h @ W1cat, 24 ntiles, wave handles 6
  f32x4 a3[6];
#pragma unroll
  for (int i = 0; i < 6; i++) a3[i] = zero;
#pragma unroll
  for (int ks = 0; ks < 4; ks++) {
    short8 af = *(const short8*)(&hs[l15 * 136 + ks * 32 + q * 8]);
#pragma unroll
    for (int j = 0; j < 6; j++) {
      short8 bfr = *(const short8*)(Cp + (((6 * wv + j) * 4 + ks) * 64 + lane) * 8);
      a3[j] = __builtin_amdgcn_mfma_f32_16x16x32_bf16(af, bfr, a3[j], 0, 0, 0);
    }
  }
#pragma unroll
  for (int j = 0; j < 6; j++) {
    int col = (6 * wv + j) * 16 + l15;
    int arr = col >> 7, cc = col & 127;
    float bias = (arr == 0) ? bb1[cc] : ((arr == 2) ? pb1[cc] : 0.f);
    float* dstp = (arr == 0) ? P : ((arr == 1) ? Q : R);
#pragma unroll
    for (int r = 0; r < 4; r++)
      dstp[(n0 + q * 4 + r) * 128 + cc] = a3[j][r] + bias;
  }
}

// ---------------- edge kernel: one wave per (node, relation); S = sum relu(H1) ---------
__global__ __launch_bounds__(256) void edge_kernel(const float* __restrict__ w,
                                                   const int* __restrict__ ppin,
                                                   const float* __restrict__ pw,
                                                   const float* __restrict__ pins,
                                                   float* __restrict__ ws) {
  int tid = threadIdx.x;
  int lane = tid & 63;
  int gw = blockIdx.x * 4 + (tid >> 6);
  int n = gw >> 1;
  const float* wlast = ws + OFF_WLAST;
  const float* pextra = ws + OFF_PEXTRA;
  if ((gw & 1) == 0) {
    const int* startB = (const int*)ws + OFF_STARTB;
    const int* cntB   = (const int*)ws + OFF_CNTB;
    const unsigned* sortedB = (const unsigned*)ws + OFF_SRTB;
    const float* Qm = ws + OFF_Q;
    float invb = 1.f / fmaxf(__uint_as_float(((const unsigned*)ws)[0]), 1.f);
    int e = startB[n];
    int s = e - cntB[n];
    float p0 = ws[OFF_P + n * 128 + lane];
    float p1 = ws[OFF_P + n * 128 + 64 + lane];
    float wl0 = wlast[lane], wl1 = wlast[64 + lane];
    float a0 = 0.f, a1 = 0.f;
    for (int m = s; m < e; m++) {
      unsigned pk = sortedB[m];
      int oth = pk >> 17;
      int eid = pk & 0x1FFFF;
      float wsc = w[eid] * invb;
      float q0 = Qm[oth * 128 + lane];
      float q1 = Qm[oth * 128 + 64 + lane];
      a0 += fmaxf(fmaf(wsc, wl0, p0) + q0, 0.f);
      a1 += fmaxf(fmaf(wsc, wl1, p1) + q1, 0.f);
    }
    ws[OFF_SB + n * 128 + lane] = a0;
    ws[OFF_SB + n * 128 + 64 + lane] = a1;
  } else {
    const int* startP = (const int*)ws + OFF_STARTP;
    const int* cntP   = (const int*)ws + OFF_CNTP;
    const int* sortedP = (const int*)ws + OFF_SRTP;
    float invp = 1.f / fmaxf(__uint_as_float(((const unsigned*)ws)[1]), 1.f);
    float cs = fmaxf(sqrtf(fmaxf(ws[2], 1e-6f)), 1e-6f);
    float invc = 1.f / cs;
    int e = startP[n];
    int s = e - cntP[n];
    float r0 = ws[OFF_R + n * 128 + lane];
    float r1 = ws[OFF_R + n * 128 + 64 + lane];
    float e00 = pextra[lane],       e01 = pextra[64 + lane];
    float e10 = pextra[128 + lane], e11 = pextra[192 + lane];
    float e20 = pextra[256 + lane], e21 = pextra[320 + lane];
    float a0 = 0.f, a1 = 0.f;
    for (int m = s; m < e; m++) {
      int eid = sortedP[m];
      int pin = ppin[eid];
      float x0 = pins[pin * 2] * invc;
      float x1 = pins[pin * 2 + 1] * invc;
      float x2 = pw[eid] * invp;
      a0 += fmaxf(r0 + x0 * e00 + x1 * e10 + x2 * e20, 0.f);
      a1 += fmaxf(r1 + x0 * e01 + x1 * e11 + x2 * e21, 0.f);
    }
    ws[OFF_SPA + n * 128 + lane] = a0;
    ws[OFF_SPA + n * 128 + 64 + lane] = a1;
  }
}

// ---------------- selfln: z = h@selfW + Sb@bW2 + Sp@pW2 + biases, LN, pooling ----------
__global__ __launch_bounds__(256) void selfln_kernel(const unsigned short* __restrict__ hb,
                                                     const float* __restrict__ sb,
                                                     const float* __restrict__ lng,
                                                     const float* __restrict__ lnb,
                                                     const float* __restrict__ bb2,
                                                     const float* __restrict__ pb2,
                                                     float* __restrict__ ws,
                                                     float* __restrict__ out) {
  __shared__ __attribute__((aligned(16))) unsigned short A[16 * 648];  // h|Sbh|Sbl|Sph|Spl
  __shared__ float zs[16 * 133];
  __shared__ float muS[16], rsg[16];
  __shared__ float partS[16][16], partQ[16][16];
  __shared__ float psumL[2][128];
  __shared__ int   pmaxL[2][128];
  int tid = threadIdx.x;
  int n0 = blockIdx.x * 16;
  {
    int m = tid >> 4, o = (tid & 15) * 8;
    *(uint4*)(&A[m * 648 + o]) = *(const uint4*)(hb + (n0 + m) * 128 + o);
  }
  for (int idx = tid; idx < 2048; idx += 256) {
    int m = idx >> 7, c = idx & 127;
    float v = ws[OFF_SB + (n0 + m) * 128 + c];
    unsigned short hi = f2bf(v);
    A[m * 648 + 128 + c] = hi;
    A[m * 648 + 256 + c] = f2bf(v - bf2f(hi));
  }
  for (int idx = tid; idx < 2048; idx += 256) {
    int m = idx >> 7, c = idx & 127;
    float v = ws[OFF_SPA + (n0 + m) * 128 + c];
    unsigned short hi = f2bf(v);
    A[m * 648 + 384 + c] = hi;
    A[m * 648 + 512 + c] = f2bf(v - bf2f(hi));
  }
  __syncthreads();
  int lane = tid & 63, wv = tid >> 6;
  int l15 = lane & 15, q = lane >> 4;
  f32x4 zero = {0.f, 0.f, 0.f, 0.f};
  f32x4 acc[2]; acc[0] = zero; acc[1] = zero;
  const unsigned short* bufs[7] = {
    (const unsigned short*)(ws + OFF_SWP), (const unsigned short*)(ws + OFF_B2H),
    (const unsigned short*)(ws + OFF_B2L), (const unsigned short*)(ws + OFF_B2H),
    (const unsigned short*)(ws + OFF_P2H), (const unsigned short*)(ws + OFF_P2L),
    (const unsigned short*)(ws + OFF_P2H)};
  const int segs[7] = {0, 128, 128, 256, 384, 384, 512};
#pragma unroll
  for (int p = 0; p < 7; p++) {
#pragma unroll
    for (int ks = 0; ks < 4; ks++) {
      short8 af = *(const short8*)(&A[l15 * 648 + segs[p] + ks * 32 + q * 8]);
#pragma unroll
      for (int j = 0; j < 2; j++) {
        short8 bfr = *(const short8*)(bufs[p] + (((2 * wv + j) * 4 + ks) * 64 + lane) * 8);
        acc[j] = __builtin_amdgcn_mfma_f32_16x16x32_bf16(af, bfr, acc[j], 0, 0, 0);
      }
    }
  }
  const int* cntB = (const int*)ws + OFF_CNTB;
  const int* cntP = (const int*)ws + OFF_CNTP;
#pragma unroll
  for (int r = 0; r < 4; r++) {
    int row = q * 4 + r;
    float cb = (float)cntB[n0 + row], cp = (float)cntP[n0 + row];
#pragma unroll
    for (int j = 0; j < 2; j++) {
      int nn = (2 * wv + j) * 16 + l15;
      zs[row * 133 + nn] = acc[j][r] + sb[nn] + cb * bb2[nn] + cp * pb2[nn];
    }
  }
  __syncthreads();
  {
    int r = tid >> 4, g = tid & 15;
    const float* zr = &zs[r * 133 + g * 8];
    float s = 0.f, s2 = 0.f;
#pragma unroll
    for (int i = 0; i < 8; i++) { float v = zr[i]; s += v; s2 += v * v; }
    partS[r][g] = s; partQ[r][g] = s2;
  }
  __syncthreads();
  if (tid < 16) {
    float s = 0.f, s2 = 0.f;
#pragma unroll
    for (int g = 0; g < 16; g++) { s += partS[tid][g]; s2 += partQ[tid][g]; }
    float m = s * (1.f / 128.f);
    float var = s2 * (1.f / 128.f) - m * m;
    muS[tid] = m;
    rsg[tid] = rsqrtf(fmaxf(var, 0.f) + 1e-5f);
  }
  __syncthreads();
  {
    int c = tid & 127, half = tid >> 7;
    float g = lng[c], b = lnb[c];
    float ls = 0.f; int lm = 0x80000000;
    for (int r = half * 8; r < half * 8 + 8; r++) {
      float v = (zs[r * 133 + c] - muS[r]) * rsg[r] * g + b;
      out[(n0 + r) * 128 + c] = v;
      ls += v;
      int e = __float_as_int(v);
      e = e >= 0 ? e : (e ^ 0x7fffffff);
      lm = max(lm, e);
    }
    psumL[half][c] = ls; pmaxL[half][c] = lm;
  }
  __syncthreads();
  if (tid < 128) {
    atomicAdd(&ws[OFF_PSUM + tid], psumL[0][tid] + psumL[1][tid]);
    atomicMax(&((int*)ws)[OFF_PMAX + tid], max(pmaxL[0][tid], pmaxL[1][tid]));
  }
  if (tid < 16) out[N_NODES * HDIM + HDIM + n0 + tid] = 1.0f;
}

// ---------------- graph embedding (512 threads) ----------------
__global__ __launch_bounds__(512) void graph_kernel(const float* __restrict__ ws,
                                                    const float* __restrict__ W1,
                                                    const float* __restrict__ b1,
                                                    const float* __restrict__ W2,
                                                    const float* __restrict__ b2,
                                                    float* __restrict__ out) {
  __shared__ float pooled[256];
  __shared__ float part[4][128];
  __shared__ float g1[128];
  int t = threadIdx.x;
  if (t < 128) {
    pooled[t] = ws[OFF_PSUM + t] * (1.f / (float)N_NODES);
  } else if (t < 256) {
    int e = ((const int*)ws)[OFF_PMAX + (t - 128)];
    int bits = e >= 0 ? e : (e ^ 0x7fffffff);
    pooled[t] = __int_as_float(bits);
  }
  __syncthreads();
  {
    int c = t & 127, g = t >> 7;
    float acc = 0.f;
#pragma unroll 8
    for (int k = g * 64; k < g * 64 + 64; k++) acc += pooled[k] * W1[k * 128 + c];
    part[g][c] = acc;
  }
  __syncthreads();
  if (t < 128) {
    g1[t] = fmaxf(part[0][t] + part[1][t] + part[2][t] + part[3][t] + b1[t], 0.f);
  }
  __syncthreads();
  {
    int c = t & 127, g = t >> 7;
    float acc = 0.f;
#pragma unroll 8
    for (int k = g * 32; k < g * 32 + 32; k++) acc += g1[k] * W2[k * 128 + c];
    part[g][c] = acc;
  }
  __syncthreads();
  if (t < 128) {
    out[N_NODES * HDIM + t] = part[0][t] + part[1][t] + part[2][t] + part[3][t] + b2[t];
  }
}

extern "C" void kernel_launch(void* const* d_in, const int* in_sizes, int n_in,
                              void* d_out, int out_size, void* d_ws, size_t ws_size,
                              hipStream_t stream) {
  const float* bfeat = (const float*)d_in[0];
  const int*   rid   = (const int*)d_in[1];
  const int*   bsrc  = (const int*)d_in[2];
  const int*   bdst  = (const int*)d_in[3];
  const float* bw    = (const float*)d_in[4];
  const int*   ppin  = (const int*)d_in[5];
  const int*   pblk  = (const int*)d_in[6];
  const float* pw    = (const float*)d_in[7];
  const float* pins  = (const float*)d_in[8];
  const float* area  = (const float*)d_in[9];
  const float* remb  = (const float*)d_in[10];
  const float* iemb  = (const float*)d_in[11];
  const float* inW1  = (const float*)d_in[12];
  const float* inb1  = (const float*)d_in[13];
  const float* inW2  = (const float*)d_in[14];
  const float* inb2  = (const float*)d_in[15];
  const float* bW1   = (const float*)d_in[16];
  const float* bb1   = (const float*)d_in[17];
  const float* bW2   = (const float*)d_in[18];
  const float* bb2   = (const float*)d_in[19];
  const float* pW1   = (const float*)d_in[20];
  const float* pb1   = (const float*)d_in[21];
  const float* pW2   = (const float*)d_in[22];
  const float* pb2   = (const float*)d_in[23];
  const float* sW    = (const float*)d_in[24];
  const float* sb    = (const float*)d_in[25];
  const float* lng   = (const float*)d_in[26];
  const float* lnb   = (const float*)d_in[27];
  const float* gW1   = (const float*)d_in[28];
  const float* gb1   = (const float*)d_in[29];
  const float* gW2   = (const float*)d_in[30];
  const float* gb2   = (const float*)d_in[31];

  float* ws  = (float*)d_ws;
  float* out = (float*)d_out;
  unsigned short* hb = (unsigned short*)(ws + OFF_HB);
  int* cntB   = (int*)ws + OFF_CNTB;
  int* startB = (int*)ws + OFF_STARTB;
  int* cntP   = (int*)ws + OFF_CNTP;
  int* startP = (int*)ws + OFF_STARTP;
  unsigned* sortedB = (unsigned*)ws + OFF_SRTB;
  int* sortedP = (int*)ws + OFF_SRTP;

  hipMemsetAsync(d_ws, 0, 260 * sizeof(float), stream);
  hipMemsetAsync((void*)cntB, 0, 4 * 4096 * sizeof(int), stream);
  reduce_kernel<<<97, 256, 0, stream>>>(bw, pw, area, ws);
  hist_kernel<<<(NMSG_B2B + E2 + 255) / 256, 256, 0, stream>>>(bsrc, bdst, pblk, cntB, cntP);
  scan_kernel<<<2, 1024, 0, stream>>>(ws);
  scatter_kernel<<<(NMSG_B2B + E2 + 255) / 256, 256, 0, stream>>>(bsrc, bdst, pblk,
                                                                  startB, startP, sortedB, sortedP);
  prep_kernel<<<128, 256, 0, stream>>>(bW1, bW2, pW1, pW2, sW, inW1, inW2, ws);
  node_kernel<<<N_NODES / 16, 256, 0, stream>>>(bfeat, rid, remb, iemb,
                                                inb1, inb2, bb1, pb1, ws, hb);
  edge_kernel<<<2 * N_NODES / 4, 256, 0, stream>>>(bw, ppin, pw, pins, ws);
  selfln_kernel<<<N_NODES / 16, 256, 0, stream>>>(hb, sb, lng, lnb, bb2, pb2, ws, out);
  graph_kernel<<<1, 512, 0, stream>>>(ws, gW1, gb1, gW2, gb2, out);
}

// Round 6
// 251.153 us; speedup vs baseline: 2.6009x; 1.0552x over previous
//
#include <hip/hip_runtime.h>
#include <hip/hip_bf16.h>

#define N_NODES 4096
#define HDIM    128
#define E1      131072
#define E2      131072
#define NMSG_B2B (2 * E1)

// ---- workspace layout (float units) ----
#define OFF_PSUM   4
#define OFF_PMAX   132
// ws[3] = selfln completion counter
#define OFF_HB     260                               // h bf16: 524288 u16
#define OFF_P      (OFF_HB + 262144)                 // P (il layout) f32 [4096][128]
#define OFF_Q      (OFF_P + 524288)
#define OFF_R      (OFF_Q + 524288)
#define OFF_SB     (OFF_R + 524288)                  // S_b2b (il layout)
#define OFF_SPA    (OFF_SB + 524288)                 // S_p2b (il layout)
#define OFF_CP     (OFF_SPA + 524288)                // W1cat pack 49152 u16
#define OFF_B2H    (OFF_CP + 24576)
#define OFF_B2L    (OFF_B2H + 8192)
#define OFF_P2H    (OFF_B2L + 8192)
#define OFF_P2L    (OFF_P2H + 8192)
#define OFF_SWP    (OFF_P2L + 8192)
#define OFF_IW1    (OFF_SWP + 8192)
#define OFF_IW2    (OFF_IW1 + 4096)
#define OFF_WLAST  (OFF_IW2 + 8192)                  // il layout f32[128]
#define OFF_PEXTRA (OFF_WLAST + 128)                 // 3 rows, il layout
#define OFF_CNTB   (OFF_PEXTRA + 384)
#define OFF_STARTB (OFF_CNTB + 4096)
#define OFF_CNTP   (OFF_STARTB + 4096)
#define OFF_STARTP (OFF_CNTP + 4096)
#define OFF_SRTBW  (OFF_STARTP + 4096)               // uint2[262144]: {oth, f32 wsc}
#define OFF_SRTPW  (OFF_SRTBW + 524288)              // uint2[131072]: {bf16x2(x0,x1), f32 x2}
#define WS_FLOATS  (OFF_SRTPW + 262144)

typedef short short8 __attribute__((ext_vector_type(8)));
typedef float f32x4 __attribute__((ext_vector_type(4)));

__device__ __forceinline__ unsigned short f2bf(float f) {
  union { float f; unsigned u; } v; v.f = f;
  unsigned r = v.u + 0x7fffu + ((v.u >> 16) & 1u);   // RNE
  return (unsigned short)(r >> 16);
}
__device__ __forceinline__ float bf2f(unsigned short h) {
  return __uint_as_float((unsigned)h << 16);
}
__device__ __forceinline__ int il(int c) { return ((c & 63) << 1) | (c >> 6); }

// ---------------- fused reduce + pmax-init + histogram ----------------
__global__ __launch_bounds__(256) void prehist_kernel(const float* __restrict__ b2bw,
                                                      const float* __restrict__ p2bw,
                                                      const float* __restrict__ area,
                                                      const int* __restrict__ src,
                                                      const int* __restrict__ dst,
                                                      const int* __restrict__ pblk,
                                                      float* __restrict__ ws) {
  __shared__ float red[256];
  int b = blockIdx.x, t = threadIdx.x;
  if (b < 32) {
    float m = 0.f;
    for (int i = b * 256 + t; i < E1; i += 32 * 256) m = fmaxf(m, fabsf(b2bw[i]));
    red[t] = m; __syncthreads();
    for (int s = 128; s > 0; s >>= 1) { if (t < s) red[t] = fmaxf(red[t], red[t + s]); __syncthreads(); }
    if (t == 0) atomicMax((unsigned*)&ws[0], __float_as_uint(red[0]));
  } else if (b < 64) {
    float m = 0.f;
    for (int i = (b - 32) * 256 + t; i < E2; i += 32 * 256) m = fmaxf(m, fabsf(p2bw[i]));
    red[t] = m; __syncthreads();
    for (int s = 128; s > 0; s >>= 1) { if (t < s) red[t] = fmaxf(red[t], red[t + s]); __syncthreads(); }
    if (t == 0) atomicMax((unsigned*)&ws[1], __float_as_uint(red[0]));
  } else if (b < 96) {
    float s0 = 0.f;
    for (int i = (b - 64) * 256 + t; i < N_NODES; i += 32 * 256) s0 += area[i];
    red[t] = s0; __syncthreads();
    for (int s = 128; s > 0; s >>= 1) { if (t < s) red[t] += red[t + s]; __syncthreads(); }
    if (t == 0) atomicAdd(&ws[2], red[0]);
  } else if (b == 96) {
    if (t < HDIM) ((int*)ws)[OFF_PMAX + t] = 0x80000000;
  } else {
    int i = (b - 97) * 256 + t;
    int* cntB = (int*)ws + OFF_CNTB;
    int* cntP = (int*)ws + OFF_CNTP;
    if (i < NMSG_B2B) {
      int e = i >> 1;
      int tg = (i & 1) ? dst[e] : src[e];
      atomicAdd(&cntB[tg], 1);
    } else if (i < NMSG_B2B + E2) {
      atomicAdd(&cntP[pblk[i - NMSG_B2B]], 1);
    }
  }
}

__global__ __launch_bounds__(1024) void scan_kernel(float* __restrict__ ws) {
  const int* cnt = (const int*)ws + (blockIdx.x == 0 ? OFF_CNTB : OFF_CNTP);
  int* start     = (int*)ws + (blockIdx.x == 0 ? OFF_STARTB : OFF_STARTP);
  __shared__ int s[1024];
  int t = threadIdx.x;
  int base = t * 4;
  int a0 = cnt[base], a1 = cnt[base + 1], a2 = cnt[base + 2], a3 = cnt[base + 3];
  int sum = a0 + a1 + a2 + a3;
  s[t] = sum; __syncthreads();
  for (int off = 1; off < 1024; off <<= 1) {
    int v = (t >= off) ? s[t - off] : 0;
    __syncthreads();
    s[t] += v;
    __syncthreads();
  }
  int excl = s[t] - sum;
  start[base]     = excl;
  start[base + 1] = excl + a0;
  start[base + 2] = excl + a0 + a1;
  start[base + 3] = excl + a0 + a1 + a2;
}

// scatter + per-edge feature precompute (sorted order)
__global__ __launch_bounds__(256) void scatter_kernel(const int* __restrict__ src,
                                                      const int* __restrict__ dst,
                                                      const int* __restrict__ pblk,
                                                      const int* __restrict__ ppin,
                                                      const float* __restrict__ bwv,
                                                      const float* __restrict__ pwv,
                                                      const float* __restrict__ pins,
                                                      float* __restrict__ ws) {
  int i = blockIdx.x * 256 + threadIdx.x;
  int* startB = (int*)ws + OFF_STARTB;
  int* startP = (int*)ws + OFF_STARTP;
  uint2* SBW = (uint2*)((int*)ws + OFF_SRTBW);
  uint2* SPW = (uint2*)((int*)ws + OFF_SRTPW);
  if (i < NMSG_B2B) {
    float invb = 1.f / fmaxf(__uint_as_float(((const unsigned*)ws)[0]), 1.f);
    int e = i >> 1, d = i & 1;
    int tg = d ? dst[e] : src[e];
    int o  = d ? src[e] : dst[e];
    int pos = atomicAdd(&startB[tg], 1);
    uint2 v; v.x = (unsigned)o; v.y = __float_as_uint(bwv[e] * invb);
    SBW[pos] = v;
  } else if (i < NMSG_B2B + E2) {
    float invp = 1.f / fmaxf(__uint_as_float(((const unsigned*)ws)[1]), 1.f);
    float cs = fmaxf(sqrtf(fmaxf(ws[2], 1e-6f)), 1e-6f);
    float invc = 1.f / cs;
    int e = i - NMSG_B2B;
    int pin = ppin[e];
    float x0 = pins[pin * 2] * invc;
    float x1 = pins[pin * 2 + 1] * invc;
    float x2 = pwv[e] * invp;
    int pos = atomicAdd(&startP[pblk[e]], 1);
    uint2 v;
    v.x = ((unsigned)f2bf(x1) << 16) | (unsigned)f2bf(x0);
    v.y = __float_as_uint(x2);
    SPW[pos] = v;
  }
}

// ---------------- pack weights ----------------
__global__ __launch_bounds__(256) void prep_kernel(const float* __restrict__ bW1,
                                                   const float* __restrict__ bW2,
                                                   const float* __restrict__ pW1,
                                                   const float* __restrict__ pW2,
                                                   const float* __restrict__ sWm,
                                                   const float* __restrict__ iW1,
                                                   const float* __restrict__ iW2,
                                                   float* __restrict__ ws) {
  unsigned short* Cp  = (unsigned short*)(ws + OFF_CP);
  unsigned short* B2h = (unsigned short*)(ws + OFF_B2H);
  unsigned short* B2l = (unsigned short*)(ws + OFF_B2L);
  unsigned short* P2h = (unsigned short*)(ws + OFF_P2H);
  unsigned short* P2l = (unsigned short*)(ws + OFF_P2L);
  unsigned short* Swp = (unsigned short*)(ws + OFF_SWP);
  unsigned short* I1p = (unsigned short*)(ws + OFF_IW1);
  unsigned short* I2p = (unsigned short*)(ws + OFF_IW2);
  float* wlast = ws + OFF_WLAST;
  float* pextra = ws + OFF_PEXTRA;
  const int total = 156160;
  for (int t = blockIdx.x * 256 + threadIdx.x; t < total; t += gridDim.x * 256) {
    if (t < 49152) {                       // W1cat: 24nt x 4ks -> [P|Q|R]
      int j = t & 7, lane = (t >> 3) & 63, ks = (t >> 9) & 3, nc = t >> 11;
      int col = nc * 16 + (lane & 15), k = ks * 32 + (lane >> 4) * 8 + j;
      float v;
      if (col < 128)      v = bW1[k * 128 + col];
      else if (col < 256) v = bW1[(128 + k) * 128 + (col - 128)];
      else                v = pW1[k * 128 + (col - 256)];
      Cp[t] = f2bf(v);
    } else if (t < 114688) {               // b2h/b2l/p2h/p2l
      int u = (t - 49152) & 16383, which = (t - 49152) >> 14;
      int j = u & 7, lane = (u >> 3) & 63, ks = (u >> 9) & 3, nt = u >> 11;
      int n = nt * 16 + (lane & 15), k = ks * 32 + (lane >> 4) * 8 + j;
      float v = (which < 2) ? bW2[k * 128 + n] : pW2[k * 128 + n];
      unsigned short hi = f2bf(v);
      unsigned short outv = (which & 1) ? f2bf(v - bf2f(hi)) : hi;
      ((which < 2) ? ((which & 1) ? B2l : B2h) : ((which & 1) ? P2l : P2h))[u] = outv;
    } else if (t < 131072) {               // self_W
      int u = t - 114688;
      int j = u & 7, lane = (u >> 3) & 63, ks = (u >> 9) & 3, nt = u >> 11;
      int n = nt * 16 + (lane & 15), k = ks * 32 + (lane >> 4) * 8 + j;
      Swp[u] = f2bf(sWm[k * 128 + n]);
    } else if (t < 139264) {               // in_W1 (K pad 40->64)
      int u = t - 131072;
      int j = u & 7, lane = (u >> 3) & 63, ks = (u >> 9) & 1, nt = u >> 10;
      int n = nt * 16 + (lane & 15), k = ks * 32 + (lane >> 4) * 8 + j;
      I1p[u] = (k < 40) ? f2bf(iW1[k * 128 + n]) : 0;
    } else if (t < 155648) {               // in_W2
      int u = t - 139264;
      int j = u & 7, lane = (u >> 3) & 63, ks = (u >> 9) & 3, nt = u >> 11;
      int n = nt * 16 + (lane & 15), k = ks * 32 + (lane >> 4) * 8 + j;
      I2p[u] = f2bf(iW2[k * 128 + n]);
    } else if (t < 155776) {
      int c = t - 155648;
      wlast[il(c)] = bW1[256 * 128 + c];
    } else {
      int u = t - 155776;
      int r = u >> 7, c = u & 127;
      pextra[r * 128 + il(c)] = pW1[(128 + r) * 128 + c];
    }
  }
}

// ---------------- node kernel: input MLP + PQR (il-layout out), 16 nodes/block -----------
__global__ __launch_bounds__(256) void node_kernel(const float* __restrict__ bfeat,
                                                   const int* __restrict__ rid,
                                                   const float* __restrict__ remb,
                                                   const float* __restrict__ iemb,
                                                   const float* __restrict__ ib1,
                                                   const float* __restrict__ ib2,
                                                   const float* __restrict__ bb1,
                                                   const float* __restrict__ pb1,
                                                   float* __restrict__ ws,
                                                   unsigned short* __restrict__ hb) {
  __shared__ __attribute__((aligned(16))) unsigned short xs[16 * 72];
  __shared__ __attribute__((aligned(16))) unsigned short h1s[16 * 136];
  __shared__ __attribute__((aligned(16))) unsigned short hs[16 * 136];
  const unsigned short* I1p = (const unsigned short*)(ws + OFF_IW1);
  const unsigned short* I2p = (const unsigned short*)(ws + OFF_IW2);
  const unsigned short* Cp  = (const unsigned short*)(ws + OFF_CP);
  float* P = ws + OFF_P;
  float* Q = ws + OFF_Q;
  float* R = ws + OFF_R;
  int tid = threadIdx.x;
  int n0 = blockIdx.x * 16;
  for (int idx = tid; idx < 1024; idx += 256) {
    int m = idx >> 6, c = idx & 63;
    int n = n0 + m;
    float v = 0.f;
    if (c < 16)      v = bfeat[n * 16 + c];
    else if (c < 32) v = remb[rid[n] * 16 + (c - 16)];
    else if (c < 40) v = iemb[(n & 1023) * 8 + (c - 32)];
    xs[m * 72 + c] = f2bf(v);
  }
  __syncthreads();
  int lane = tid & 63, wv = tid >> 6;
  int l15 = lane & 15, q = lane >> 4;
  f32x4 zero = {0.f, 0.f, 0.f, 0.f};
  f32x4 a1[2]; a1[0] = zero; a1[1] = zero;
#pragma unroll
  for (int ks = 0; ks < 2; ks++) {
    short8 af = *(const short8*)(&xs[l15 * 72 + ks * 32 + q * 8]);
#pragma unroll
    for (int j = 0; j < 2; j++) {
      short8 bfr = *(const short8*)(I1p + (((2 * wv + j) * 2 + ks) * 64 + lane) * 8);
      a1[j] = __builtin_amdgcn_mfma_f32_16x16x32_bf16(af, bfr, a1[j], 0, 0, 0);
    }
  }
#pragma unroll
  for (int j = 0; j < 2; j++) {
    int n = (2 * wv + j) * 16 + l15;
    float b = ib1[n];
#pragma unroll
    for (int r = 0; r < 4; r++)
      h1s[(q * 4 + r) * 136 + n] = f2bf(fmaxf(a1[j][r] + b, 0.f));
  }
  __syncthreads();
  f32x4 a2[2]; a2[0] = zero; a2[1] = zero;
#pragma unroll
  for (int ks = 0; ks < 4; ks++) {
    short8 af = *(const short8*)(&h1s[l15 * 136 + ks * 32 + q * 8]);
#pragma unroll
    for (int j = 0; j < 2; j++) {
      short8 bfr = *(const short8*)(I2p + (((2 * wv + j) * 4 + ks) * 64 + lane) * 8);
      a2[j] = __builtin_amdgcn_mfma_f32_16x16x32_bf16(af, bfr, a2[j], 0, 0, 0);
    }
  }
#pragma unroll
  for (int j = 0; j < 2; j++) {
    int n = (2 * wv + j) * 16 + l15;
    float b = ib2[n];
#pragma unroll
    for (int r = 0; r < 4; r++) {
      unsigned short hv = f2bf(fmaxf(a2[j][r] + b, 0.f));
      hs[(q * 4 + r) * 136 + n] = hv;
      hb[(n0 + q * 4 + r) * 128 + n] = hv;
    }
  }
  __syncthreads();
  f32x4 a3[6];
#pragma unroll
  for (int i = 0; i < 6; i++) a3[i] = zero;
#pragma unroll
  for (int ks = 0; ks < 4; ks++) {
    short8 af = *(const short8*)(&hs[l15 * 136 + ks * 32 + q * 8]);
#pragma unroll
    for (int j = 0; j < 6; j++) {
      short8 bfr = *(const short8*)(Cp + (((6 * wv + j) * 4 + ks) * 64 + lane) * 8);
      a3[j] = __builtin_amdgcn_mfma_f32_16x16x32_bf16(af, bfr, a3[j], 0, 0, 0);
    }
  }
#pragma unroll
  for (int j = 0; j < 6; j++) {
    int col = (6 * wv + j) * 16 + l15;
    int arr = col >> 7, cc = col & 127;
    float bias = (arr == 0) ? bb1[cc] : ((arr == 2) ? pb1[cc] : 0.f);
    float* dstp = (arr == 0) ? P : ((arr == 1) ? Q : R);
    int ic = il(cc);
#pragma unroll
    for (int r = 0; r < 4; r++)
      dstp[(n0 + q * 4 + r) * 128 + ic] = a3[j][r] + bias;
  }
}

// ---------------- edge kernel v3 ----------------
__global__ __launch_bounds__(256) void edge_kernel(float* __restrict__ ws) {
  __shared__ float partial[4][128];
  int tid = threadIdx.x;
  int lane = tid & 63, w = tid >> 6;
  if (blockIdx.x < 2048) {                 // b2b: 2 nodes/block, 2 waves per node
    int node = blockIdx.x * 2 + (w >> 1);
    int half = w & 1;
    const int* startB = (const int*)ws + OFF_STARTB;
    const int* cntB   = (const int*)ws + OFF_CNTB;
    const uint2* SBW  = (const uint2*)((const int*)ws + OFF_SRTBW);
    const float* Pm = ws + OFF_P;
    const float* Qm = ws + OFF_Q;
    int e = startB[node];
    int cnt = cntB[node];
    int s = e - cnt;
    int h = (cnt + 1) >> 1;
    int lo = half ? s + h : s;
    int hi = half ? e : s + h;
    float2 p  = *(const float2*)(Pm + node * 128 + 2 * lane);
    float2 wl = *(const float2*)(ws + OFF_WLAST + 2 * lane);
    float a0 = 0.f, a1 = 0.f, b0 = 0.f, b1 = 0.f;
    int m = lo;
    for (; m + 2 <= hi; m += 2) {
      uint2 k0 = SBW[m], k1 = SBW[m + 1];
      float w0 = __uint_as_float(k0.y), w1 = __uint_as_float(k1.y);
      float2 q0 = *(const float2*)(Qm + k0.x * 128 + 2 * lane);
      float2 q1 = *(const float2*)(Qm + k1.x * 128 + 2 * lane);
      a0 += fmaxf(fmaf(w0, wl.x, p.x) + q0.x, 0.f);
      a1 += fmaxf(fmaf(w0, wl.y, p.y) + q0.y, 0.f);
      b0 += fmaxf(fmaf(w1, wl.x, p.x) + q1.x, 0.f);
      b1 += fmaxf(fmaf(w1, wl.y, p.y) + q1.y, 0.f);
    }
    if (m < hi) {
      uint2 k0 = SBW[m];
      float w0 = __uint_as_float(k0.y);
      float2 q0 = *(const float2*)(Qm + k0.x * 128 + 2 * lane);
      a0 += fmaxf(fmaf(w0, wl.x, p.x) + q0.x, 0.f);
      a1 += fmaxf(fmaf(w0, wl.y, p.y) + q0.y, 0.f);
    }
    partial[w][2 * lane]     = a0 + b0;
    partial[w][2 * lane + 1] = a1 + b1;
    __syncthreads();
    int nl = tid >> 7, c = tid & 127;
    ws[OFF_SB + (blockIdx.x * 2 + nl) * 128 + c] = partial[nl * 2][c] + partial[nl * 2 + 1][c];
  } else {                                 // p2b: 4 nodes/block, 1 wave each
    int node = (blockIdx.x - 2048) * 4 + w;
    const int* startP = (const int*)ws + OFF_STARTP;
    const int* cntP   = (const int*)ws + OFF_CNTP;
    const uint2* SPW  = (const uint2*)((const int*)ws + OFF_SRTPW);
    const float* Rm = ws + OFF_R;
    const float* pex = ws + OFF_PEXTRA;
    int e = startP[node];
    int s = e - cntP[node];
    float2 r  = *(const float2*)(Rm + node * 128 + 2 * lane);
    float2 e0 = *(const float2*)(pex + 2 * lane);
    float2 e1 = *(const float2*)(pex + 128 + 2 * lane);
    float2 e2 = *(const float2*)(pex + 256 + 2 * lane);
    float a0 = 0.f, a1 = 0.f, b0 = 0.f, b1 = 0.f;
    int m = s;
    for (; m + 2 <= e; m += 2) {
      uint2 k0 = SPW[m], k1 = SPW[m + 1];
      float x00 = __uint_as_float((k0.x & 0xFFFFu) << 16);
      float x01 = __uint_as_float(k0.x & 0xFFFF0000u);
      float x02 = __uint_as_float(k0.y);
      float x10 = __uint_as_float((k1.x & 0xFFFFu) << 16);
      float x11 = __uint_as_float(k1.x & 0xFFFF0000u);
      float x12 = __uint_as_float(k1.y);
      float t0 = fmaf(x02, e2.x, fmaf(x01, e1.x, fmaf(x00, e0.x, r.x)));
      float t1 = fmaf(x02, e2.y, fmaf(x01, e1.y, fmaf(x00, e0.y, r.y)));
      float u0 = fmaf(x12, e2.x, fmaf(x11, e1.x, fmaf(x10, e0.x, r.x)));
      float u1 = fmaf(x12, e2.y, fmaf(x11, e1.y, fmaf(x10, e0.y, r.y)));
      a0 += fmaxf(t0, 0.f); a1 += fmaxf(t1, 0.f);
      b0 += fmaxf(u0, 0.f); b1 += fmaxf(u1, 0.f);
    }
    if (m < e) {
      uint2 k0 = SPW[m];
      float x00 = __uint_as_float((k0.x & 0xFFFFu) << 16);
      float x01 = __uint_as_float(k0.x & 0xFFFF0000u);
      float x02 = __uint_as_float(k0.y);
      a0 += fmaxf(fmaf(x02, e2.x, fmaf(x01, e1.x, fmaf(x00, e0.x, r.x))), 0.f);
      a1 += fmaxf(fmaf(x02, e2.y, fmaf(x01, e1.y, fmaf(x00, e0.y, r.y))), 0.f);
    }
    ws[OFF_SPA + node * 128 + 2 * lane]     = a0 + b0;
    ws[OFF_SPA + node * 128 + 2 * lane + 1] = a1 + b1;
  }
}

// ---------------- selfln + fused graph tail ----------------
__global__ __launch_bounds__(256) void selfln_kernel(const unsigned short* __restrict__ hb,
                                                     const float* __restrict__ sb,
                                                     const float* __restrict__ lng,
                                                     const float* __restrict__ lnb,
                                                     const float* __restrict__ bb2,
                                                     const float* __restrict__ pb2,
                                                     const float* __restrict__ gW1,
                                                     const float* __restrict__ gb1,
                                                     const float* __restrict__ gW2,
                                                     const float* __restrict__ gb2,
                                                     float* __restrict__ ws,
                                                     float* __restrict__ out) {
  __shared__ __attribute__((aligned(16))) unsigned short A[16 * 648];  // h|Sbh|Sbl|Sph|Spl
  __shared__ float zs[16 * 133];
  __shared__ float muS[16], rsg[16];
  __shared__ float partS[16][16], partQ[16][16];
  __shared__ float psumL[2][128];
  __shared__ int   pmaxL[2][128];
  __shared__ int   isLast;
  int tid = threadIdx.x;
  int n0 = blockIdx.x * 16;
  {
    int m = tid >> 4, o = (tid & 15) * 8;
    *(uint4*)(&A[m * 648 + o]) = *(const uint4*)(hb + (n0 + m) * 128 + o);
  }
  for (int idx = tid; idx < 2048; idx += 256) {
    int m = idx >> 7, c = idx & 127;
    float v = ws[OFF_SB + (n0 + m) * 128 + il(c)];
    unsigned short hi = f2bf(v);
    A[m * 648 + 128 + c] = hi;
    A[m * 648 + 256 + c] = f2bf(v - bf2f(hi));
  }
  for (int idx = tid; idx < 2048; idx += 256) {
    int m = idx >> 7, c = idx & 127;
    float v = ws[OFF_SPA + (n0 + m) * 128 + il(c)];
    unsigned short hi = f2bf(v);
    A[m * 648 + 384 + c] = hi;
    A[m * 648 + 512 + c] = f2bf(v - bf2f(hi));
  }
  __syncthreads();
  int lane = tid & 63, wv = tid >> 6;
  int l15 = lane & 15, q = lane >> 4;
  f32x4 zero = {0.f, 0.f, 0.f, 0.f};
  f32x4 acc[2]; acc[0] = zero; acc[1] = zero;
  const unsigned short* bufs[7] = {
    (const unsigned short*)(ws + OFF_SWP), (const unsigned short*)(ws + OFF_B2H),
    (const unsigned short*)(ws + OFF_B2L), (const unsigned short*)(ws + OFF_B2H),
    (const unsigned short*)(ws + OFF_P2H), (const unsigned short*)(ws + OFF_P2L),
    (const unsigned short*)(ws + OFF_P2H)};
  const int segs[7] = {0, 128, 128, 256, 384, 384, 512};
#pragma unroll
  for (int p = 0; p < 7; p++) {
#pragma unroll
    for (int ks = 0; ks < 4; ks++) {
      short8 af = *(const short8*)(&A[l15 * 648 + segs[p] + ks * 32 + q * 8]);
#pragma unroll
      for (int j = 0; j < 2; j++) {
        short8 bfr = *(const short8*)(bufs[p] + (((2 * wv + j) * 4 + ks) * 64 + lane) * 8);
        acc[j] = __builtin_amdgcn_mfma_f32_16x16x32_bf16(af, bfr, acc[j], 0, 0, 0);
      }
    }
  }
  const int* cntB = (const int*)ws + OFF_CNTB;
  const int* cntP = (const int*)ws + OFF_CNTP;
#pragma unroll
  for (int r = 0; r < 4; r++) {
    int row = q * 4 + r;
    float cb = (float)cntB[n0 + row], cp = (float)cntP[n0 + row];
#pragma unroll
    for (int j = 0; j < 2; j++) {
      int nn = (2 * wv + j) * 16 + l15;
      zs[row * 133 + nn] = acc[j][r] + sb[nn] + cb * bb2[nn] + cp * pb2[nn];
    }
  }
  __syncthreads();
  {
    int r = tid >> 4, g = tid & 15;
    const float* zr = &zs[r * 133 + g * 8];
    float s = 0.f, s2 = 0.f;
#pragma unroll
    for (int i = 0; i < 8; i++) { float v = zr[i]; s += v; s2 += v * v; }
    partS[r][g] = s; partQ[r][g] = s2;
  }
  __syncthreads();
  if (tid < 16) {
    float s = 0.f, s2 = 0.f;
#pragma unroll
    for (int g = 0; g < 16; g++) { s += partS[tid][g]; s2 += partQ[tid][g]; }
    float m = s * (1.f / 128.f);
    float var = s2 * (1.f / 128.f) - m * m;
    muS[tid] = m;
    rsg[tid] = rsqrtf(fmaxf(var, 0.f) + 1e-5f);
  }
  __syncthreads();
  {
    int c = tid & 127, half = tid >> 7;
    float g = lng[c], b = lnb[c];
    float ls = 0.f; int lm = 0x80000000;
    for (int r = half * 8; r < half * 8 + 8; r++) {
      float v = (zs[r * 133 + c] - muS[r]) * rsg[r] * g + b;
      out[(n0 + r) * 128 + c] = v;
      ls += v;
      int e = __float_as_int(v);
      e = e >= 0 ? e : (e ^ 0x7fffffff);
      lm = max(lm, e);
    }
    psumL[half][c] = ls; pmaxL[half][c] = lm;
  }
  __syncthreads();
  if (tid < 128) {
    atomicAdd(&ws[OFF_PSUM + tid], psumL[0][tid] + psumL[1][tid]);
    atomicMax(&((int*)ws)[OFF_PMAX + tid], max(pmaxL[0][tid], pmaxL[1][tid]));
  }
  if (tid < 16) out[N_NODES * HDIM + HDIM + n0 + tid] = 1.0f;
  // ---- graph-embedding tail: last block only ----
  __syncthreads();   // drains this block's atomics (vmcnt(0) before barrier)
  if (tid == 0) {
    __threadfence();
    int v = atomicAdd(&((int*)ws)[3], 1);
    isLast = (v == (int)gridDim.x - 1);
  }
  __syncthreads();
  if (!isLast) return;
  __shared__ float pooled[256];
  __shared__ float gpart[2][128];
  __shared__ float g1[128];
  if (tid < 128) {
    pooled[tid] = atomicAdd(&ws[OFF_PSUM + tid], 0.f) * (1.f / (float)N_NODES);
  } else {
    int e = atomicAdd(&((int*)ws)[OFF_PMAX + (tid - 128)], 0);
    int bits = e >= 0 ? e : (e ^ 0x7fffffff);
    pooled[tid] = __int_as_float(bits);
  }
  __syncthreads();
  {
    int c = tid & 127, g = tid >> 7;
    float acc2 = 0.f;
#pragma unroll 8
    for (int k = g * 128; k < g * 128 + 128; k++) acc2 += pooled[k] * gW1[k * 128 + c];
    gpart[g][c] = acc2;
  }
  __syncthreads();
  if (tid < 128) g1[tid] = fmaxf(gpart[0][tid] + gpart[1][tid] + gb1[tid], 0.f);
  __syncthreads();
  {
    int c = tid & 127, g = tid >> 7;
    float acc2 = 0.f;
#pragma unroll 8
    for (int k = g * 64; k < g * 64 + 64; k++) acc2 += g1[k] * gW2[k * 128 + c];
    gpart[g][c] = acc2;
  }
  __syncthreads();
  if (tid < 128) out[N_NODES * HDIM + tid] = gpart[0][tid] + gpart[1][tid] + gb2[tid];
}

extern "C" void kernel_launch(void* const* d_in, const int* in_sizes, int n_in,
                              void* d_out, int out_size, void* d_ws, size_t ws_size,
                              hipStream_t stream) {
  const float* bfeat = (const float*)d_in[0];
  const int*   rid   = (const int*)d_in[1];
  const int*   bsrc  = (const int*)d_in[2];
  const int*   bdst  = (const int*)d_in[3];
  const float* bw    = (const float*)d_in[4];
  const int*   ppin  = (const int*)d_in[5];
  const int*   pblk  = (const int*)d_in[6];
  const float* pw    = (const float*)d_in[7];
  const float* pins  = (const float*)d_in[8];
  const float* area  = (const float*)d_in[9];
  const float* remb  = (const float*)d_in[10];
  const float* iemb  = (const float*)d_in[11];
  const float* inW1  = (const float*)d_in[12];
  const float* inb1  = (const float*)d_in[13];
  const float* inW2  = (const float*)d_in[14];
  const float* inb2  = (const float*)d_in[15];
  const float* bW1   = (const float*)d_in[16];
  const float* bb1   = (const float*)d_in[17];
  const float* bW2   = (const float*)d_in[18];
  const float* bb2   = (const float*)d_in[19];
  const float* pW1   = (const float*)d_in[20];
  const float* pb1   = (const float*)d_in[21];
  const float* pW2   = (const float*)d_in[22];
  const float* pb2   = (const float*)d_in[23];
  const float* sW    = (const float*)d_in[24];
  const float* sb    = (const float*)d_in[25];
  const float* lng   = (const float*)d_in[26];
  const float* lnb   = (const float*)d_in[27];
  const float* gW1   = (const float*)d_in[28];
  const float* gb1   = (const float*)d_in[29];
  const float* gW2   = (const float*)d_in[30];
  const float* gb2   = (const float*)d_in[31];

  float* ws  = (float*)d_ws;
  float* out = (float*)d_out;
  unsigned short* hb = (unsigned short*)(ws + OFF_HB);
  int* cntB = (int*)ws + OFF_CNTB;

  hipMemsetAsync(d_ws, 0, 260 * sizeof(float), stream);
  hipMemsetAsync((void*)cntB, 0, 4 * 4096 * sizeof(int), stream);
  prehist_kernel<<<97 + (NMSG_B2B + E2) / 256, 256, 0, stream>>>(bw, pw, area,
                                                                 bsrc, bdst, pblk, ws);
  scan_kernel<<<2, 1024, 0, stream>>>(ws);
  scatter_kernel<<<(NMSG_B2B + E2 + 255) / 256, 256, 0, stream>>>(bsrc, bdst, pblk, ppin,
                                                                  bw, pw, pins, ws);
  prep_kernel<<<128, 256, 0, stream>>>(bW1, bW2, pW1, pW2, sW, inW1, inW2, ws);
  node_kernel<<<N_NODES / 16, 256, 0, stream>>>(bfeat, rid, remb, iemb,
                                                inb1, inb2, bb1, pb1, ws, hb);
  edge_kernel<<<2048 + 1024, 256, 0, stream>>>(ws);
  selfln_kernel<<<N_NODES / 16, 256, 0, stream>>>(hb, sb, lng, lnb, bb2, pb2,
                                                  gW1, gb1, gW2, gb2, ws, out);
}

// Round 7
// 232.513 us; speedup vs baseline: 2.8094x; 1.0802x over previous
//
#include <hip/hip_runtime.h>
#include <hip/hip_bf16.h>

#define N_NODES 4096
#define HDIM    128
#define E1      131072
#define E2      131072
#define NMSG_B2B (2 * E1)

// ---- workspace layout (float units) ----
#define OFF_PSUM   4
#define OFF_PMAX   132
// ws[3] = selfln completion counter
#define OFF_HB     260                               // h bf16: 524288 u16
#define OFF_P      (OFF_HB + 262144)                 // P (il layout) f32 [4096][128]
#define OFF_Q      (OFF_P + 524288)
#define OFF_R      (OFF_Q + 524288)
#define OFF_SB     (OFF_R + 524288)                  // S_b2b (il layout)
#define OFF_SPA    (OFF_SB + 524288)                 // S_p2b (il layout)
#define OFF_CP     (OFF_SPA + 524288)                // W1cat pack 49152 u16
#define OFF_B2H    (OFF_CP + 24576)
#define OFF_B2L    (OFF_B2H + 8192)
#define OFF_P2H    (OFF_B2L + 8192)
#define OFF_P2L    (OFF_P2H + 8192)
#define OFF_SWP    (OFF_P2L + 8192)
#define OFF_IW1    (OFF_SWP + 8192)
#define OFF_IW2    (OFF_IW1 + 4096)
#define OFF_WLAST  (OFF_IW2 + 8192)                  // il layout f32[128]
#define OFF_PEXTRA (OFF_WLAST + 128)                 // 3 rows, il layout
#define OFF_CNTB   (OFF_PEXTRA + 384)
#define OFF_STARTB (OFF_CNTB + 4096)
#define OFF_CNTP   (OFF_STARTB + 4096)
#define OFF_STARTP (OFF_CNTP + 4096)
#define OFF_SRTBW  (OFF_STARTP + 4096)               // uint2[262144]: {oth, f32 wsc}
#define OFF_SRTPW  (OFF_SRTBW + 524288)              // uint2[131072]: {bf16x2(x0,x1), f32 x2}
#define WS_FLOATS  (OFF_SRTPW + 262144)

typedef short short8 __attribute__((ext_vector_type(8)));
typedef float f32x4 __attribute__((ext_vector_type(4)));

__device__ __forceinline__ unsigned short f2bf(float f) {
  union { float f; unsigned u; } v; v.f = f;
  unsigned r = v.u + 0x7fffu + ((v.u >> 16) & 1u);   // RNE
  return (unsigned short)(r >> 16);
}
__device__ __forceinline__ float bf2f(unsigned short h) {
  return __uint_as_float((unsigned)h << 16);
}
__device__ __forceinline__ int il(int c) { return ((c & 63) << 1) | (c >> 6); }

// ================ setup: reduces + pmax-init + histogram + weight packing =============
__global__ __launch_bounds__(256) void setup_kernel(const float* __restrict__ b2bw,
                                                    const float* __restrict__ p2bw,
                                                    const float* __restrict__ area,
                                                    const int* __restrict__ src,
                                                    const int* __restrict__ dst,
                                                    const int* __restrict__ pblk,
                                                    const float* __restrict__ bW1,
                                                    const float* __restrict__ bW2,
                                                    const float* __restrict__ pW1,
                                                    const float* __restrict__ pW2,
                                                    const float* __restrict__ sWm,
                                                    const float* __restrict__ iW1,
                                                    const float* __restrict__ iW2,
                                                    float* __restrict__ ws) {
  __shared__ float red[256];
  int b = blockIdx.x, t = threadIdx.x;
  if (b < 32) {
    float m = 0.f;
    for (int i = b * 256 + t; i < E1; i += 32 * 256) m = fmaxf(m, fabsf(b2bw[i]));
    red[t] = m; __syncthreads();
    for (int s = 128; s > 0; s >>= 1) { if (t < s) red[t] = fmaxf(red[t], red[t + s]); __syncthreads(); }
    if (t == 0) atomicMax((unsigned*)&ws[0], __float_as_uint(red[0]));
  } else if (b < 64) {
    float m = 0.f;
    for (int i = (b - 32) * 256 + t; i < E2; i += 32 * 256) m = fmaxf(m, fabsf(p2bw[i]));
    red[t] = m; __syncthreads();
    for (int s = 128; s > 0; s >>= 1) { if (t < s) red[t] = fmaxf(red[t], red[t + s]); __syncthreads(); }
    if (t == 0) atomicMax((unsigned*)&ws[1], __float_as_uint(red[0]));
  } else if (b < 96) {
    float s0 = 0.f;
    for (int i = (b - 64) * 256 + t; i < N_NODES; i += 32 * 256) s0 += area[i];
    red[t] = s0; __syncthreads();
    for (int s = 128; s > 0; s >>= 1) { if (t < s) red[t] += red[t + s]; __syncthreads(); }
    if (t == 0) atomicAdd(&ws[2], red[0]);
  } else if (b == 96) {
    if (t < HDIM) ((int*)ws)[OFF_PMAX + t] = 0x80000000;
  } else if (b < 1633) {                   // histogram over 393216 items
    int i = (b - 97) * 256 + t;
    int* cntB = (int*)ws + OFF_CNTB;
    int* cntP = (int*)ws + OFF_CNTP;
    if (i < NMSG_B2B) {
      int e = i >> 1;
      int tg = (i & 1) ? dst[e] : src[e];
      atomicAdd(&cntB[tg], 1);
    } else if (i < NMSG_B2B + E2) {
      atomicAdd(&cntP[pblk[i - NMSG_B2B]], 1);
    }
  } else {                                 // weight packing (128 blocks, grid-stride)
    unsigned short* Cp  = (unsigned short*)(ws + OFF_CP);
    unsigned short* B2h = (unsigned short*)(ws + OFF_B2H);
    unsigned short* B2l = (unsigned short*)(ws + OFF_B2L);
    unsigned short* P2h = (unsigned short*)(ws + OFF_P2H);
    unsigned short* P2l = (unsigned short*)(ws + OFF_P2L);
    unsigned short* Swp = (unsigned short*)(ws + OFF_SWP);
    unsigned short* I1p = (unsigned short*)(ws + OFF_IW1);
    unsigned short* I2p = (unsigned short*)(ws + OFF_IW2);
    float* wlast = ws + OFF_WLAST;
    float* pextra = ws + OFF_PEXTRA;
    const int total = 156160;
    for (int x = (b - 1633) * 256 + t; x < total; x += 128 * 256) {
      if (x < 49152) {                     // W1cat: 24nt x 4ks -> [P|Q|R]
        int j = x & 7, lane = (x >> 3) & 63, ks = (x >> 9) & 3, nc = x >> 11;
        int col = nc * 16 + (lane & 15), k = ks * 32 + (lane >> 4) * 8 + j;
        float v;
        if (col < 128)      v = bW1[k * 128 + col];
        else if (col < 256) v = bW1[(128 + k) * 128 + (col - 128)];
        else                v = pW1[k * 128 + (col - 256)];
        Cp[x] = f2bf(v);
      } else if (x < 114688) {             // b2h/b2l/p2h/p2l
        int u = (x - 49152) & 16383, which = (x - 49152) >> 14;
        int j = u & 7, lane = (u >> 3) & 63, ks = (u >> 9) & 3, nt = u >> 11;
        int n = nt * 16 + (lane & 15), k = ks * 32 + (lane >> 4) * 8 + j;
        float v = (which < 2) ? bW2[k * 128 + n] : pW2[k * 128 + n];
        unsigned short hi = f2bf(v);
        unsigned short outv = (which & 1) ? f2bf(v - bf2f(hi)) : hi;
        ((which < 2) ? ((which & 1) ? B2l : B2h) : ((which & 1) ? P2l : P2h))[u] = outv;
      } else if (x < 131072) {             // self_W
        int u = x - 114688;
        int j = u & 7, lane = (u >> 3) & 63, ks = (u >> 9) & 3, nt = u >> 11;
        int n = nt * 16 + (lane & 15), k = ks * 32 + (lane >> 4) * 8 + j;
        Swp[u] = f2bf(sWm[k * 128 + n]);
      } else if (x < 139264) {             // in_W1 (K pad 40->64)
        int u = x - 131072;
        int j = u & 7, lane = (u >> 3) & 63, ks = (u >> 9) & 1, nt = u >> 10;
        int n = nt * 16 + (lane & 15), k = ks * 32 + (lane >> 4) * 8 + j;
        I1p[u] = (k < 40) ? f2bf(iW1[k * 128 + n]) : 0;
      } else if (x < 155648) {             // in_W2
        int u = x - 139264;
        int j = u & 7, lane = (u >> 3) & 63, ks = (u >> 9) & 3, nt = u >> 11;
        int n = nt * 16 + (lane & 15), k = ks * 32 + (lane >> 4) * 8 + j;
        I2p[u] = f2bf(iW2[k * 128 + n]);
      } else if (x < 155776) {
        int c = x - 155648;
        wlast[il(c)] = bW1[256 * 128 + c];
      } else {
        int u = x - 155776;
        int r = u >> 7, c = u & 127;
        pextra[r * 128 + il(c)] = pW1[(128 + r) * 128 + c];
      }
    }
  }
}

__global__ __launch_bounds__(1024) void scan_kernel(float* __restrict__ ws) {
  const int* cnt = (const int*)ws + (blockIdx.x == 0 ? OFF_CNTB : OFF_CNTP);
  int* start     = (int*)ws + (blockIdx.x == 0 ? OFF_STARTB : OFF_STARTP);
  __shared__ int s[1024];
  int t = threadIdx.x;
  int base = t * 4;
  int a0 = cnt[base], a1 = cnt[base + 1], a2 = cnt[base + 2], a3 = cnt[base + 3];
  int sum = a0 + a1 + a2 + a3;
  s[t] = sum; __syncthreads();
  for (int off = 1; off < 1024; off <<= 1) {
    int v = (t >= off) ? s[t - off] : 0;
    __syncthreads();
    s[t] += v;
    __syncthreads();
  }
  int excl = s[t] - sum;
  start[base]     = excl;
  start[base + 1] = excl + a0;
  start[base + 2] = excl + a0 + a1;
  start[base + 3] = excl + a0 + a1 + a2;
}

// ================ mid: scatter (768 blocks) + node MLP/PQR (256 blocks) ==============
__global__ __launch_bounds__(512) void mid_kernel(const int* __restrict__ src,
                                                  const int* __restrict__ dst,
                                                  const int* __restrict__ pblk,
                                                  const int* __restrict__ ppin,
                                                  const float* __restrict__ bwv,
                                                  const float* __restrict__ pwv,
                                                  const float* __restrict__ pins,
                                                  const float* __restrict__ bfeat,
                                                  const int* __restrict__ rid,
                                                  const float* __restrict__ remb,
                                                  const float* __restrict__ iemb,
                                                  const float* __restrict__ ib1,
                                                  const float* __restrict__ ib2,
                                                  const float* __restrict__ bb1,
                                                  const float* __restrict__ pb1,
                                                  float* __restrict__ ws,
                                                  unsigned short* __restrict__ hb) {
  __shared__ __attribute__((aligned(16))) unsigned short xs[16 * 72];
  __shared__ __attribute__((aligned(16))) unsigned short h1s[16 * 136];
  __shared__ __attribute__((aligned(16))) unsigned short hs[16 * 136];
  int tid = threadIdx.x;
  if (blockIdx.x < 768) {
    // ---- scatter + per-edge feature precompute ----
    int i = blockIdx.x * 512 + tid;
    int* startB = (int*)ws + OFF_STARTB;
    int* startP = (int*)ws + OFF_STARTP;
    uint2* SBW = (uint2*)((int*)ws + OFF_SRTBW);
    uint2* SPW = (uint2*)((int*)ws + OFF_SRTPW);
    if (i < NMSG_B2B) {
      float invb = 1.f / fmaxf(__uint_as_float(((const unsigned*)ws)[0]), 1.f);
      int e = i >> 1, d = i & 1;
      int tg = d ? dst[e] : src[e];
      int o  = d ? src[e] : dst[e];
      int pos = atomicAdd(&startB[tg], 1);
      uint2 v; v.x = (unsigned)o; v.y = __float_as_uint(bwv[e] * invb);
      SBW[pos] = v;
    } else {
      float invp = 1.f / fmaxf(__uint_as_float(((const unsigned*)ws)[1]), 1.f);
      float cs = fmaxf(sqrtf(fmaxf(ws[2], 1e-6f)), 1e-6f);
      float invc = 1.f / cs;
      int e = i - NMSG_B2B;
      int pin = ppin[e];
      float x0 = pins[pin * 2] * invc;
      float x1 = pins[pin * 2 + 1] * invc;
      float x2 = pwv[e] * invp;
      int pos = atomicAdd(&startP[pblk[e]], 1);
      uint2 v;
      v.x = ((unsigned)f2bf(x1) << 16) | (unsigned)f2bf(x0);
      v.y = __float_as_uint(x2);
      SPW[pos] = v;
    }
    return;
  }
  // ---- node: input MLP + PQR, 16 nodes/block, 8 waves ----
  const unsigned short* I1p = (const unsigned short*)(ws + OFF_IW1);
  const unsigned short* I2p = (const unsigned short*)(ws + OFF_IW2);
  const unsigned short* Cp  = (const unsigned short*)(ws + OFF_CP);
  float* P = ws + OFF_P;
  float* Q = ws + OFF_Q;
  float* R = ws + OFF_R;
  int n0 = (blockIdx.x - 768) * 16;
  for (int idx = tid; idx < 1024; idx += 512) {
    int m = idx >> 6, c = idx & 63;
    int n = n0 + m;
    float v = 0.f;
    if (c < 16)      v = bfeat[n * 16 + c];
    else if (c < 32) v = remb[rid[n] * 16 + (c - 16)];
    else if (c < 40) v = iemb[(n & 1023) * 8 + (c - 32)];
    xs[m * 72 + c] = f2bf(v);
  }
  __syncthreads();
  int lane = tid & 63, wv = tid >> 6;   // wv 0..7
  int l15 = lane & 15, q = lane >> 4;
  f32x4 zero = {0.f, 0.f, 0.f, 0.f};
  f32x4 a1 = zero;
#pragma unroll
  for (int ks = 0; ks < 2; ks++) {
    short8 af = *(const short8*)(&xs[l15 * 72 + ks * 32 + q * 8]);
    short8 bfr = *(const short8*)(I1p + ((wv * 2 + ks) * 64 + lane) * 8);
    a1 = __builtin_amdgcn_mfma_f32_16x16x32_bf16(af, bfr, a1, 0, 0, 0);
  }
  {
    int n = wv * 16 + l15;
    float b = ib1[n];
#pragma unroll
    for (int r = 0; r < 4; r++)
      h1s[(q * 4 + r) * 136 + n] = f2bf(fmaxf(a1[r] + b, 0.f));
  }
  __syncthreads();
  f32x4 a2 = zero;
#pragma unroll
  for (int ks = 0; ks < 4; ks++) {
    short8 af = *(const short8*)(&h1s[l15 * 136 + ks * 32 + q * 8]);
    short8 bfr = *(const short8*)(I2p + ((wv * 4 + ks) * 64 + lane) * 8);
    a2 = __builtin_amdgcn_mfma_f32_16x16x32_bf16(af, bfr, a2, 0, 0, 0);
  }
  {
    int n = wv * 16 + l15;
    float b = ib2[n];
#pragma unroll
    for (int r = 0; r < 4; r++) {
      unsigned short hv = f2bf(fmaxf(a2[r] + b, 0.f));
      hs[(q * 4 + r) * 136 + n] = hv;
      hb[(n0 + q * 4 + r) * 128 + n] = hv;
    }
  }
  __syncthreads();
  f32x4 a3[3];
#pragma unroll
  for (int i = 0; i < 3; i++) a3[i] = zero;
#pragma unroll
  for (int ks = 0; ks < 4; ks++) {
    short8 af = *(const short8*)(&hs[l15 * 136 + ks * 32 + q * 8]);
#pragma unroll
    for (int j = 0; j < 3; j++) {
      short8 bfr = *(const short8*)(Cp + (((3 * wv + j) * 4 + ks) * 64 + lane) * 8);
      a3[j] = __builtin_amdgcn_mfma_f32_16x16x32_bf16(af, bfr, a3[j], 0, 0, 0);
    }
  }
#pragma unroll
  for (int j = 0; j < 3; j++) {
    int col = (3 * wv + j) * 16 + l15;
    int arr = col >> 7, cc = col & 127;
    float bias = (arr == 0) ? bb1[cc] : ((arr == 2) ? pb1[cc] : 0.f);
    float* dstp = (arr == 0) ? P : ((arr == 1) ? Q : R);
    int ic = il(cc);
#pragma unroll
    for (int r = 0; r < 4; r++)
      dstp[(n0 + q * 4 + r) * 128 + ic] = a3[j][r] + bias;
  }
}

// ================ edge kernel ================
__global__ __launch_bounds__(256) void edge_kernel(float* __restrict__ ws) {
  __shared__ float partial[4][128];
  int tid = threadIdx.x;
  int lane = tid & 63, w = tid >> 6;
  if (blockIdx.x < 2048) {                 // b2b: 2 nodes/block, 2 waves per node
    int node = blockIdx.x * 2 + (w >> 1);
    int half = w & 1;
    const int* startB = (const int*)ws + OFF_STARTB;
    const int* cntB   = (const int*)ws + OFF_CNTB;
    const uint2* SBW  = (const uint2*)((const int*)ws + OFF_SRTBW);
    const float* Pm = ws + OFF_P;
    const float* Qm = ws + OFF_Q;
    int e = startB[node];
    int cnt = cntB[node];
    int s = e - cnt;
    int h = (cnt + 1) >> 1;
    int lo = half ? s + h : s;
    int hi = half ? e : s + h;
    float2 p  = *(const float2*)(Pm + node * 128 + 2 * lane);
    float2 wl = *(const float2*)(ws + OFF_WLAST + 2 * lane);
    float a0 = 0.f, a1 = 0.f, b0 = 0.f, b1 = 0.f;
    float c0 = 0.f, c1 = 0.f, d0 = 0.f, d1 = 0.f;
    int m = lo;
    for (; m + 4 <= hi; m += 4) {
      uint2 k0 = SBW[m], k1 = SBW[m + 1], k2 = SBW[m + 2], k3 = SBW[m + 3];
      float2 q0 = *(const float2*)(Qm + k0.x * 128 + 2 * lane);
      float2 q1 = *(const float2*)(Qm + k1.x * 128 + 2 * lane);
      float2 q2 = *(const float2*)(Qm + k2.x * 128 + 2 * lane);
      float2 q3 = *(const float2*)(Qm + k3.x * 128 + 2 * lane);
      float w0 = __uint_as_float(k0.y), w1 = __uint_as_float(k1.y);
      float w2 = __uint_as_float(k2.y), w3 = __uint_as_float(k3.y);
      a0 += fmaxf(fmaf(w0, wl.x, p.x) + q0.x, 0.f);
      a1 += fmaxf(fmaf(w0, wl.y, p.y) + q0.y, 0.f);
      b0 += fmaxf(fmaf(w1, wl.x, p.x) + q1.x, 0.f);
      b1 += fmaxf(fmaf(w1, wl.y, p.y) + q1.y, 0.f);
      c0 += fmaxf(fmaf(w2, wl.x, p.x) + q2.x, 0.f);
      c1 += fmaxf(fmaf(w2, wl.y, p.y) + q2.y, 0.f);
      d0 += fmaxf(fmaf(w3, wl.x, p.x) + q3.x, 0.f);
      d1 += fmaxf(fmaf(w3, wl.y, p.y) + q3.y, 0.f);
    }
    for (; m < hi; m++) {
      uint2 k0 = SBW[m];
      float w0 = __uint_as_float(k0.y);
      float2 q0 = *(const float2*)(Qm + k0.x * 128 + 2 * lane);
      a0 += fmaxf(fmaf(w0, wl.x, p.x) + q0.x, 0.f);
      a1 += fmaxf(fmaf(w0, wl.y, p.y) + q0.y, 0.f);
    }
    partial[w][2 * lane]     = (a0 + b0) + (c0 + d0);
    partial[w][2 * lane + 1] = (a1 + b1) + (c1 + d1);
    __syncthreads();
    int nl = tid >> 7, c = tid & 127;
    ws[OFF_SB + (blockIdx.x * 2 + nl) * 128 + c] = partial[nl * 2][c] + partial[nl * 2 + 1][c];
  } else {                                 // p2b: 4 nodes/block, 1 wave each
    int node = (blockIdx.x - 2048) * 4 + w;
    const int* startP = (const int*)ws + OFF_STARTP;
    const int* cntP   = (const int*)ws + OFF_CNTP;
    const uint2* SPW  = (const uint2*)((const int*)ws + OFF_SRTPW);
    const float* Rm = ws + OFF_R;
    const float* pex = ws + OFF_PEXTRA;
    int e = startP[node];
    int s = e - cntP[node];
    float2 r  = *(const float2*)(Rm + node * 128 + 2 * lane);
    float2 e0 = *(const float2*)(pex + 2 * lane);
    float2 e1 = *(const float2*)(pex + 128 + 2 * lane);
    float2 e2 = *(const float2*)(pex + 256 + 2 * lane);
    float a0 = 0.f, a1 = 0.f, b0 = 0.f, b1 = 0.f;
    float c0 = 0.f, c1 = 0.f, d0 = 0.f, d1 = 0.f;
    int m = s;
    for (; m + 4 <= e; m += 4) {
      uint2 k0 = SPW[m], k1 = SPW[m + 1], k2 = SPW[m + 2], k3 = SPW[m + 3];
      float x00 = __uint_as_float((k0.x & 0xFFFFu) << 16);
      float x01 = __uint_as_float(k0.x & 0xFFFF0000u);
      float x02 = __uint_as_float(k0.y);
      float x10 = __uint_as_float((k1.x & 0xFFFFu) << 16);
      float x11 = __uint_as_float(k1.x & 0xFFFF0000u);
      float x12 = __uint_as_float(k1.y);
      float x20 = __uint_as_float((k2.x & 0xFFFFu) << 16);
      float x21 = __uint_as_float(k2.x & 0xFFFF0000u);
      float x22 = __uint_as_float(k2.y);
      float x30 = __uint_as_float((k3.x & 0xFFFFu) << 16);
      float x31 = __uint_as_float(k3.x & 0xFFFF0000u);
      float x32 = __uint_as_float(k3.y);
      a0 += fmaxf(fmaf(x02, e2.x, fmaf(x01, e1.x, fmaf(x00, e0.x, r.x))), 0.f);
      a1 += fmaxf(fmaf(x02, e2.y, fmaf(x01, e1.y, fmaf(x00, e0.y, r.y))), 0.f);
      b0 += fmaxf(fmaf(x12, e2.x, fmaf(x11, e1.x, fmaf(x10, e0.x, r.x))), 0.f);
      b1 += fmaxf(fmaf(x12, e2.y, fmaf(x11, e1.y, fmaf(x10, e0.y, r.y))), 0.f);
      c0 += fmaxf(fmaf(x22, e2.x, fmaf(x21, e1.x, fmaf(x20, e0.x, r.x))), 0.f);
      c1 += fmaxf(fmaf(x22, e2.y, fmaf(x21, e1.y, fmaf(x20, e0.y, r.y))), 0.f);
      d0 += fmaxf(fmaf(x32, e2.x, fmaf(x31, e1.x, fmaf(x30, e0.x, r.x))), 0.f);
      d1 += fmaxf(fmaf(x32, e2.y, fmaf(x31, e1.y, fmaf(x30, e0.y, r.y))), 0.f);
    }
    for (; m < e; m++) {
      uint2 k0 = SPW[m];
      float x00 = __uint_as_float((k0.x & 0xFFFFu) << 16);
      float x01 = __uint_as_float(k0.x & 0xFFFF0000u);
      float x02 = __uint_as_float(k0.y);
      a0 += fmaxf(fmaf(x02, e2.x, fmaf(x01, e1.x, fmaf(x00, e0.x, r.x))), 0.f);
      a1 += fmaxf(fmaf(x02, e2.y, fmaf(x01, e1.y, fmaf(x00, e0.y, r.y))), 0.f);
    }
    ws[OFF_SPA + node * 128 + 2 * lane]     = (a0 + b0) + (c0 + d0);
    ws[OFF_SPA + node * 128 + 2 * lane + 1] = (a1 + b1) + (c1 + d1);
  }
}

// ================ selfln (512 thr, 8 waves) + fused graph tail ================
__global__ __launch_bounds__(512) void selfln_kernel(const unsigned short* __restrict__ hb,
                                                     const float* __restrict__ sb,
                                                     const float* __restrict__ lng,
                                                     const float* __restrict__ lnb,
                                                     const float* __restrict__ bb2,
                                                     const float* __restrict__ pb2,
                                                     const float* __restrict__ gW1,
                                                     const float* __restrict__ gb1,
                                                     const float* __restrict__ gW2,
                                                     const float* __restrict__ gb2,
                                                     float* __restrict__ ws,
                                                     float* __restrict__ out) {
  __shared__ __attribute__((aligned(16))) unsigned short A[16 * 648];  // h|Sbh|Sbl|Sph|Spl
  __shared__ float zs[16 * 133];
  __shared__ float muS[16], rsg[16];
  __shared__ float partS[16][16], partQ[16][16];
  __shared__ float psumL[4][128];
  __shared__ int   pmaxL[4][128];
  __shared__ int   isLast;
  int tid = threadIdx.x;
  int n0 = blockIdx.x * 16;
  if (tid < 256) {
    int m = tid >> 4, o = (tid & 15) * 8;
    *(uint4*)(&A[m * 648 + o]) = *(const uint4*)(hb + (n0 + m) * 128 + o);
  }
  for (int idx = tid; idx < 2048; idx += 512) {
    int m = idx >> 7, c = idx & 127;
    float v = ws[OFF_SB + (n0 + m) * 128 + il(c)];
    unsigned short hi = f2bf(v);
    A[m * 648 + 128 + c] = hi;
    A[m * 648 + 256 + c] = f2bf(v - bf2f(hi));
  }
  for (int idx = tid; idx < 2048; idx += 512) {
    int m = idx >> 7, c = idx & 127;
    float v = ws[OFF_SPA + (n0 + m) * 128 + il(c)];
    unsigned short hi = f2bf(v);
    A[m * 648 + 384 + c] = hi;
    A[m * 648 + 512 + c] = f2bf(v - bf2f(hi));
  }
  __syncthreads();
  int lane = tid & 63, wv = tid >> 6;   // 0..7, one 16-col tile each
  int l15 = lane & 15, q = lane >> 4;
  f32x4 zero = {0.f, 0.f, 0.f, 0.f};
  f32x4 acc = zero;
  const unsigned short* bufs[7] = {
    (const unsigned short*)(ws + OFF_SWP), (const unsigned short*)(ws + OFF_B2H),
    (const unsigned short*)(ws + OFF_B2L), (const unsigned short*)(ws + OFF_B2H),
    (const unsigned short*)(ws + OFF_P2H), (const unsigned short*)(ws + OFF_P2L),
    (const unsigned short*)(ws + OFF_P2H)};
  const int segs[7] = {0, 128, 128, 256, 384, 384, 512};
#pragma unroll
  for (int p = 0; p < 7; p++) {
#pragma unroll
    for (int ks = 0; ks < 4; ks++) {
      short8 af = *(const short8*)(&A[l15 * 648 + segs[p] + ks * 32 + q * 8]);
      short8 bfr = *(const short8*)(bufs[p] + ((wv * 4 + ks) * 64 + lane) * 8);
      acc = __builtin_amdgcn_mfma_f32_16x16x32_bf16(af, bfr, acc, 0, 0, 0);
    }
  }
  const int* cntB = (const int*)ws + OFF_CNTB;
  const int* cntP = (const int*)ws + OFF_CNTP;
  {
    int nn = wv * 16 + l15;
    float sbv = sb[nn], b2v = bb2[nn], p2v = pb2[nn];
#pragma unroll
    for (int r = 0; r < 4; r++) {
      int row = q * 4 + r;
      float cb = (float)cntB[n0 + row], cp = (float)cntP[n0 + row];
      zs[row * 133 + nn] = acc[r] + sbv + cb * b2v + cp * p2v;
    }
  }
  __syncthreads();
  if (tid < 256) {
    int r = tid >> 4, g = tid & 15;
    const float* zr = &zs[r * 133 + g * 8];
    float s = 0.f, s2 = 0.f;
#pragma unroll
    for (int i = 0; i < 8; i++) { float v = zr[i]; s += v; s2 += v * v; }
    partS[r][g] = s; partQ[r][g] = s2;
  }
  __syncthreads();
  if (tid < 16) {
    float s = 0.f, s2 = 0.f;
#pragma unroll
    for (int g = 0; g < 16; g++) { s += partS[tid][g]; s2 += partQ[tid][g]; }
    float m = s * (1.f / 128.f);
    float var = s2 * (1.f / 128.f) - m * m;
    muS[tid] = m;
    rsg[tid] = rsqrtf(fmaxf(var, 0.f) + 1e-5f);
  }
  __syncthreads();
  {
    int c = tid & 127, grp = tid >> 7;   // grp 0..3, 4 rows each
    float g = lng[c], b = lnb[c];
    float ls = 0.f; int lm = 0x80000000;
    for (int r = grp * 4; r < grp * 4 + 4; r++) {
      float v = (zs[r * 133 + c] - muS[r]) * rsg[r] * g + b;
      out[(n0 + r) * 128 + c] = v;
      ls += v;
      int e = __float_as_int(v);
      e = e >= 0 ? e : (e ^ 0x7fffffff);
      lm = max(lm, e);
    }
    psumL[grp][c] = ls; pmaxL[grp][c] = lm;
  }
  __syncthreads();
  if (tid < 128) {
    atomicAdd(&ws[OFF_PSUM + tid],
              (psumL[0][tid] + psumL[1][tid]) + (psumL[2][tid] + psumL[3][tid]));
    atomicMax(&((int*)ws)[OFF_PMAX + tid],
              max(max(pmaxL[0][tid], pmaxL[1][tid]), max(pmaxL[2][tid], pmaxL[3][tid])));
  }
  if (tid < 16) out[N_NODES * HDIM + HDIM + n0 + tid] = 1.0f;
  // ---- graph-embedding tail: last block only ----
  __syncthreads();
  if (tid == 0) {
    __threadfence();
    int v = atomicAdd(&((int*)ws)[3], 1);
    isLast = (v == (int)gridDim.x - 1);
  }
  __syncthreads();
  if (!isLast) return;
  __shared__ float pooled[256];
  __shared__ float gpart[4][128];
  __shared__ float g1[128];
  if (tid < 128) {
    pooled[tid] = atomicAdd(&ws[OFF_PSUM + tid], 0.f) * (1.f / (float)N_NODES);
  } else if (tid < 256) {
    int e = atomicAdd(&((int*)ws)[OFF_PMAX + (tid - 128)], 0);
    int bits = e >= 0 ? e : (e ^ 0x7fffffff);
    pooled[tid] = __int_as_float(bits);
  }
  __syncthreads();
  {
    int c = tid & 127, g = tid >> 7;
    float acc2 = 0.f;
#pragma unroll 8
    for (int k = g * 64; k < g * 64 + 64; k++) acc2 += pooled[k] * gW1[k * 128 + c];
    gpart[g][c] = acc2;
  }
  __syncthreads();
  if (tid < 128)
    g1[tid] = fmaxf((gpart[0][tid] + gpart[1][tid]) + (gpart[2][tid] + gpart[3][tid]) + gb1[tid], 0.f);
  __syncthreads();
  {
    int c = tid & 127, g = tid >> 7;
    float acc2 = 0.f;
#pragma unroll 8
    for (int k = g * 32; k < g * 32 + 32; k++) acc2 += g1[k] * gW2[k * 128 + c];
    gpart[g][c] = acc2;
  }
  __syncthreads();
  if (tid < 128)
    out[N_NODES * HDIM + tid] =
        (gpart[0][tid] + gpart[1][tid]) + (gpart[2][tid] + gpart[3][tid]) + gb2[tid];
}

extern "C" void kernel_launch(void* const* d_in, const int* in_sizes, int n_in,
                              void* d_out, int out_size, void* d_ws, size_t ws_size,
                              hipStream_t stream) {
  const float* bfeat = (const float*)d_in[0];
  const int*   rid   = (const int*)d_in[1];
  const int*   bsrc  = (const int*)d_in[2];
  const int*   bdst  = (const int*)d_in[3];
  const float* bw    = (const float*)d_in[4];
  const int*   ppin  = (const int*)d_in[5];
  const int*   pblk  = (const int*)d_in[6];
  const float* pw    = (const float*)d_in[7];
  const float* pins  = (const float*)d_in[8];
  const float* area  = (const float*)d_in[9];
  const float* remb  = (const float*)d_in[10];
  const float* iemb  = (const float*)d_in[11];
  const float* inW1  = (const float*)d_in[12];
  const float* inb1  = (const float*)d_in[13];
  const float* inW2  = (const float*)d_in[14];
  const float* inb2  = (const float*)d_in[15];
  const float* bW1   = (const float*)d_in[16];
  const float* bb1   = (const float*)d_in[17];
  const float* bW2   = (const float*)d_in[18];
  const float* bb2   = (const float*)d_in[19];
  const float* pW1   = (const float*)d_in[20];
  const float* pb1   = (const float*)d_in[21];
  const float* pW2   = (const float*)d_in[22];
  const float* pb2   = (const float*)d_in[23];
  const float* sW    = (const float*)d_in[24];
  const float* sb    = (const float*)d_in[25];
  const float* lng   = (const float*)d_in[26];
  const float* lnb   = (const float*)d_in[27];
  const float* gW1   = (const float*)d_in[28];
  const float* gb1   = (const float*)d_in[29];
  const float* gW2   = (const float*)d_in[30];
  const float* gb2   = (const float*)d_in[31];

  float* ws  = (float*)d_ws;
  float* out = (float*)d_out;
  unsigned short* hb = (unsigned short*)(ws + OFF_HB);
  int* cntB = (int*)ws + OFF_CNTB;

  hipMemsetAsync(d_ws, 0, 260 * sizeof(float), stream);
  hipMemsetAsync((void*)cntB, 0, 4 * 4096 * sizeof(int), stream);
  setup_kernel<<<1761, 256, 0, stream>>>(bw, pw, area, bsrc, bdst, pblk,
                                         bW1, bW2, pW1, pW2, sW, inW1, inW2, ws);
  scan_kernel<<<2, 1024, 0, stream>>>(ws);
  mid_kernel<<<1024, 512, 0, stream>>>(bsrc, bdst, pblk, ppin, bw, pw, pins,
                                       bfeat, rid, remb, iemb, inb1, inb2, bb1, pb1,
                                       ws, hb);
  edge_kernel<<<3072, 256, 0, stream>>>(ws);
  selfln_kernel<<<256, 512, 0, stream>>>(hb, sb, lng, lnb, bb2, pb2,
                                         gW1, gb1, gW2, gb2, ws, out);
}